// Round 1
// baseline (3994.501 us; speedup 1.0000x reference)
//
#include <hip/hip_runtime.h>
#include <hip/hip_bf16.h>
#include <cstdint>
#include <cstddef>

// Problem constants
constexpr int B_  = 4;
constexpr int M_  = 1024;
constexpr int S_  = 1024;
constexpr int D_  = 1024;
constexpr int H_  = 16;
constexpr int FF_ = 4096;
constexpr int NE_ = 128;
// HD = 64, scale = 1/sqrt(64) = 0.125

// ---------------------------------------------------------------------------
// GEMM: C[r][c] = sum_k A[r][k] * W[c][k] + bias[c]   (W stored (Nout, K))
// 128x128 tile, BK=16, 256 threads, 8x8 per thread.
// Grid: (Nout/128, Nrows/128). All dims must divide evenly (they do here).
// ---------------------------------------------------------------------------
template <bool RELU>
__global__ __launch_bounds__(256) void gemm_wt_kernel(
    const float* __restrict__ A, const float* __restrict__ W,
    const float* __restrict__ bias, float* __restrict__ C,
    int K, int Nout)
{
    __shared__ float As[16][132];
    __shared__ float Bs[16][132];
    const int tid = threadIdx.x;
    const int bm = blockIdx.y * 128;
    const int bn = blockIdx.x * 128;
    const int tx = tid & 15;
    const int ty = tid >> 4;
    const int lr = tid >> 1;          // 0..127
    const int lk = (tid & 1) * 8;     // 0 or 8

    const float* aptr = A + (size_t)(bm + lr) * K + lk;
    const float* wptr = W + (size_t)(bn + lr) * K + lk;

    float acc[8][8];
#pragma unroll
    for (int i = 0; i < 8; ++i)
#pragma unroll
        for (int j = 0; j < 8; ++j) acc[i][j] = 0.f;

    for (int k0 = 0; k0 < K; k0 += 16) {
        float ta[8], tb[8];
        *(float4*)(ta)     = *(const float4*)(aptr + k0);
        *(float4*)(ta + 4) = *(const float4*)(aptr + k0 + 4);
        *(float4*)(tb)     = *(const float4*)(wptr + k0);
        *(float4*)(tb + 4) = *(const float4*)(wptr + k0 + 4);
#pragma unroll
        for (int q = 0; q < 8; ++q) As[lk + q][lr] = ta[q];
#pragma unroll
        for (int q = 0; q < 8; ++q) Bs[lk + q][lr] = tb[q];
        __syncthreads();
#pragma unroll
        for (int kk = 0; kk < 16; ++kk) {
            float a[8], b[8];
            *(float4*)(a)     = *(const float4*)(&As[kk][ty * 8]);
            *(float4*)(a + 4) = *(const float4*)(&As[kk][ty * 8 + 4]);
            *(float4*)(b)     = *(const float4*)(&Bs[kk][tx * 8]);
            *(float4*)(b + 4) = *(const float4*)(&Bs[kk][tx * 8 + 4]);
#pragma unroll
            for (int i = 0; i < 8; ++i)
#pragma unroll
                for (int j = 0; j < 8; ++j)
                    acc[i][j] = fmaf(a[i], b[j], acc[i][j]);
        }
        __syncthreads();
    }

    float bv[8];
    *(float4*)(bv)     = *(const float4*)(bias + bn + tx * 8);
    *(float4*)(bv + 4) = *(const float4*)(bias + bn + tx * 8 + 4);
#pragma unroll
    for (int i = 0; i < 8; ++i) {
        float* cp = C + (size_t)(bm + ty * 8 + i) * Nout + bn + tx * 8;
        float o[8];
#pragma unroll
        for (int j = 0; j < 8; ++j) {
            float v = acc[i][j] + bv[j];
            if (RELU) v = fmaxf(v, 0.f);
            o[j] = v;
        }
        *(float4*)(cp)     = *(const float4*)(o);
        *(float4*)(cp + 4) = *(const float4*)(o + 4);
    }
}

// ---------------------------------------------------------------------------
// GEMM (K-major B): C[m][n] = sum_k A[m][k] * Bm[k][n]   (no bias)
// 64x64 tile, BK=16, 256 threads, 4x4 per thread. Batched via blockIdx.z.
// ---------------------------------------------------------------------------
__global__ __launch_bounds__(256) void gemm_kn_kernel(
    const float* __restrict__ A, const float* __restrict__ Bm,
    float* __restrict__ C, int K, int Ncols,
    size_t batchA, size_t batchB, size_t batchC)
{
    __shared__ float As[64][20];   // [m][k]
    __shared__ float Bs[16][68];   // [k][n]
    const float* Ab = A + (size_t)blockIdx.z * batchA;
    const float* Bb = Bm + (size_t)blockIdx.z * batchB;
    float* Cb = C + (size_t)blockIdx.z * batchC;
    const int tid = threadIdx.x;
    const int m0 = blockIdx.y * 64, n0 = blockIdx.x * 64;
    const int tx = tid & 15, ty = tid >> 4;
    const int am = tid >> 2, ak = (tid & 3) * 4;
    const int bk = tid >> 4, bn = (tid & 15) * 4;

    float acc[4][4];
#pragma unroll
    for (int i = 0; i < 4; ++i)
#pragma unroll
        for (int j = 0; j < 4; ++j) acc[i][j] = 0.f;

    for (int k0 = 0; k0 < K; k0 += 16) {
        float4 av = *(const float4*)(Ab + (size_t)(m0 + am) * K + k0 + ak);
        float4 bvv = *(const float4*)(Bb + (size_t)(k0 + bk) * Ncols + n0 + bn);
        *(float4*)&As[am][ak] = av;
        *(float4*)&Bs[bk][bn] = bvv;
        __syncthreads();
#pragma unroll
        for (int kk = 0; kk < 16; ++kk) {
            float a[4], b[4];
#pragma unroll
            for (int i = 0; i < 4; ++i) a[i] = As[ty * 4 + i][kk];
            *(float4*)b = *(const float4*)&Bs[kk][tx * 4];
#pragma unroll
            for (int i = 0; i < 4; ++i)
#pragma unroll
                for (int j = 0; j < 4; ++j)
                    acc[i][j] = fmaf(a[i], b[j], acc[i][j]);
        }
        __syncthreads();
    }
#pragma unroll
    for (int i = 0; i < 4; ++i) {
        float* cp = Cb + (size_t)(m0 + ty * 4 + i) * Ncols + n0 + tx * 4;
        *(float4*)cp = *(const float4*)(acc[i]);
    }
}

// ---------------------------------------------------------------------------
// slots[b][n][d] = sum_m disp[b][m][n] * h[b][m][d]   (A^T GEMM)
// Grid: (FF/64, NE/64, B). 64x64 tile, BK=16.
// ---------------------------------------------------------------------------
__global__ __launch_bounds__(256) void slots_kernel(
    const float* __restrict__ disp, const float* __restrict__ h,
    float* __restrict__ slots)
{
    __shared__ float As[16][68];   // [m][n]
    __shared__ float Bs[16][68];   // [m][d]
    const int b = blockIdx.z;
    const int n0 = blockIdx.y * 64, d0 = blockIdx.x * 64;
    const float* Db = disp + (size_t)b * M_ * NE_;
    const float* Hb = h + (size_t)b * M_ * FF_;
    const int tid = threadIdx.x;
    const int tx = tid & 15, ty = tid >> 4;
    const int lk = tid >> 4, lc = (tid & 15) * 4;

    float acc[4][4];
#pragma unroll
    for (int i = 0; i < 4; ++i)
#pragma unroll
        for (int j = 0; j < 4; ++j) acc[i][j] = 0.f;

    for (int m0 = 0; m0 < M_; m0 += 16) {
        *(float4*)&As[lk][lc] = *(const float4*)(Db + (size_t)(m0 + lk) * NE_ + n0 + lc);
        *(float4*)&Bs[lk][lc] = *(const float4*)(Hb + (size_t)(m0 + lk) * FF_ + d0 + lc);
        __syncthreads();
#pragma unroll
        for (int kk = 0; kk < 16; ++kk) {
            float a[4], b4[4];
            *(float4*)a  = *(const float4*)&As[kk][ty * 4];
            *(float4*)b4 = *(const float4*)&Bs[kk][tx * 4];
#pragma unroll
            for (int i = 0; i < 4; ++i)
#pragma unroll
                for (int j = 0; j < 4; ++j)
                    acc[i][j] = fmaf(a[i], b4[j], acc[i][j]);
        }
        __syncthreads();
    }
#pragma unroll
    for (int i = 0; i < 4; ++i) {
        float* cp = slots + ((size_t)b * NE_ + n0 + ty * 4 + i) * FF_ + d0 + tx * 4;
        *(float4*)cp = *(const float4*)(acc[i]);
    }
}

// ---------------------------------------------------------------------------
// Attention (f32, non-flash, whole score strip per 8-row Q tile in LDS).
// Grid: (M/8, H, B). 256 threads.
// ---------------------------------------------------------------------------
__global__ __launch_bounds__(256) void attn_kernel(
    const float* __restrict__ Qm, int q_stride,
    const float* __restrict__ Km, int k_stride,
    const float* __restrict__ Vm, int v_stride,
    float* __restrict__ Om, int Slen)
{
    __shared__ float sc[8][1024];    // 32 KB score strip
    __shared__ float Qs[8][68];
    __shared__ float KVs[64][69];    // K phase: [d][j]; V phase: [j][d]
    const int b = blockIdx.z, hh = blockIdx.y;
    const int m0 = blockIdx.x * 8;
    const int tid = threadIdx.x;
    const int r = tid >> 5;          // 0..7  (q row)
    const int c = tid & 31;          // 0..31

    if (tid < 128) {
        const int qr = tid >> 4;          // 0..7
        const int d4 = (tid & 15) * 4;
        const float* qp = Qm + ((size_t)b * M_ + m0 + qr) * q_stride + hh * 64 + d4;
        float4 q4 = *(const float4*)qp;
        Qs[qr][d4 + 0] = q4.x * 0.125f;
        Qs[qr][d4 + 1] = q4.y * 0.125f;
        Qs[qr][d4 + 2] = q4.z * 0.125f;
        Qs[qr][d4 + 3] = q4.w * 0.125f;
    }
    const int lj = tid >> 2;             // 0..63
    const int ld = (tid & 3) * 16;       // 0,16,32,48

    // Phase 1: scores
    for (int s0 = 0; s0 < Slen; s0 += 64) {
        __syncthreads();
        {
            const float* kp = Km + ((size_t)b * Slen + s0 + lj) * k_stride + hh * 64 + ld;
            float tmp[16];
            *(float4*)(tmp)      = *(const float4*)(kp);
            *(float4*)(tmp + 4)  = *(const float4*)(kp + 4);
            *(float4*)(tmp + 8)  = *(const float4*)(kp + 8);
            *(float4*)(tmp + 12) = *(const float4*)(kp + 12);
#pragma unroll
            for (int q = 0; q < 16; ++q) KVs[ld + q][lj] = tmp[q];  // transposed: [d][j]
        }
        __syncthreads();
        float a0 = 0.f, a1 = 0.f;
#pragma unroll 8
        for (int d = 0; d < 64; ++d) {
            float qv = Qs[r][d];
            a0 = fmaf(qv, KVs[d][2 * c],     a0);
            a1 = fmaf(qv, KVs[d][2 * c + 1], a1);
        }
        sc[r][s0 + 2 * c]     = a0;
        sc[r][s0 + 2 * c + 1] = a1;
    }

    // Softmax over each row (32 lanes per row, same wave -> lockstep)
    float mx = -3.0e38f;
    for (int i = 0; i < 32; ++i) mx = fmaxf(mx, sc[r][c + 32 * i]);
#pragma unroll
    for (int off = 16; off; off >>= 1) mx = fmaxf(mx, __shfl_xor(mx, off, 32));
    float sum = 0.f;
    for (int i = 0; i < 32; ++i) {
        float p = __expf(sc[r][c + 32 * i] - mx);
        sc[r][c + 32 * i] = p;
        sum += p;
    }
#pragma unroll
    for (int off = 16; off; off >>= 1) sum += __shfl_xor(sum, off, 32);
    const float inv = 1.f / sum;

    // Phase 2: O = P @ V
    float acc0 = 0.f, acc1 = 0.f;
    for (int s0 = 0; s0 < Slen; s0 += 64) {
        __syncthreads();
        {
            const float* vp = Vm + ((size_t)b * Slen + s0 + lj) * v_stride + hh * 64 + ld;
            float tmp[16];
            *(float4*)(tmp)      = *(const float4*)(vp);
            *(float4*)(tmp + 4)  = *(const float4*)(vp + 4);
            *(float4*)(tmp + 8)  = *(const float4*)(vp + 8);
            *(float4*)(tmp + 12) = *(const float4*)(vp + 12);
#pragma unroll
            for (int q = 0; q < 16; ++q) KVs[lj][ld + q] = tmp[q];  // row-major: [j][d]
        }
        __syncthreads();
#pragma unroll 8
        for (int j = 0; j < 64; ++j) {
            float p = sc[r][s0 + j];
            acc0 = fmaf(p, KVs[j][2 * c],     acc0);
            acc1 = fmaf(p, KVs[j][2 * c + 1], acc1);
        }
    }
    float2 o2 = make_float2(acc0 * inv, acc1 * inv);
    *(float2*)(Om + ((size_t)b * M_ + m0 + r) * D_ + hh * 64 + 2 * c) = o2;
}

// ---------------------------------------------------------------------------
// y = LayerNorm(X + R) * g + b over rows of 1024. Grid: B*M, 256 threads.
// ---------------------------------------------------------------------------
__global__ __launch_bounds__(256) void resid_ln_kernel(
    const float* __restrict__ X, const float* __restrict__ R,
    const float* __restrict__ g, const float* __restrict__ bt,
    float* __restrict__ Y)
{
    __shared__ float s1[4], s2[4];
    const size_t row = blockIdx.x;
    const int tid = threadIdx.x;
    const float4 x4 = *(const float4*)(X + row * 1024 + tid * 4);
    const float4 r4 = *(const float4*)(R + row * 1024 + tid * 4);
    float v[4] = {x4.x + r4.x, x4.y + r4.y, x4.z + r4.z, x4.w + r4.w};
    float s = v[0] + v[1] + v[2] + v[3];
    float q = v[0] * v[0] + v[1] * v[1] + v[2] * v[2] + v[3] * v[3];
#pragma unroll
    for (int off = 32; off; off >>= 1) {
        s += __shfl_xor(s, off);
        q += __shfl_xor(q, off);
    }
    if ((tid & 63) == 0) { s1[tid >> 6] = s; s2[tid >> 6] = q; }
    __syncthreads();
    s = s1[0] + s1[1] + s1[2] + s1[3];
    q = s2[0] + s2[1] + s2[2] + s2[3];
    const float mu = s * (1.f / 1024.f);
    const float var = q * (1.f / 1024.f) - mu * mu;
    const float rinv = rsqrtf(var + 1e-5f);
    const float4 g4 = *(const float4*)(g + tid * 4);
    const float4 b4 = *(const float4*)(bt + tid * 4);
    float4 o;
    o.x = (v[0] - mu) * rinv * g4.x + b4.x;
    o.y = (v[1] - mu) * rinv * g4.y + b4.y;
    o.z = (v[2] - mu) * rinv * g4.z + b4.z;
    o.w = (v[3] - mu) * rinv * g4.w + b4.w;
    *(float4*)(Y + row * 1024 + tid * 4) = o;
}

// ---------------------------------------------------------------------------
// dispatch[b][m][n] = softmax over m of logits[b][m][n]. Grid: (NE, B), 256 thr.
// ---------------------------------------------------------------------------
__global__ __launch_bounds__(256) void dispatch_softmax_kernel(
    const float* __restrict__ logits, float* __restrict__ disp)
{
    __shared__ float red[4];
    const int n = blockIdx.x, b = blockIdx.y;
    const float* L = logits + (size_t)b * M_ * NE_ + n;
    float* O = disp + (size_t)b * M_ * NE_ + n;
    const int tid = threadIdx.x;
    float v[4];
#pragma unroll
    for (int i = 0; i < 4; ++i) v[i] = L[(size_t)(tid + 256 * i) * NE_];
    float mx = fmaxf(fmaxf(v[0], v[1]), fmaxf(v[2], v[3]));
#pragma unroll
    for (int off = 32; off; off >>= 1) mx = fmaxf(mx, __shfl_xor(mx, off));
    if ((tid & 63) == 0) red[tid >> 6] = mx;
    __syncthreads();
    mx = fmaxf(fmaxf(red[0], red[1]), fmaxf(red[2], red[3]));
    __syncthreads();
    float e[4], s = 0.f;
#pragma unroll
    for (int i = 0; i < 4; ++i) { e[i] = __expf(v[i] - mx); s += e[i]; }
#pragma unroll
    for (int off = 32; off; off >>= 1) s += __shfl_xor(s, off);
    if ((tid & 63) == 0) red[tid >> 6] = s;
    __syncthreads();
    s = red[0] + red[1] + red[2] + red[3];
    const float inv = 1.f / s;
#pragma unroll
    for (int i = 0; i < 4; ++i) O[(size_t)(tid + 256 * i) * NE_] = e[i] * inv;
}

// ---------------------------------------------------------------------------
// combine[b][m][:] = softmax over the 128 experts. Grid: B*M, 64 threads.
// ---------------------------------------------------------------------------
__global__ __launch_bounds__(64) void combine_softmax_kernel(
    const float* __restrict__ logits, float* __restrict__ comb)
{
    const size_t row = blockIdx.x;
    const int lane = threadIdx.x;
    const float* L = logits + row * NE_;
    float a = L[lane], c = L[lane + 64];
    float mx = fmaxf(a, c);
#pragma unroll
    for (int off = 32; off; off >>= 1) mx = fmaxf(mx, __shfl_xor(mx, off));
    float e0 = __expf(a - mx), e1 = __expf(c - mx);
    float s = e0 + e1;
#pragma unroll
    for (int off = 32; off; off >>= 1) s += __shfl_xor(s, off);
    const float inv = 1.f / s;
    comb[row * NE_ + lane] = e0 * inv;
    comb[row * NE_ + lane + 64] = e1 * inv;
}

// ---------------------------------------------------------------------------
// y[b][n][d] = sum_f slots[b][n][f] * exp_w[n][f][d] + exp_b[n][d]
// Grid: (NE, D/256). 256 threads, one d each, 4 batches per thread.
// Memory-bound: reads exp_w (2.15 GB) exactly once, coalesced.
// ---------------------------------------------------------------------------
__global__ __launch_bounds__(256) void expert_kernel(
    const float* __restrict__ slots, const float* __restrict__ exp_w,
    const float* __restrict__ exp_b, float* __restrict__ y)
{
    __shared__ float sl[4][128];
    const int n = blockIdx.x;
    const int d = blockIdx.y * 256 + threadIdx.x;
    float acc0 = 0.f, acc1 = 0.f, acc2 = 0.f, acc3 = 0.f;
    const float eb = exp_b[(size_t)n * D_ + d];
    const float* wbase = exp_w + (size_t)n * FF_ * D_ + d;
    for (int f0 = 0; f0 < FF_; f0 += 128) {
        __syncthreads();
        const int t = threadIdx.x;
        sl[t >> 7][t & 127] =
            slots[((size_t)(t >> 7) * NE_ + n) * FF_ + f0 + (t & 127)];
        sl[(t >> 7) + 2][t & 127] =
            slots[((size_t)((t >> 7) + 2) * NE_ + n) * FF_ + f0 + (t & 127)];
        __syncthreads();
        const float* wp = wbase + (size_t)f0 * D_;
#pragma unroll 8
        for (int f = 0; f < 128; ++f) {
            float w = wp[(size_t)f * D_];
            acc0 = fmaf(sl[0][f], w, acc0);
            acc1 = fmaf(sl[1][f], w, acc1);
            acc2 = fmaf(sl[2][f], w, acc2);
            acc3 = fmaf(sl[3][f], w, acc3);
        }
    }
    y[((size_t)0 * NE_ + n) * D_ + d] = acc0 + eb;
    y[((size_t)1 * NE_ + n) * D_ + d] = acc1 + eb;
    y[((size_t)2 * NE_ + n) * D_ + d] = acc2 + eb;
    y[((size_t)3 * NE_ + n) * D_ + d] = acc3 + eb;
}

// ---------------------------------------------------------------------------
extern "C" void kernel_launch(void* const* d_in, const int* in_sizes, int n_in,
                              void* d_out, int out_size, void* d_ws, size_t ws_size,
                              hipStream_t stream)
{
    const float* tgt      = (const float*)d_in[0];
    const float* memry    = (const float*)d_in[1];
    const float* sa_in_w  = (const float*)d_in[2];
    const float* sa_in_b  = (const float*)d_in[3];
    const float* sa_out_w = (const float*)d_in[4];
    const float* sa_out_b = (const float*)d_in[5];
    const float* ca_in_w  = (const float*)d_in[6];
    const float* ca_in_b  = (const float*)d_in[7];
    const float* ca_out_w = (const float*)d_in[8];
    const float* ca_out_b = (const float*)d_in[9];
    const float* norm1_g  = (const float*)d_in[10];
    const float* norm1_b  = (const float*)d_in[11];
    const float* norm2_g  = (const float*)d_in[12];
    const float* norm2_b  = (const float*)d_in[13];
    const float* norm3_g  = (const float*)d_in[14];
    const float* norm3_b  = (const float*)d_in[15];
    const float* lin_w    = (const float*)d_in[16];
    const float* lin_b    = (const float*)d_in[17];
    const float* phi      = (const float*)d_in[18];
    const float* exp_w    = (const float*)d_in[19];
    const float* exp_b    = (const float*)d_in[20];

    float* ws = (float*)d_ws;
    // Region layout (floats). Peak ~201.3 MB.
    float* qkv   = ws;                  // 12,582,912  (SA qkv; later reused: q_ca @0, kv_ca @4.19M)
    float* q_ca  = ws;                  //  4,194,304  (alias, after qkv dead)
    float* kv_ca = ws + 4194304;        //  8,388,608  (alias)
    float* o_buf = ws + 12582912;       //  4,194,304
    float* proj  = ws + 16777216;       //  4,194,304  (attn proj / ca proj / ff_out)
    float* x1    = ws + 20971520;       //  4,194,304
    float* x2    = ws + 25165824;       //  4,194,304
    float* hbuf  = ws + 29360128;       // 16,777,216
    float* logit = ws + 46137344;       //    524,288
    float* disp  = ws + 46661632;       //    524,288
    float* comb  = ws + 47185920;       //    524,288
    float* slotb = ws + 47710208;       //  2,097,152
    float* ybuf  = ws + 49807360;       //    524,288

    // ---- Self-attention ----
    gemm_wt_kernel<false><<<dim3(3072 / 128, 4096 / 128), 256, 0, stream>>>(
        tgt, sa_in_w, sa_in_b, qkv, 1024, 3072);
    attn_kernel<<<dim3(M_ / 8, H_, B_), 256, 0, stream>>>(
        qkv, 3072, qkv + 1024, 3072, qkv + 2048, 3072, o_buf, S_);
    gemm_wt_kernel<false><<<dim3(8, 32), 256, 0, stream>>>(
        o_buf, sa_out_w, sa_out_b, proj, 1024, 1024);
    resid_ln_kernel<<<4096, 256, 0, stream>>>(tgt, proj, norm1_g, norm1_b, x1);

    // ---- Cross-attention ----
    gemm_wt_kernel<false><<<dim3(8, 32), 256, 0, stream>>>(
        x1, ca_in_w, ca_in_b, q_ca, 1024, 1024);
    gemm_wt_kernel<false><<<dim3(16, 32), 256, 0, stream>>>(
        memry, ca_in_w + (size_t)1024 * 1024, ca_in_b + 1024, kv_ca, 1024, 2048);
    attn_kernel<<<dim3(M_ / 8, H_, B_), 256, 0, stream>>>(
        q_ca, 1024, kv_ca, 2048, kv_ca + 1024, 2048, o_buf, S_);
    gemm_wt_kernel<false><<<dim3(8, 32), 256, 0, stream>>>(
        o_buf, ca_out_w, ca_out_b, proj, 1024, 1024);
    resid_ln_kernel<<<4096, 256, 0, stream>>>(x1, proj, norm2_g, norm2_b, x2);

    // ---- FF + SoftMoE ----
    gemm_wt_kernel<true><<<dim3(32, 32), 256, 0, stream>>>(
        x2, lin_w, lin_b, hbuf, 1024, 4096);
    // logits = h @ phi  (phi is (FF, NE) K-major)
    gemm_kn_kernel<<<dim3(2, 64, 1), 256, 0, stream>>>(
        hbuf, phi, logit, 4096, 128, 0, 0, 0);
    dispatch_softmax_kernel<<<dim3(NE_, B_), 256, 0, stream>>>(logit, disp);
    combine_softmax_kernel<<<dim3(B_ * M_), 64, 0, stream>>>(logit, comb);
    slots_kernel<<<dim3(FF_ / 64, NE_ / 64, B_), 256, 0, stream>>>(disp, hbuf, slotb);
    expert_kernel<<<dim3(NE_, D_ / 256), 256, 0, stream>>>(slotb, exp_w, exp_b, ybuf);
    // ff_out = combine @ y   (batched, K = NE)
    gemm_kn_kernel<<<dim3(16, 16, B_), 256, 0, stream>>>(
        comb, ybuf, proj, 128, 1024,
        (size_t)M_ * NE_, (size_t)NE_ * D_, (size_t)M_ * D_);
    resid_ln_kernel<<<4096, 256, 0, stream>>>(x2, proj, norm3_g, norm3_b, (float*)d_out);
}

// Round 2
// 2765.536 us; speedup vs baseline: 1.4444x; 1.4444x over previous
//
#include <hip/hip_runtime.h>
#include <cstdint>
#include <cstddef>

typedef unsigned short u16;
typedef unsigned int   u32;
typedef short bf16x8 __attribute__((ext_vector_type(8)));
typedef float f32x4  __attribute__((ext_vector_type(4)));
typedef u16   u16x8  __attribute__((ext_vector_type(8)));
typedef u16   u16x4  __attribute__((ext_vector_type(4)));
typedef u16   u16x2  __attribute__((ext_vector_type(2)));

// Problem constants
constexpr int B_  = 4;
constexpr int M_  = 1024;
constexpr int S_  = 1024;
constexpr int D_  = 1024;
constexpr int H_  = 16;
constexpr int FF_ = 4096;
constexpr int NE_ = 128;

__device__ __forceinline__ u16 f2bf(float f) {
    u32 u = __builtin_bit_cast(u32, f);
    u = (u + 0x7fffu + ((u >> 16) & 1u)) >> 16;   // RNE
    return (u16)u;
}

__device__ __forceinline__ void gload_lds16(const u16* g, u16* l) {
    __builtin_amdgcn_global_load_lds(
        (const __attribute__((address_space(1))) u32*)g,
        (__attribute__((address_space(3))) u32*)l, 16, 0, 0);
}

// ---------------------------------------------------------------------------
// bf16 MFMA GEMM (m97 structure): C[r][c] = sum_k A[r][k]*W[c][k] (+bias[c])
// A: (Mr x K) bf16 row-major. W: (N x K) bf16 row-major. 128x128 tile, BK=32.
// 256 threads = 4 waves in 2x2 over 64x64 quadrants; acc 4x4 frags of 16x16.
// Strides sA/sW/sC are per-blockIdx.z batch strides in ELEMENTS.
// ---------------------------------------------------------------------------
template<int OUT_BF16, int RELU, int HAS_BIAS>
__global__ __launch_bounds__(256) void gemm_bt_mfma(
    const u16* __restrict__ A, const u16* __restrict__ W,
    const float* __restrict__ bias, void* __restrict__ Cout,
    int K, int N, size_t sA, size_t sW, size_t sC)
{
    __shared__ u16 As[128 * 32];
    __shared__ u16 Bs[128 * 32];
    const int tid = threadIdx.x;
    const int w = tid >> 6, l = tid & 63;
    const int bm = blockIdx.y * 128, bn = blockIdx.x * 128;
    const u16* Ab = A + (size_t)blockIdx.z * sA;
    const u16* Wb = W + (size_t)blockIdx.z * sW;

    const int wr = w >> 1, wc = w & 1;
    // staging: wave w fills 1KB chunks q=w and q=w+4 of each 8KB tile.
    // chunk q covers rows [q*16, q*16+16); lane l -> row q*16 + l/4, k (l%4)*8
    const int sr = l >> 2;
    const int sk = (l & 3) * 8;
    const u16* aG0 = Ab + (size_t)(bm + w * 16 + sr) * K + sk;
    const u16* aG1 = Ab + (size_t)(bm + (w + 4) * 16 + sr) * K + sk;
    const u16* bG0 = Wb + (size_t)(bn + w * 16 + sr) * K + sk;
    const u16* bG1 = Wb + (size_t)(bn + (w + 4) * 16 + sr) * K + sk;
    u16* aL0 = &As[w * 512];
    u16* aL1 = &As[(w + 4) * 512];
    u16* bL0 = &Bs[w * 512];
    u16* bL1 = &Bs[(w + 4) * 512];

    // fragment read: row l&15 within 16-row frag, k elems [(l>>4)*8, +8)
    const int fr = l & 15;
    const int fk = (l >> 4) * 8;

    f32x4 acc[4][4];
#pragma unroll
    for (int i = 0; i < 4; ++i)
#pragma unroll
        for (int j = 0; j < 4; ++j)
#pragma unroll
            for (int q = 0; q < 4; ++q) acc[i][j][q] = 0.f;

    for (int k0 = 0; k0 < K; k0 += 32) {
        __syncthreads();                    // prev compute done before overwrite
        gload_lds16(aG0, aL0);
        gload_lds16(aG1, aL1);
        gload_lds16(bG0, bL0);
        gload_lds16(bG1, bL1);
        aG0 += 32; aG1 += 32; bG0 += 32; bG1 += 32;
        __syncthreads();                    // drains vmcnt(0): tiles ready
        bf16x8 af[4], bfr[4];
#pragma unroll
        for (int m = 0; m < 4; ++m)
            af[m] = *(const bf16x8*)&As[(wr * 64 + m * 16 + fr) * 32 + fk];
#pragma unroll
        for (int n = 0; n < 4; ++n)
            bfr[n] = *(const bf16x8*)&Bs[(wc * 64 + n * 16 + fr) * 32 + fk];
#pragma unroll
        for (int m = 0; m < 4; ++m)
#pragma unroll
            for (int n = 0; n < 4; ++n)
                acc[m][n] = __builtin_amdgcn_mfma_f32_16x16x32_bf16(
                    af[m], bfr[n], acc[m][n], 0, 0, 0);
    }

    // epilogue: D row=(l>>4)*4+j, col=l&15 (m89-verified layout)
    const int row0 = bm + wr * 64 + (l >> 4) * 4;
    const int col0 = bn + wc * 64;
#pragma unroll
    for (int n = 0; n < 4; ++n) {
        const int col = col0 + n * 16 + fr;
        float bv = 0.f;
        if (HAS_BIAS) bv = bias[col];
#pragma unroll
        for (int m = 0; m < 4; ++m) {
            const int row = row0 + m * 16;
#pragma unroll
            for (int j = 0; j < 4; ++j) {
                float v = acc[m][n][j] + bv;
                if (RELU) v = fmaxf(v, 0.f);
                const size_t idx = (size_t)blockIdx.z * sC + (size_t)(row + j) * N + col;
                if (OUT_BF16) ((u16*)Cout)[idx] = f2bf(v);
                else          ((float*)Cout)[idx] = v;
            }
        }
    }
}

// ---------------------------------------------------------------------------
// f32 -> bf16 elementwise convert. n must be a multiple of 2048.
// ---------------------------------------------------------------------------
__global__ __launch_bounds__(256) void cvt_f32_bf16_kernel(
    const float* __restrict__ src, u16* __restrict__ dst)
{
    const size_t i = ((size_t)blockIdx.x * 256 + threadIdx.x) * 8;
    float4 a = *(const float4*)(src + i);
    float4 b = *(const float4*)(src + i + 4);
    u16x8 o;
    o[0] = f2bf(a.x); o[1] = f2bf(a.y); o[2] = f2bf(a.z); o[3] = f2bf(a.w);
    o[4] = f2bf(b.x); o[5] = f2bf(b.y); o[6] = f2bf(b.z); o[7] = f2bf(b.w);
    *(u16x8*)(dst + i) = o;
}

// ---------------------------------------------------------------------------
// Transpose (R x C) -> (C x R), to bf16. 32x32 LDS tiles, 256 threads.
// ---------------------------------------------------------------------------
__global__ __launch_bounds__(256) void transpose_f32_bf16_kernel(
    const float* __restrict__ src, u16* __restrict__ dst, int R, int C)
{
    __shared__ u16 t[32][33];
    const int c0 = blockIdx.x * 32, r0 = blockIdx.y * 32;
    const int x = threadIdx.x & 31, y = threadIdx.x >> 5;
    for (int i = y; i < 32; i += 8)
        t[i][x] = f2bf(src[(size_t)(r0 + i) * C + c0 + x]);
    __syncthreads();
    for (int i = y; i < 32; i += 8)
        dst[(size_t)(c0 + i) * R + r0 + x] = t[x][i];
}

__global__ __launch_bounds__(256) void transpose_bf16_kernel(
    const u16* __restrict__ src, u16* __restrict__ dst, int R, int C,
    size_t sI, size_t sO)
{
    __shared__ u16 t[32][33];
    src += (size_t)blockIdx.z * sI;
    dst += (size_t)blockIdx.z * sO;
    const int c0 = blockIdx.x * 32, r0 = blockIdx.y * 32;
    const int x = threadIdx.x & 31, y = threadIdx.x >> 5;
    for (int i = y; i < 32; i += 8)
        t[i][x] = src[(size_t)(r0 + i) * C + c0 + x];
    __syncthreads();
    for (int i = y; i < 32; i += 8)
        dst[(size_t)(c0 + i) * R + r0 + x] = t[x][i];
}

// ---------------------------------------------------------------------------
// GEMM (K-major B) f32: C[m][n] = sum_k A[m][k]*Bm[k][n]. 64x64 tile. (combine)
// ---------------------------------------------------------------------------
__global__ __launch_bounds__(256) void gemm_kn_kernel(
    const float* __restrict__ A, const float* __restrict__ Bm,
    float* __restrict__ C, int K, int Ncols,
    size_t batchA, size_t batchB, size_t batchC)
{
    __shared__ float As[64][20];
    __shared__ float Bs[16][68];
    const float* Ab = A + (size_t)blockIdx.z * batchA;
    const float* Bb = Bm + (size_t)blockIdx.z * batchB;
    float* Cb = C + (size_t)blockIdx.z * batchC;
    const int tid = threadIdx.x;
    const int m0 = blockIdx.y * 64, n0 = blockIdx.x * 64;
    const int tx = tid & 15, ty = tid >> 4;
    const int am = tid >> 2, ak = (tid & 3) * 4;
    const int bk = tid >> 4, bn = (tid & 15) * 4;

    float acc[4][4];
#pragma unroll
    for (int i = 0; i < 4; ++i)
#pragma unroll
        for (int j = 0; j < 4; ++j) acc[i][j] = 0.f;

    for (int k0 = 0; k0 < K; k0 += 16) {
        float4 av = *(const float4*)(Ab + (size_t)(m0 + am) * K + k0 + ak);
        float4 bvv = *(const float4*)(Bb + (size_t)(k0 + bk) * Ncols + n0 + bn);
        *(float4*)&As[am][ak] = av;
        *(float4*)&Bs[bk][bn] = bvv;
        __syncthreads();
#pragma unroll
        for (int kk = 0; kk < 16; ++kk) {
            float a[4], b[4];
#pragma unroll
            for (int i = 0; i < 4; ++i) a[i] = As[ty * 4 + i][kk];
            *(float4*)b = *(const float4*)&Bs[kk][tx * 4];
#pragma unroll
            for (int i = 0; i < 4; ++i)
#pragma unroll
                for (int j = 0; j < 4; ++j)
                    acc[i][j] = fmaf(a[i], b[j], acc[i][j]);
        }
        __syncthreads();
    }
#pragma unroll
    for (int i = 0; i < 4; ++i) {
        float* cp = Cb + (size_t)(m0 + ty * 4 + i) * Ncols + n0 + tx * 4;
        *(float4*)cp = *(const float4*)(acc[i]);
    }
}

// ---------------------------------------------------------------------------
// Attention (f32 compute), bf16 output. Grid: (M/8, H, B). 256 threads.
// ---------------------------------------------------------------------------
__global__ __launch_bounds__(256) void attn_kernel(
    const float* __restrict__ Qm, int q_stride,
    const float* __restrict__ Km, int k_stride,
    const float* __restrict__ Vm, int v_stride,
    u16* __restrict__ Om, int Slen)
{
    __shared__ float sc[8][1024];
    __shared__ float Qs[8][68];
    __shared__ float KVs[64][69];
    const int b = blockIdx.z, hh = blockIdx.y;
    const int m0 = blockIdx.x * 8;
    const int tid = threadIdx.x;
    const int r = tid >> 5;
    const int c = tid & 31;

    if (tid < 128) {
        const int qr = tid >> 4;
        const int d4 = (tid & 15) * 4;
        const float* qp = Qm + ((size_t)b * M_ + m0 + qr) * q_stride + hh * 64 + d4;
        float4 q4 = *(const float4*)qp;
        Qs[qr][d4 + 0] = q4.x * 0.125f;
        Qs[qr][d4 + 1] = q4.y * 0.125f;
        Qs[qr][d4 + 2] = q4.z * 0.125f;
        Qs[qr][d4 + 3] = q4.w * 0.125f;
    }
    const int lj = tid >> 2;
    const int ld = (tid & 3) * 16;

    for (int s0 = 0; s0 < Slen; s0 += 64) {
        __syncthreads();
        {
            const float* kp = Km + ((size_t)b * Slen + s0 + lj) * k_stride + hh * 64 + ld;
            float tmp[16];
            *(float4*)(tmp)      = *(const float4*)(kp);
            *(float4*)(tmp + 4)  = *(const float4*)(kp + 4);
            *(float4*)(tmp + 8)  = *(const float4*)(kp + 8);
            *(float4*)(tmp + 12) = *(const float4*)(kp + 12);
#pragma unroll
            for (int q = 0; q < 16; ++q) KVs[ld + q][lj] = tmp[q];
        }
        __syncthreads();
        float a0 = 0.f, a1 = 0.f;
#pragma unroll 8
        for (int d = 0; d < 64; ++d) {
            float qv = Qs[r][d];
            a0 = fmaf(qv, KVs[d][2 * c],     a0);
            a1 = fmaf(qv, KVs[d][2 * c + 1], a1);
        }
        sc[r][s0 + 2 * c]     = a0;
        sc[r][s0 + 2 * c + 1] = a1;
    }

    float mx = -3.0e38f;
    for (int i = 0; i < 32; ++i) mx = fmaxf(mx, sc[r][c + 32 * i]);
#pragma unroll
    for (int off = 16; off; off >>= 1) mx = fmaxf(mx, __shfl_xor(mx, off, 32));
    float sum = 0.f;
    for (int i = 0; i < 32; ++i) {
        float p = __expf(sc[r][c + 32 * i] - mx);
        sc[r][c + 32 * i] = p;
        sum += p;
    }
#pragma unroll
    for (int off = 16; off; off >>= 1) sum += __shfl_xor(sum, off, 32);
    const float inv = 1.f / sum;

    float acc0 = 0.f, acc1 = 0.f;
    for (int s0 = 0; s0 < Slen; s0 += 64) {
        __syncthreads();
        {
            const float* vp = Vm + ((size_t)b * Slen + s0 + lj) * v_stride + hh * 64 + ld;
            float tmp[16];
            *(float4*)(tmp)      = *(const float4*)(vp);
            *(float4*)(tmp + 4)  = *(const float4*)(vp + 4);
            *(float4*)(tmp + 8)  = *(const float4*)(vp + 8);
            *(float4*)(tmp + 12) = *(const float4*)(vp + 12);
#pragma unroll
            for (int q = 0; q < 16; ++q) KVs[lj][ld + q] = tmp[q];
        }
        __syncthreads();
#pragma unroll 8
        for (int j = 0; j < 64; ++j) {
            float p = sc[r][s0 + j];
            acc0 = fmaf(p, KVs[j][2 * c],     acc0);
            acc1 = fmaf(p, KVs[j][2 * c + 1], acc1);
        }
    }
    u16x2 o2;
    o2[0] = f2bf(acc0 * inv);
    o2[1] = f2bf(acc1 * inv);
    *(u16x2*)(Om + ((size_t)b * M_ + m0 + r) * D_ + hh * 64 + 2 * c) = o2;
}

// ---------------------------------------------------------------------------
// y = LayerNorm(X + R); writes f32 Y and (optionally) bf16 Ybf.
// ---------------------------------------------------------------------------
__global__ __launch_bounds__(256) void resid_ln_kernel(
    const float* __restrict__ X, const float* __restrict__ R,
    const float* __restrict__ g, const float* __restrict__ bt,
    float* __restrict__ Y, u16* __restrict__ Ybf)
{
    __shared__ float s1[4], s2[4];
    const size_t row = blockIdx.x;
    const int tid = threadIdx.x;
    const float4 x4 = *(const float4*)(X + row * 1024 + tid * 4);
    const float4 r4 = *(const float4*)(R + row * 1024 + tid * 4);
    float v[4] = {x4.x + r4.x, x4.y + r4.y, x4.z + r4.z, x4.w + r4.w};
    float s = v[0] + v[1] + v[2] + v[3];
    float q = v[0] * v[0] + v[1] * v[1] + v[2] * v[2] + v[3] * v[3];
#pragma unroll
    for (int off = 32; off; off >>= 1) {
        s += __shfl_xor(s, off);
        q += __shfl_xor(q, off);
    }
    if ((tid & 63) == 0) { s1[tid >> 6] = s; s2[tid >> 6] = q; }
    __syncthreads();
    s = s1[0] + s1[1] + s1[2] + s1[3];
    q = s2[0] + s2[1] + s2[2] + s2[3];
    const float mu = s * (1.f / 1024.f);
    const float var = q * (1.f / 1024.f) - mu * mu;
    const float rinv = rsqrtf(var + 1e-5f);
    const float4 g4 = *(const float4*)(g + tid * 4);
    const float4 b4 = *(const float4*)(bt + tid * 4);
    float o[4];
    o[0] = (v[0] - mu) * rinv * g4.x + b4.x;
    o[1] = (v[1] - mu) * rinv * g4.y + b4.y;
    o[2] = (v[2] - mu) * rinv * g4.z + b4.z;
    o[3] = (v[3] - mu) * rinv * g4.w + b4.w;
    *(float4*)(Y + row * 1024 + tid * 4) = *(float4*)o;
    if (Ybf) {
        u16x4 ob;
        ob[0] = f2bf(o[0]); ob[1] = f2bf(o[1]);
        ob[2] = f2bf(o[2]); ob[3] = f2bf(o[3]);
        *(u16x4*)(Ybf + row * 1024 + tid * 4) = ob;
    }
}

// ---------------------------------------------------------------------------
// dispatch softmax over m, output TRANSPOSED bf16: dispT[b][n][m].
// ---------------------------------------------------------------------------
__global__ __launch_bounds__(256) void dispatch_softmax_T_kernel(
    const float* __restrict__ logits, u16* __restrict__ dispT)
{
    __shared__ float red[4];
    const int n = blockIdx.x, b = blockIdx.y;
    const float* L = logits + (size_t)b * M_ * NE_ + n;
    u16* O = dispT + ((size_t)b * NE_ + n) * M_;
    const int tid = threadIdx.x;
    float v[4];
#pragma unroll
    for (int i = 0; i < 4; ++i) v[i] = L[(size_t)(tid + 256 * i) * NE_];
    float mx = fmaxf(fmaxf(v[0], v[1]), fmaxf(v[2], v[3]));
#pragma unroll
    for (int off = 32; off; off >>= 1) mx = fmaxf(mx, __shfl_xor(mx, off));
    if ((tid & 63) == 0) red[tid >> 6] = mx;
    __syncthreads();
    mx = fmaxf(fmaxf(red[0], red[1]), fmaxf(red[2], red[3]));
    __syncthreads();
    float e[4], s = 0.f;
#pragma unroll
    for (int i = 0; i < 4; ++i) { e[i] = __expf(v[i] - mx); s += e[i]; }
#pragma unroll
    for (int off = 32; off; off >>= 1) s += __shfl_xor(s, off);
    if ((tid & 63) == 0) red[tid >> 6] = s;
    __syncthreads();
    s = red[0] + red[1] + red[2] + red[3];
    const float inv = 1.f / s;
#pragma unroll
    for (int i = 0; i < 4; ++i) O[tid + 256 * i] = f2bf(e[i] * inv);
}

// ---------------------------------------------------------------------------
// combine softmax over 128 experts (f32 out). Grid: B*M, 64 threads.
// ---------------------------------------------------------------------------
__global__ __launch_bounds__(64) void combine_softmax_kernel(
    const float* __restrict__ logits, float* __restrict__ comb)
{
    const size_t row = blockIdx.x;
    const int lane = threadIdx.x;
    const float* L = logits + row * NE_;
    float a = L[lane], c = L[lane + 64];
    float mx = fmaxf(a, c);
#pragma unroll
    for (int off = 32; off; off >>= 1) mx = fmaxf(mx, __shfl_xor(mx, off));
    float e0 = __expf(a - mx), e1 = __expf(c - mx);
    float s = e0 + e1;
#pragma unroll
    for (int off = 32; off; off >>= 1) s += __shfl_xor(s, off);
    const float inv = 1.f / s;
    comb[row * NE_ + lane] = e0 * inv;
    comb[row * NE_ + lane + 64] = e1 * inv;
}

// ---------------------------------------------------------------------------
// y[b][n][d] = sum_f slots[b][n][f] * exp_w[n][f][d] + exp_b[n][d]
// Memory-bound: reads exp_w (2.15 GB f32) exactly once, coalesced.
// ---------------------------------------------------------------------------
__global__ __launch_bounds__(256) void expert_kernel(
    const float* __restrict__ slots, const float* __restrict__ exp_w,
    const float* __restrict__ exp_b, float* __restrict__ y)
{
    __shared__ float sl[4][128];
    const int n = blockIdx.x;
    const int d = blockIdx.y * 256 + threadIdx.x;
    float acc0 = 0.f, acc1 = 0.f, acc2 = 0.f, acc3 = 0.f;
    const float eb = exp_b[(size_t)n * D_ + d];
    const float* wbase = exp_w + (size_t)n * FF_ * D_ + d;
    for (int f0 = 0; f0 < FF_; f0 += 128) {
        __syncthreads();
        const int t = threadIdx.x;
        sl[t >> 7][t & 127] =
            slots[((size_t)(t >> 7) * NE_ + n) * FF_ + f0 + (t & 127)];
        sl[(t >> 7) + 2][t & 127] =
            slots[((size_t)((t >> 7) + 2) * NE_ + n) * FF_ + f0 + (t & 127)];
        __syncthreads();
        const float* wp = wbase + (size_t)f0 * D_;
#pragma unroll 8
        for (int f = 0; f < 128; ++f) {
            float w = wp[(size_t)f * D_];
            acc0 = fmaf(sl[0][f], w, acc0);
            acc1 = fmaf(sl[1][f], w, acc1);
            acc2 = fmaf(sl[2][f], w, acc2);
            acc3 = fmaf(sl[3][f], w, acc3);
        }
    }
    y[((size_t)0 * NE_ + n) * D_ + d] = acc0 + eb;
    y[((size_t)1 * NE_ + n) * D_ + d] = acc1 + eb;
    y[((size_t)2 * NE_ + n) * D_ + d] = acc2 + eb;
    y[((size_t)3 * NE_ + n) * D_ + d] = acc3 + eb;
}

// ---------------------------------------------------------------------------
extern "C" void kernel_launch(void* const* d_in, const int* in_sizes, int n_in,
                              void* d_out, int out_size, void* d_ws, size_t ws_size,
                              hipStream_t stream)
{
    const float* tgt      = (const float*)d_in[0];
    const float* memry    = (const float*)d_in[1];
    const float* sa_in_w  = (const float*)d_in[2];
    const float* sa_in_b  = (const float*)d_in[3];
    const float* sa_out_w = (const float*)d_in[4];
    const float* sa_out_b = (const float*)d_in[5];
    const float* ca_in_w  = (const float*)d_in[6];
    const float* ca_in_b  = (const float*)d_in[7];
    const float* ca_out_w = (const float*)d_in[8];
    const float* ca_out_b = (const float*)d_in[9];
    const float* norm1_g  = (const float*)d_in[10];
    const float* norm1_b  = (const float*)d_in[11];
    const float* norm2_g  = (const float*)d_in[12];
    const float* norm2_b  = (const float*)d_in[13];
    const float* norm3_g  = (const float*)d_in[14];
    const float* norm3_b  = (const float*)d_in[15];
    const float* lin_w    = (const float*)d_in[16];
    const float* lin_b    = (const float*)d_in[17];
    const float* phi      = (const float*)d_in[18];
    const float* exp_w    = (const float*)d_in[19];
    const float* exp_b    = (const float*)d_in[20];

    float* ws = (float*)d_ws;
    // float-unit offsets; ws_size ~8 GiB, total use ~252 MB, no aliasing.
    float* qkv     = ws;                         // 12,582,912 f (also CA: q | kv)
    float* proj    = ws + 12582912;              //  4,194,304
    float* x1      = ws + 16777216;              //  4,194,304
    float* x2      = ws + 20971520;              //  4,194,304
    float* logits  = ws + 25165824;              //    524,288
    float* comb    = ws + 25690112;              //    524,288
    float* slots   = ws + 26214400;              //  2,097,152
    float* ybuf    = ws + 28311552;              //    524,288
    u16*   h_bf    = (u16*)(ws + 28835840);      // 16,777,216 u16
    u16*   hT_bf   = (u16*)(ws + 37224448);      // 16,777,216 u16
    u16*   obuf_bf = (u16*)(ws + 45613056);      //  4,194,304 u16
    u16*   x1_bf   = (u16*)(ws + 47710208);      //  4,194,304 u16
    u16*   x2_bf   = (u16*)(ws + 49807360);      //  4,194,304 u16
    u16*   tgt_bf  = (u16*)(ws + 51904512);      //  4,194,304 u16
    u16*   mem_bf  = (u16*)(ws + 54001664);      //  4,194,304 u16
    u16*   dispT   = (u16*)(ws + 56098816);      //    524,288 u16
    u16*   w_sa_in = (u16*)(ws + 56360960);      //  3,145,728 u16
    u16*   w_sa_out= (u16*)(ws + 57933824);      //  1,048,576 u16
    u16*   w_ca_in = (u16*)(ws + 58458112);      //  3,145,728 u16
    u16*   w_ca_out= (u16*)(ws + 60030976);      //  1,048,576 u16
    u16*   w_lin   = (u16*)(ws + 60555264);      //  4,194,304 u16
    u16*   phiT    = (u16*)(ws + 62652416);      //    524,288 u16

    // ---- bf16 conversions (weights + global activations) ----
    cvt_f32_bf16_kernel<<<2048, 256, 0, stream>>>(tgt, tgt_bf);
    cvt_f32_bf16_kernel<<<2048, 256, 0, stream>>>(memry, mem_bf);
    cvt_f32_bf16_kernel<<<1536, 256, 0, stream>>>(sa_in_w, w_sa_in);
    cvt_f32_bf16_kernel<<<512,  256, 0, stream>>>(sa_out_w, w_sa_out);
    cvt_f32_bf16_kernel<<<1536, 256, 0, stream>>>(ca_in_w, w_ca_in);
    cvt_f32_bf16_kernel<<<512,  256, 0, stream>>>(ca_out_w, w_ca_out);
    cvt_f32_bf16_kernel<<<2048, 256, 0, stream>>>(lin_w, w_lin);
    transpose_f32_bf16_kernel<<<dim3(4, 128, 1), 256, 0, stream>>>(phi, phiT, 4096, 128);

    // ---- Self-attention ----
    gemm_bt_mfma<0, 0, 1><<<dim3(24, 32, 1), 256, 0, stream>>>(
        tgt_bf, w_sa_in, sa_in_b, qkv, 1024, 3072, 0, 0, 0);
    attn_kernel<<<dim3(M_ / 8, H_, B_), 256, 0, stream>>>(
        qkv, 3072, qkv + 1024, 3072, qkv + 2048, 3072, obuf_bf, S_);
    gemm_bt_mfma<0, 0, 1><<<dim3(8, 32, 1), 256, 0, stream>>>(
        obuf_bf, w_sa_out, sa_out_b, proj, 1024, 1024, 0, 0, 0);
    resid_ln_kernel<<<4096, 256, 0, stream>>>(tgt, proj, norm1_g, norm1_b, x1, x1_bf);

    // ---- Cross-attention ----
    gemm_bt_mfma<0, 0, 1><<<dim3(8, 32, 1), 256, 0, stream>>>(
        x1_bf, w_ca_in, ca_in_b, qkv, 1024, 1024, 0, 0, 0);
    gemm_bt_mfma<0, 0, 1><<<dim3(16, 32, 1), 256, 0, stream>>>(
        mem_bf, w_ca_in + (size_t)1024 * 1024, ca_in_b + 1024,
        qkv + 4194304, 1024, 2048, 0, 0, 0);
    attn_kernel<<<dim3(M_ / 8, H_, B_), 256, 0, stream>>>(
        qkv, 1024, qkv + 4194304, 2048, qkv + 4194304 + 1024, 2048, obuf_bf, S_);
    gemm_bt_mfma<0, 0, 1><<<dim3(8, 32, 1), 256, 0, stream>>>(
        obuf_bf, w_ca_out, ca_out_b, proj, 1024, 1024, 0, 0, 0);
    resid_ln_kernel<<<4096, 256, 0, stream>>>(x1, proj, norm2_g, norm2_b, x2, x2_bf);

    // ---- FF + SoftMoE ----
    gemm_bt_mfma<1, 1, 1><<<dim3(32, 32, 1), 256, 0, stream>>>(
        x2_bf, w_lin, lin_b, h_bf, 1024, 4096, 0, 0, 0);
    gemm_bt_mfma<0, 0, 0><<<dim3(1, 32, 1), 256, 0, stream>>>(
        h_bf, phiT, nullptr, logits, 4096, 128, 0, 0, 0);
    dispatch_softmax_T_kernel<<<dim3(NE_, B_), 256, 0, stream>>>(logits, dispT);
    combine_softmax_kernel<<<dim3(B_ * M_), 64, 0, stream>>>(logits, comb);
    transpose_bf16_kernel<<<dim3(128, 32, 4), 256, 0, stream>>>(
        h_bf, hT_bf, 1024, 4096, (size_t)M_ * FF_, (size_t)M_ * FF_);
    gemm_bt_mfma<0, 0, 0><<<dim3(32, 1, 4), 256, 0, stream>>>(
        dispT, hT_bf, nullptr, slots, 1024, 4096,
        (size_t)NE_ * M_, (size_t)FF_ * M_, (size_t)NE_ * FF_);
    expert_kernel<<<dim3(NE_, D_ / 256), 256, 0, stream>>>(slots, exp_w, exp_b, ybuf);
    gemm_kn_kernel<<<dim3(16, 16, B_), 256, 0, stream>>>(
        comb, ybuf, proj, 128, 1024,
        (size_t)M_ * NE_, (size_t)NE_ * D_, (size_t)M_ * D_);
    resid_ln_kernel<<<4096, 256, 0, stream>>>(x2, proj, norm3_g, norm3_b,
                                              (float*)d_out, nullptr);
}

// Round 3
// 896.833 us; speedup vs baseline: 4.4540x; 3.0837x over previous
//
#include <hip/hip_runtime.h>
#include <cstdint>
#include <cstddef>

typedef unsigned short u16;
typedef unsigned int   u32;
typedef short bf16x8 __attribute__((ext_vector_type(8)));
typedef float f32x4  __attribute__((ext_vector_type(4)));
typedef u16   u16x8  __attribute__((ext_vector_type(8)));
typedef u16   u16x4  __attribute__((ext_vector_type(4)));
typedef u16   u16x2  __attribute__((ext_vector_type(2)));

constexpr int B_  = 4;
constexpr int M_  = 1024;
constexpr int S_  = 1024;
constexpr int D_  = 1024;
constexpr int H_  = 16;
constexpr int FF_ = 4096;
constexpr int NE_ = 128;

__device__ __forceinline__ u16 f2bf(float f) {
    u32 u = __builtin_bit_cast(u32, f);
    u = (u + 0x7fffu + ((u >> 16) & 1u)) >> 16;   // RNE
    return (u16)u;
}
__device__ __forceinline__ float bf2f(u16 u) {
    u32 x = ((u32)u) << 16;
    return __builtin_bit_cast(float, x);
}
__device__ __forceinline__ void gload_lds16(const u16* g, u16* l) {
    __builtin_amdgcn_global_load_lds(
        (const __attribute__((address_space(1))) u32*)g,
        (__attribute__((address_space(3))) u32*)l, 16, 0, 0);
}

// ---------------------------------------------------------------------------
// bf16 MFMA GEMM (m97 structure): C[r][c] = sum_k A[r][k]*W[c][k] (+bias[c])
// A: rows x K bf16, row stride lda. W: N x K bf16, row stride ldw.
// 128x128 tile, BK=32, 4 waves. sA/sW/sC = per-blockIdx.z strides (elements).
// (sA/sW double as split-K offsets when z indexes K-chunks.)
// ---------------------------------------------------------------------------
template<int OUT_BF16, int RELU, int HAS_BIAS>
__global__ __launch_bounds__(256) void gemm_bt_mfma(
    const u16* __restrict__ A, const u16* __restrict__ W,
    const float* __restrict__ bias, void* __restrict__ Cout,
    int K, int N, int lda, int ldw,
    size_t sA, size_t sW, size_t sC)
{
    __shared__ u16 As[128 * 32];
    __shared__ u16 Bs[128 * 32];
    const int tid = threadIdx.x;
    const int w = tid >> 6, l = tid & 63;
    const int bm = blockIdx.y * 128, bn = blockIdx.x * 128;
    const u16* Ab = A + (size_t)blockIdx.z * sA;
    const u16* Wb = W + (size_t)blockIdx.z * sW;

    const int wr = w >> 1, wc = w & 1;
    const int sr = l >> 2;
    const int sk = (l & 3) * 8;
    const u16* aG0 = Ab + (size_t)(bm + w * 16 + sr) * lda + sk;
    const u16* aG1 = Ab + (size_t)(bm + (w + 4) * 16 + sr) * lda + sk;
    const u16* bG0 = Wb + (size_t)(bn + w * 16 + sr) * ldw + sk;
    const u16* bG1 = Wb + (size_t)(bn + (w + 4) * 16 + sr) * ldw + sk;
    u16* aL0 = &As[w * 512];
    u16* aL1 = &As[(w + 4) * 512];
    u16* bL0 = &Bs[w * 512];
    u16* bL1 = &Bs[(w + 4) * 512];

    const int fr = l & 15;
    const int fk = (l >> 4) * 8;

    f32x4 acc[4][4];
#pragma unroll
    for (int i = 0; i < 4; ++i)
#pragma unroll
        for (int j = 0; j < 4; ++j)
#pragma unroll
            for (int q = 0; q < 4; ++q) acc[i][j][q] = 0.f;

    for (int k0 = 0; k0 < K; k0 += 32) {
        __syncthreads();
        gload_lds16(aG0, aL0);
        gload_lds16(aG1, aL1);
        gload_lds16(bG0, bL0);
        gload_lds16(bG1, bL1);
        aG0 += 32; aG1 += 32; bG0 += 32; bG1 += 32;
        __syncthreads();
        bf16x8 af[4], bfr[4];
#pragma unroll
        for (int m = 0; m < 4; ++m)
            af[m] = *(const bf16x8*)&As[(wr * 64 + m * 16 + fr) * 32 + fk];
#pragma unroll
        for (int n = 0; n < 4; ++n)
            bfr[n] = *(const bf16x8*)&Bs[(wc * 64 + n * 16 + fr) * 32 + fk];
#pragma unroll
        for (int m = 0; m < 4; ++m)
#pragma unroll
            for (int n = 0; n < 4; ++n)
                acc[m][n] = __builtin_amdgcn_mfma_f32_16x16x32_bf16(
                    af[m], bfr[n], acc[m][n], 0, 0, 0);
    }

    const int row0 = bm + wr * 64 + (l >> 4) * 4;
    const int col0 = bn + wc * 64;
#pragma unroll
    for (int n = 0; n < 4; ++n) {
        const int col = col0 + n * 16 + fr;
        float bv = 0.f;
        if (HAS_BIAS) bv = bias[col];
#pragma unroll
        for (int m = 0; m < 4; ++m) {
            const int row = row0 + m * 16;
#pragma unroll
            for (int j = 0; j < 4; ++j) {
                float v = acc[m][n][j] + bv;
                if (RELU) v = fmaxf(v, 0.f);
                const size_t idx = (size_t)blockIdx.z * sC + (size_t)(row + j) * N + col;
                if (OUT_BF16) ((u16*)Cout)[idx] = f2bf(v);
                else          ((float*)Cout)[idx] = v;
            }
        }
    }
}

// ---------------------------------------------------------------------------
// Flash attention fwd. bf16 Q/K/V (head h at col h*64), f32 softmax, bf16 out.
// Block: 256 thr = 4 waves; Q-tile 64 rows (wave w -> rows w*16..+16).
// Grid: (M/64, H, B). KV-blocks of 64 keys.
// S^T = mfma(A=K rows, B=Q rows): lane owns q=l&15, keys (l>>4)*4+j+16*mb.
// PV  = mfma(A=P rows from LDS, B=V^T rows): lane owns q=(l>>4)*4+j, d=nb*16+l&15.
// ---------------------------------------------------------------------------
__global__ __launch_bounds__(256) void flash_attn_kernel(
    const u16* __restrict__ Q, int qs,
    const u16* __restrict__ K, int ks,
    const u16* __restrict__ V, int vs,
    u16* __restrict__ O, int Slen)
{
    __shared__ u16 Qs[64][72];
    __shared__ u16 Ks[64][72];
    __shared__ u16 Vt[64][72];     // V^T: row d, col k
    __shared__ u16 Pw[4][16][72];  // per-wave P: [q_local][k]
    const int b = blockIdx.z, hh = blockIdx.y;
    const int m0 = blockIdx.x * 64;
    const int tid = threadIdx.x;
    const int w = tid >> 6, l = tid & 63;
    const int lq = l & 15, g = l >> 4;

    // ---- stage Q once, scaled by 0.125 (exact for bf16) ----
    {
        const int row = tid >> 2, cg = (tid & 3) * 16;
        const u16* qp = Q + ((size_t)b * M_ + m0 + row) * qs + hh * 64 + cg;
        u16x8 v0 = *(const u16x8*)qp;
        u16x8 v1 = *(const u16x8*)(qp + 8);
        u16x8 o0, o1;
#pragma unroll
        for (int i = 0; i < 8; ++i) {
            o0[i] = f2bf(bf2f(v0[i]) * 0.125f);
            o1[i] = f2bf(bf2f(v1[i]) * 0.125f);
        }
        *(u16x8*)&Qs[row][cg]     = o0;
        *(u16x8*)&Qs[row][cg + 8] = o1;
    }
    __syncthreads();
    bf16x8 qf[2];
    qf[0] = *(const bf16x8*)&Qs[w * 16 + lq][g * 8];
    qf[1] = *(const bf16x8*)&Qs[w * 16 + lq][32 + g * 8];

    f32x4 acc_o[4];
#pragma unroll
    for (int nb = 0; nb < 4; ++nb)
#pragma unroll
        for (int j = 0; j < 4; ++j) acc_o[nb][j] = 0.f;
    float m_run = -1e30f, l_run = 0.f;

    const int kp = tid & 31, dg = tid >> 5;      // V staging: k=2kp,2kp+1; d=dg*8..+8
    const int krow = tid >> 2, kcg = (tid & 3) * 16;  // K staging

    for (int s0 = 0; s0 < Slen; s0 += 64) {
        __syncthreads();
        {   // K tile [64][72]
            const u16* kpp = K + ((size_t)b * Slen + s0 + krow) * ks + hh * 64 + kcg;
            *(u16x8*)&Ks[krow][kcg]     = *(const u16x8*)kpp;
            *(u16x8*)&Ks[krow][kcg + 8] = *(const u16x8*)(kpp + 8);
        }
        {   // V^T tile: pack two k-rows per u16x2 write (2-way banks, free)
            const u16* vp0 = V + ((size_t)b * Slen + s0 + 2 * kp) * vs + hh * 64 + dg * 8;
            const u16* vp1 = vp0 + vs;
            u16x8 a = *(const u16x8*)vp0;
            u16x8 c = *(const u16x8*)vp1;
#pragma unroll
            for (int i = 0; i < 8; ++i) {
                u16x2 pk; pk[0] = a[i]; pk[1] = c[i];
                *(u16x2*)&Vt[dg * 8 + i][2 * kp] = pk;
            }
        }
        __syncthreads();

        // S^T
        f32x4 s4[4];
#pragma unroll
        for (int mb = 0; mb < 4; ++mb) {
            f32x4 z = {0.f, 0.f, 0.f, 0.f};
            bf16x8 a0 = *(const bf16x8*)&Ks[mb * 16 + lq][g * 8];
            bf16x8 a1 = *(const bf16x8*)&Ks[mb * 16 + lq][32 + g * 8];
            z = __builtin_amdgcn_mfma_f32_16x16x32_bf16(a0, qf[0], z, 0, 0, 0);
            z = __builtin_amdgcn_mfma_f32_16x16x32_bf16(a1, qf[1], z, 0, 0, 0);
            s4[mb] = z;
        }

        // online softmax for q = lq (4 replica lanes agree after xor 16/32)
        float pm = -1e30f;
#pragma unroll
        for (int mb = 0; mb < 4; ++mb)
#pragma unroll
            for (int j = 0; j < 4; ++j) pm = fmaxf(pm, s4[mb][j]);
        pm = fmaxf(pm, __shfl_xor(pm, 16));
        pm = fmaxf(pm, __shfl_xor(pm, 32));
        const float m_new = fmaxf(m_run, pm);
        const float alpha = __expf(m_run - m_new);
        float ls = 0.f;
        u16 pbf[4][4];
#pragma unroll
        for (int mb = 0; mb < 4; ++mb)
#pragma unroll
            for (int j = 0; j < 4; ++j) {
                float p = __expf(s4[mb][j] - m_new);
                ls += p;
                pbf[mb][j] = f2bf(p);
            }
        ls += __shfl_xor(ls, 16);
        ls += __shfl_xor(ls, 32);
        l_run = l_run * alpha + ls;
        m_run = m_new;

        // P -> LDS (keys mb*16+4g..+4 are j-consecutive -> b64 write)
#pragma unroll
        for (int mb = 0; mb < 4; ++mb) {
            u16x4 pk;
            pk[0] = pbf[mb][0]; pk[1] = pbf[mb][1];
            pk[2] = pbf[mb][2]; pk[3] = pbf[mb][3];
            *(u16x4*)&Pw[w][lq][mb * 16 + g * 4] = pk;
        }

        // rescale O (its rows are q=4g+j; fetch alpha from lane 4g+j)
        float al[4];
#pragma unroll
        for (int j = 0; j < 4; ++j) al[j] = __shfl(alpha, 4 * g + j);
#pragma unroll
        for (int nb = 0; nb < 4; ++nb)
#pragma unroll
            for (int j = 0; j < 4; ++j) acc_o[nb][j] *= al[j];

        // PV
#pragma unroll
        for (int kc = 0; kc < 2; ++kc) {
            bf16x8 pa = *(const bf16x8*)&Pw[w][lq][kc * 32 + g * 8];
#pragma unroll
            for (int nb = 0; nb < 4; ++nb) {
                bf16x8 bv = *(const bf16x8*)&Vt[nb * 16 + lq][kc * 32 + g * 8];
                acc_o[nb] = __builtin_amdgcn_mfma_f32_16x16x32_bf16(pa, bv, acc_o[nb], 0, 0, 0);
            }
        }
    }

    // epilogue: divide by row-sum, write bf16
    float linv[4];
#pragma unroll
    for (int j = 0; j < 4; ++j) linv[j] = 1.f / __shfl(l_run, 4 * g + j);
#pragma unroll
    for (int nb = 0; nb < 4; ++nb)
#pragma unroll
        for (int j = 0; j < 4; ++j) {
            const size_t row = (size_t)b * M_ + m0 + w * 16 + 4 * g + j;
            O[row * D_ + hh * 64 + nb * 16 + lq] = f2bf(acc_o[nb][j] * linv[j]);
        }
}

// ---------------------------------------------------------------------------
// f32 -> bf16 convert. n multiple of 2048.
// ---------------------------------------------------------------------------
__global__ __launch_bounds__(256) void cvt_f32_bf16_kernel(
    const float* __restrict__ src, u16* __restrict__ dst)
{
    const size_t i = ((size_t)blockIdx.x * 256 + threadIdx.x) * 8;
    float4 a = *(const float4*)(src + i);
    float4 b = *(const float4*)(src + i + 4);
    u16x8 o;
    o[0] = f2bf(a.x); o[1] = f2bf(a.y); o[2] = f2bf(a.z); o[3] = f2bf(a.w);
    o[4] = f2bf(b.x); o[5] = f2bf(b.y); o[6] = f2bf(b.z); o[7] = f2bf(b.w);
    *(u16x8*)(dst + i) = o;
}

// ---------------------------------------------------------------------------
// Transpose (R x C) f32 -> (C x R) bf16, batched over z.
// ---------------------------------------------------------------------------
__global__ __launch_bounds__(256) void transpose_f32_bf16_kernel(
    const float* __restrict__ src, u16* __restrict__ dst, int R, int C,
    size_t sI, size_t sO)
{
    __shared__ u16 t[32][33];
    src += (size_t)blockIdx.z * sI;
    dst += (size_t)blockIdx.z * sO;
    const int c0 = blockIdx.x * 32, r0 = blockIdx.y * 32;
    const int x = threadIdx.x & 31, y = threadIdx.x >> 5;
    for (int i = y; i < 32; i += 8)
        t[i][x] = f2bf(src[(size_t)(r0 + i) * C + c0 + x]);
    __syncthreads();
    for (int i = y; i < 32; i += 8)
        dst[(size_t)(c0 + i) * R + r0 + x] = t[x][i];
}

__global__ __launch_bounds__(256) void transpose_bf16_kernel(
    const u16* __restrict__ src, u16* __restrict__ dst, int R, int C,
    size_t sI, size_t sO)
{
    __shared__ u16 t[32][33];
    src += (size_t)blockIdx.z * sI;
    dst += (size_t)blockIdx.z * sO;
    const int c0 = blockIdx.x * 32, r0 = blockIdx.y * 32;
    const int x = threadIdx.x & 31, y = threadIdx.x >> 5;
    for (int i = y; i < 32; i += 8)
        t[i][x] = src[(size_t)(r0 + i) * C + c0 + x];
    __syncthreads();
    for (int i = y; i < 32; i += 8)
        dst[(size_t)(c0 + i) * R + r0 + x] = t[x][i];
}

// ---------------------------------------------------------------------------
// y = LayerNorm(X + R); writes f32 Y and (optionally) bf16 Ybf.
// ---------------------------------------------------------------------------
__global__ __launch_bounds__(256) void resid_ln_kernel(
    const float* __restrict__ X, const float* __restrict__ R,
    const float* __restrict__ g, const float* __restrict__ bt,
    float* __restrict__ Y, u16* __restrict__ Ybf)
{
    __shared__ float s1[4], s2[4];
    const size_t row = blockIdx.x;
    const int tid = threadIdx.x;
    const float4 x4 = *(const float4*)(X + row * 1024 + tid * 4);
    const float4 r4 = *(const float4*)(R + row * 1024 + tid * 4);
    float v[4] = {x4.x + r4.x, x4.y + r4.y, x4.z + r4.z, x4.w + r4.w};
    float s = v[0] + v[1] + v[2] + v[3];
    float q = v[0] * v[0] + v[1] * v[1] + v[2] * v[2] + v[3] * v[3];
#pragma unroll
    for (int off = 32; off; off >>= 1) {
        s += __shfl_xor(s, off);
        q += __shfl_xor(q, off);
    }
    if ((tid & 63) == 0) { s1[tid >> 6] = s; s2[tid >> 6] = q; }
    __syncthreads();
    s = s1[0] + s1[1] + s1[2] + s1[3];
    q = s2[0] + s2[1] + s2[2] + s2[3];
    const float mu = s * (1.f / 1024.f);
    const float var = q * (1.f / 1024.f) - mu * mu;
    const float rinv = rsqrtf(var + 1e-5f);
    const float4 g4 = *(const float4*)(g + tid * 4);
    const float4 b4 = *(const float4*)(bt + tid * 4);
    float o[4];
    o[0] = (v[0] - mu) * rinv * g4.x + b4.x;
    o[1] = (v[1] - mu) * rinv * g4.y + b4.y;
    o[2] = (v[2] - mu) * rinv * g4.z + b4.z;
    o[3] = (v[3] - mu) * rinv * g4.w + b4.w;
    *(float4*)(Y + row * 1024 + tid * 4) = *(float4*)o;
    if (Ybf) {
        u16x4 ob;
        ob[0] = f2bf(o[0]); ob[1] = f2bf(o[1]);
        ob[2] = f2bf(o[2]); ob[3] = f2bf(o[3]);
        *(u16x4*)(Ybf + row * 1024 + tid * 4) = ob;
    }
}

// ---------------------------------------------------------------------------
// dispatch softmax over m (sums 4 split-K partials), bf16 transposed out.
// ---------------------------------------------------------------------------
__global__ __launch_bounds__(256) void dispatch_softmax_T_kernel(
    const float* __restrict__ logitsP, u16* __restrict__ dispT)
{
    __shared__ float red[4];
    constexpr size_t CH = (size_t)B_ * M_ * NE_;
    const int n = blockIdx.x, b = blockIdx.y;
    u16* O = dispT + ((size_t)b * NE_ + n) * M_;
    const int tid = threadIdx.x;
    float v[4];
#pragma unroll
    for (int i = 0; i < 4; ++i) {
        const size_t idx = (size_t)(b * M_ + tid + 256 * i) * NE_ + n;
        v[i] = logitsP[idx] + logitsP[CH + idx] + logitsP[2 * CH + idx] + logitsP[3 * CH + idx];
    }
    float mx = fmaxf(fmaxf(v[0], v[1]), fmaxf(v[2], v[3]));
#pragma unroll
    for (int off = 32; off; off >>= 1) mx = fmaxf(mx, __shfl_xor(mx, off));
    if ((tid & 63) == 0) red[tid >> 6] = mx;
    __syncthreads();
    mx = fmaxf(fmaxf(red[0], red[1]), fmaxf(red[2], red[3]));
    __syncthreads();
    float e[4], s = 0.f;
#pragma unroll
    for (int i = 0; i < 4; ++i) { e[i] = __expf(v[i] - mx); s += e[i]; }
#pragma unroll
    for (int off = 32; off; off >>= 1) s += __shfl_xor(s, off);
    if ((tid & 63) == 0) red[tid >> 6] = s;
    __syncthreads();
    s = red[0] + red[1] + red[2] + red[3];
    const float inv = 1.f / s;
#pragma unroll
    for (int i = 0; i < 4; ++i) O[tid + 256 * i] = f2bf(e[i] * inv);
}

// ---------------------------------------------------------------------------
// combine softmax over 128 experts (sums partials), bf16 out. Grid B*M, 64 thr.
// ---------------------------------------------------------------------------
__global__ __launch_bounds__(64) void combine_softmax_kernel(
    const float* __restrict__ logitsP, u16* __restrict__ comb)
{
    constexpr size_t CH = (size_t)B_ * M_ * NE_;
    const size_t row = blockIdx.x;
    const int lane = threadIdx.x;
    const size_t i0 = row * NE_ + lane;
    const size_t i1 = i0 + 64;
    float a = logitsP[i0] + logitsP[CH + i0] + logitsP[2 * CH + i0] + logitsP[3 * CH + i0];
    float c = logitsP[i1] + logitsP[CH + i1] + logitsP[2 * CH + i1] + logitsP[3 * CH + i1];
    float mx = fmaxf(a, c);
#pragma unroll
    for (int off = 32; off; off >>= 1) mx = fmaxf(mx, __shfl_xor(mx, off));
    float e0 = __expf(a - mx), e1 = __expf(c - mx);
    float s = e0 + e1;
#pragma unroll
    for (int off = 32; off; off >>= 1) s += __shfl_xor(s, off);
    const float inv = 1.f / s;
    comb[row * NE_ + lane]      = f2bf(e0 * inv);
    comb[row * NE_ + lane + 64] = f2bf(e1 * inv);
}

// ---------------------------------------------------------------------------
// y[b][n][d] = sum_f slots[b][n][f] * exp_w[n][f][d] + exp_b[n][d]
// Memory-bound: reads exp_w (2.15 GB f32) exactly once, coalesced.
// ---------------------------------------------------------------------------
__global__ __launch_bounds__(256) void expert_kernel(
    const float* __restrict__ slots, const float* __restrict__ exp_w,
    const float* __restrict__ exp_b, float* __restrict__ y)
{
    __shared__ float sl[4][128];
    const int n = blockIdx.x;
    const int d = blockIdx.y * 256 + threadIdx.x;
    float acc0 = 0.f, acc1 = 0.f, acc2 = 0.f, acc3 = 0.f;
    const float eb = exp_b[(size_t)n * D_ + d];
    const float* wbase = exp_w + (size_t)n * FF_ * D_ + d;
    for (int f0 = 0; f0 < FF_; f0 += 128) {
        __syncthreads();
        const int t = threadIdx.x;
        sl[t >> 7][t & 127] =
            slots[((size_t)(t >> 7) * NE_ + n) * FF_ + f0 + (t & 127)];
        sl[(t >> 7) + 2][t & 127] =
            slots[((size_t)((t >> 7) + 2) * NE_ + n) * FF_ + f0 + (t & 127)];
        __syncthreads();
        const float* wp = wbase + (size_t)f0 * D_;
#pragma unroll 8
        for (int f = 0; f < 128; ++f) {
            float w = wp[(size_t)f * D_];
            acc0 = fmaf(sl[0][f], w, acc0);
            acc1 = fmaf(sl[1][f], w, acc1);
            acc2 = fmaf(sl[2][f], w, acc2);
            acc3 = fmaf(sl[3][f], w, acc3);
        }
    }
    y[((size_t)0 * NE_ + n) * D_ + d] = acc0 + eb;
    y[((size_t)1 * NE_ + n) * D_ + d] = acc1 + eb;
    y[((size_t)2 * NE_ + n) * D_ + d] = acc2 + eb;
    y[((size_t)3 * NE_ + n) * D_ + d] = acc3 + eb;
}

// ---------------------------------------------------------------------------
extern "C" void kernel_launch(void* const* d_in, const int* in_sizes, int n_in,
                              void* d_out, int out_size, void* d_ws, size_t ws_size,
                              hipStream_t stream)
{
    const float* tgt      = (const float*)d_in[0];
    const float* memry    = (const float*)d_in[1];
    const float* sa_in_w  = (const float*)d_in[2];
    const float* sa_in_b  = (const float*)d_in[3];
    const float* sa_out_w = (const float*)d_in[4];
    const float* sa_out_b = (const float*)d_in[5];
    const float* ca_in_w  = (const float*)d_in[6];
    const float* ca_in_b  = (const float*)d_in[7];
    const float* ca_out_w = (const float*)d_in[8];
    const float* ca_out_b = (const float*)d_in[9];
    const float* norm1_g  = (const float*)d_in[10];
    const float* norm1_b  = (const float*)d_in[11];
    const float* norm2_g  = (const float*)d_in[12];
    const float* norm2_b  = (const float*)d_in[13];
    const float* norm3_g  = (const float*)d_in[14];
    const float* norm3_b  = (const float*)d_in[15];
    const float* lin_w    = (const float*)d_in[16];
    const float* lin_b    = (const float*)d_in[17];
    const float* phi      = (const float*)d_in[18];
    const float* exp_w    = (const float*)d_in[19];
    const float* exp_b    = (const float*)d_in[20];

    float* ws = (float*)d_ws;
    // float-unit offsets, ~233 MB total, no aliasing except qkv_bf reuse for CA.
    u16*   qkv_bf  = (u16*)(ws);                 // [4096][3072] u16 (CA: q[.][1024] then kv at +4096*1024)
    float* proj    = ws + 6291456;               // 4,194,304
    float* x1      = ws + 10485760;              // 4,194,304
    float* x2      = ws + 14680064;              // 4,194,304
    float* logitsP = ws + 18874368;              // 4 x 524,288
    float* slots   = ws + 20971520;              // 2,097,152
    float* ybuf    = ws + 23068672;              // 524,288
    u16*   h_bf    = (u16*)(ws + 23592960);      // [4096][4096]
    u16*   hT_bf   = (u16*)(ws + 31981568);      // [4][4096][1024]
    u16*   obuf_bf = (u16*)(ws + 40370176);      // [4096][1024]
    u16*   x1_bf   = (u16*)(ws + 42467328);
    u16*   x2_bf   = (u16*)(ws + 44564480);
    u16*   tgt_bf  = (u16*)(ws + 46661632);
    u16*   mem_bf  = (u16*)(ws + 48758784);
    u16*   dispT   = (u16*)(ws + 50855936);      // [4][128][1024]
    u16*   comb_bf = (u16*)(ws + 51118080);      // [4096][128]
    u16*   yT_bf   = (u16*)(ws + 51380224);      // [4][1024][128]
    u16*   w_sa_in = (u16*)(ws + 51642368);
    u16*   w_sa_out= (u16*)(ws + 53215232);
    u16*   w_ca_in = (u16*)(ws + 53739520);
    u16*   w_ca_out= (u16*)(ws + 55312384);
    u16*   w_lin   = (u16*)(ws + 55836672);
    u16*   phiT    = (u16*)(ws + 57933824);

    // ---- bf16 conversions ----
    cvt_f32_bf16_kernel<<<2048, 256, 0, stream>>>(tgt, tgt_bf);
    cvt_f32_bf16_kernel<<<2048, 256, 0, stream>>>(memry, mem_bf);
    cvt_f32_bf16_kernel<<<1536, 256, 0, stream>>>(sa_in_w, w_sa_in);
    cvt_f32_bf16_kernel<<<512,  256, 0, stream>>>(sa_out_w, w_sa_out);
    cvt_f32_bf16_kernel<<<1536, 256, 0, stream>>>(ca_in_w, w_ca_in);
    cvt_f32_bf16_kernel<<<512,  256, 0, stream>>>(ca_out_w, w_ca_out);
    cvt_f32_bf16_kernel<<<2048, 256, 0, stream>>>(lin_w, w_lin);
    transpose_f32_bf16_kernel<<<dim3(4, 128, 1), 256, 0, stream>>>(phi, phiT, 4096, 128, 0, 0);

    // ---- Self-attention ----
    gemm_bt_mfma<1, 0, 1><<<dim3(24, 32, 1), 256, 0, stream>>>(
        tgt_bf, w_sa_in, sa_in_b, qkv_bf, 1024, 3072, 1024, 1024, 0, 0, 0);
    flash_attn_kernel<<<dim3(16, 16, 4), 256, 0, stream>>>(
        qkv_bf, 3072, qkv_bf + 1024, 3072, qkv_bf + 2048, 3072, obuf_bf, S_);
    gemm_bt_mfma<0, 0, 1><<<dim3(8, 32, 1), 256, 0, stream>>>(
        obuf_bf, w_sa_out, sa_out_b, proj, 1024, 1024, 1024, 1024, 0, 0, 0);
    resid_ln_kernel<<<4096, 256, 0, stream>>>(tgt, proj, norm1_g, norm1_b, x1, x1_bf);

    // ---- Cross-attention ----
    u16* qca_bf = qkv_bf;                          // [4096][1024]
    u16* kvca_bf = qkv_bf + (size_t)4096 * 1024;   // [4096][2048]
    gemm_bt_mfma<1, 0, 1><<<dim3(8, 32, 1), 256, 0, stream>>>(
        x1_bf, w_ca_in, ca_in_b, qca_bf, 1024, 1024, 1024, 1024, 0, 0, 0);
    gemm_bt_mfma<1, 0, 1><<<dim3(16, 32, 1), 256, 0, stream>>>(
        mem_bf, w_ca_in + (size_t)1024 * 1024, ca_in_b + 1024,
        kvca_bf, 1024, 2048, 1024, 1024, 0, 0, 0);
    flash_attn_kernel<<<dim3(16, 16, 4), 256, 0, stream>>>(
        qca_bf, 1024, kvca_bf, 2048, kvca_bf + 1024, 2048, obuf_bf, S_);
    gemm_bt_mfma<0, 0, 1><<<dim3(8, 32, 1), 256, 0, stream>>>(
        obuf_bf, w_ca_out, ca_out_b, proj, 1024, 1024, 1024, 1024, 0, 0, 0);
    resid_ln_kernel<<<4096, 256, 0, stream>>>(x1, proj, norm2_g, norm2_b, x2, x2_bf);

    // ---- FF + SoftMoE ----
    gemm_bt_mfma<1, 1, 1><<<dim3(32, 32, 1), 256, 0, stream>>>(
        x2_bf, w_lin, lin_b, h_bf, 1024, 4096, 1024, 1024, 0, 0, 0);
    // logits: split-K x4 (z = K-chunk), partials to logitsP[z]
    gemm_bt_mfma<0, 0, 0><<<dim3(1, 32, 4), 256, 0, stream>>>(
        h_bf, phiT, nullptr, logitsP, 1024, 128, 4096, 4096,
        1024, 1024, (size_t)B_ * M_ * NE_);
    dispatch_softmax_T_kernel<<<dim3(NE_, B_), 256, 0, stream>>>(logitsP, dispT);
    combine_softmax_kernel<<<dim3(B_ * M_), 64, 0, stream>>>(logitsP, comb_bf);
    transpose_bf16_kernel<<<dim3(128, 32, 4), 256, 0, stream>>>(
        h_bf, hT_bf, 1024, 4096, (size_t)M_ * FF_, (size_t)M_ * FF_);
    gemm_bt_mfma<0, 0, 0><<<dim3(32, 1, 4), 256, 0, stream>>>(
        dispT, hT_bf, nullptr, slots, 1024, 4096, 1024, 1024,
        (size_t)NE_ * M_, (size_t)FF_ * M_, (size_t)NE_ * FF_);
    expert_kernel<<<dim3(NE_, D_ / 256), 256, 0, stream>>>(slots, exp_w, exp_b, ybuf);
    transpose_f32_bf16_kernel<<<dim3(32, 4, 4), 256, 0, stream>>>(
        ybuf, yT_bf, 128, 1024, (size_t)NE_ * D_, (size_t)NE_ * D_);
    // ff_out = combine @ y : MFMA, batched over B
    gemm_bt_mfma<0, 0, 0><<<dim3(8, 8, 4), 256, 0, stream>>>(
        comb_bf, yT_bf, nullptr, proj, 128, 1024, 128, 128,
        (size_t)M_ * NE_, (size_t)D_ * NE_, (size_t)M_ * D_);
    resid_ln_kernel<<<4096, 256, 0, stream>>>(x2, proj, norm3_g, norm3_b,
                                              (float*)d_out, nullptr);
}

// Round 4
// 839.002 us; speedup vs baseline: 4.7610x; 1.0689x over previous
//
#include <hip/hip_runtime.h>
#include <cstdint>
#include <cstddef>

typedef unsigned short u16;
typedef unsigned int   u32;
typedef short bf16x8 __attribute__((ext_vector_type(8)));
typedef float f32x4  __attribute__((ext_vector_type(4)));
typedef u16   u16x8  __attribute__((ext_vector_type(8)));
typedef u16   u16x4  __attribute__((ext_vector_type(4)));
typedef u16   u16x2  __attribute__((ext_vector_type(2)));

constexpr int B_  = 4;
constexpr int M_  = 1024;
constexpr int S_  = 1024;
constexpr int D_  = 1024;
constexpr int H_  = 16;
constexpr int FF_ = 4096;
constexpr int NE_ = 128;

__device__ __forceinline__ u16 f2bf(float f) {
    u32 u = __builtin_bit_cast(u32, f);
    u = (u + 0x7fffu + ((u >> 16) & 1u)) >> 16;   // RNE
    return (u16)u;
}
__device__ __forceinline__ float bf2f(u16 u) {
    u32 x = ((u32)u) << 16;
    return __builtin_bit_cast(float, x);
}
__device__ __forceinline__ void gload_lds16(const u16* g, u16* l) {
    __builtin_amdgcn_global_load_lds(
        (const __attribute__((address_space(1))) u32*)g,
        (__attribute__((address_space(3))) u32*)l, 16, 0, 0);
}

// ---------------------------------------------------------------------------
// bf16 MFMA GEMM (m97 structure): C[r][c] = sum_k A[r][k]*W[c][k] (+bias[c])
// ---------------------------------------------------------------------------
template<int OUT_BF16, int RELU, int HAS_BIAS>
__global__ __launch_bounds__(256) void gemm_bt_mfma(
    const u16* __restrict__ A, const u16* __restrict__ W,
    const float* __restrict__ bias, void* __restrict__ Cout,
    int K, int N, int lda, int ldw,
    size_t sA, size_t sW, size_t sC)
{
    __shared__ u16 As[128 * 32];
    __shared__ u16 Bs[128 * 32];
    const int tid = threadIdx.x;
    const int w = tid >> 6, l = tid & 63;
    const int bm = blockIdx.y * 128, bn = blockIdx.x * 128;
    const u16* Ab = A + (size_t)blockIdx.z * sA;
    const u16* Wb = W + (size_t)blockIdx.z * sW;

    const int wr = w >> 1, wc = w & 1;
    const int sr = l >> 2;
    const int sk = (l & 3) * 8;
    const u16* aG0 = Ab + (size_t)(bm + w * 16 + sr) * lda + sk;
    const u16* aG1 = Ab + (size_t)(bm + (w + 4) * 16 + sr) * lda + sk;
    const u16* bG0 = Wb + (size_t)(bn + w * 16 + sr) * ldw + sk;
    const u16* bG1 = Wb + (size_t)(bn + (w + 4) * 16 + sr) * ldw + sk;
    u16* aL0 = &As[w * 512];
    u16* aL1 = &As[(w + 4) * 512];
    u16* bL0 = &Bs[w * 512];
    u16* bL1 = &Bs[(w + 4) * 512];

    const int fr = l & 15;
    const int fk = (l >> 4) * 8;

    f32x4 acc[4][4];
#pragma unroll
    for (int i = 0; i < 4; ++i)
#pragma unroll
        for (int j = 0; j < 4; ++j)
#pragma unroll
            for (int q = 0; q < 4; ++q) acc[i][j][q] = 0.f;

    for (int k0 = 0; k0 < K; k0 += 32) {
        __syncthreads();
        gload_lds16(aG0, aL0);
        gload_lds16(aG1, aL1);
        gload_lds16(bG0, bL0);
        gload_lds16(bG1, bL1);
        aG0 += 32; aG1 += 32; bG0 += 32; bG1 += 32;
        __syncthreads();
        bf16x8 af[4], bfr[4];
#pragma unroll
        for (int m = 0; m < 4; ++m)
            af[m] = *(const bf16x8*)&As[(wr * 64 + m * 16 + fr) * 32 + fk];
#pragma unroll
        for (int n = 0; n < 4; ++n)
            bfr[n] = *(const bf16x8*)&Bs[(wc * 64 + n * 16 + fr) * 32 + fk];
#pragma unroll
        for (int m = 0; m < 4; ++m)
#pragma unroll
            for (int n = 0; n < 4; ++n)
                acc[m][n] = __builtin_amdgcn_mfma_f32_16x16x32_bf16(
                    af[m], bfr[n], acc[m][n], 0, 0, 0);
    }

    const int row0 = bm + wr * 64 + (l >> 4) * 4;
    const int col0 = bn + wc * 64;
#pragma unroll
    for (int n = 0; n < 4; ++n) {
        const int col = col0 + n * 16 + fr;
        float bv = 0.f;
        if (HAS_BIAS) bv = bias[col];
#pragma unroll
        for (int m = 0; m < 4; ++m) {
            const int row = row0 + m * 16;
#pragma unroll
            for (int j = 0; j < 4; ++j) {
                float v = acc[m][n][j] + bv;
                if (RELU) v = fmaxf(v, 0.f);
                const size_t idx = (size_t)blockIdx.z * sC + (size_t)(row + j) * N + col;
                if (OUT_BF16) ((u16*)Cout)[idx] = f2bf(v);
                else          ((float*)Cout)[idx] = v;
            }
        }
    }
}

// ---------------------------------------------------------------------------
// Flash attention fwd with defer-max (THR=8). bf16 in/out, f32 softmax state.
// ---------------------------------------------------------------------------
__global__ __launch_bounds__(256) void flash_attn_kernel(
    const u16* __restrict__ Q, int qs,
    const u16* __restrict__ K, int ks,
    const u16* __restrict__ V, int vs,
    u16* __restrict__ O, int Slen)
{
    __shared__ u16 Qs[64][72];
    __shared__ u16 Ks[64][72];
    __shared__ u16 Vt[64][72];
    __shared__ u16 Pw[4][16][72];
    const int b = blockIdx.z, hh = blockIdx.y;
    const int m0 = blockIdx.x * 64;
    const int tid = threadIdx.x;
    const int w = tid >> 6, l = tid & 63;
    const int lq = l & 15, g = l >> 4;

    {
        const int row = tid >> 2, cg = (tid & 3) * 16;
        const u16* qp = Q + ((size_t)b * M_ + m0 + row) * qs + hh * 64 + cg;
        u16x8 v0 = *(const u16x8*)qp;
        u16x8 v1 = *(const u16x8*)(qp + 8);
        u16x8 o0, o1;
#pragma unroll
        for (int i = 0; i < 8; ++i) {
            o0[i] = f2bf(bf2f(v0[i]) * 0.125f);
            o1[i] = f2bf(bf2f(v1[i]) * 0.125f);
        }
        *(u16x8*)&Qs[row][cg]     = o0;
        *(u16x8*)&Qs[row][cg + 8] = o1;
    }
    __syncthreads();
    bf16x8 qf[2];
    qf[0] = *(const bf16x8*)&Qs[w * 16 + lq][g * 8];
    qf[1] = *(const bf16x8*)&Qs[w * 16 + lq][32 + g * 8];

    f32x4 acc_o[4];
#pragma unroll
    for (int nb = 0; nb < 4; ++nb)
#pragma unroll
        for (int j = 0; j < 4; ++j) acc_o[nb][j] = 0.f;
    float m_run = -1e30f, l_run = 0.f;

    const int kp = tid & 31, dg = tid >> 5;
    const int krow = tid >> 2, kcg = (tid & 3) * 16;

    for (int s0 = 0; s0 < Slen; s0 += 64) {
        __syncthreads();
        {   // K tile
            const u16* kpp = K + ((size_t)b * Slen + s0 + krow) * ks + hh * 64 + kcg;
            *(u16x8*)&Ks[krow][kcg]     = *(const u16x8*)kpp;
            *(u16x8*)&Ks[krow][kcg + 8] = *(const u16x8*)(kpp + 8);
        }
        {   // V^T tile (paired u16x2 writes: 2-way banks, free)
            const u16* vp0 = V + ((size_t)b * Slen + s0 + 2 * kp) * vs + hh * 64 + dg * 8;
            const u16* vp1 = vp0 + vs;
            u16x8 a = *(const u16x8*)vp0;
            u16x8 c = *(const u16x8*)vp1;
#pragma unroll
            for (int i = 0; i < 8; ++i) {
                u16x2 pk; pk[0] = a[i]; pk[1] = c[i];
                *(u16x2*)&Vt[dg * 8 + i][2 * kp] = pk;
            }
        }
        __syncthreads();

        // S^T = K @ Q^T
        f32x4 s4[4];
#pragma unroll
        for (int mb = 0; mb < 4; ++mb) {
            f32x4 z = {0.f, 0.f, 0.f, 0.f};
            bf16x8 a0 = *(const bf16x8*)&Ks[mb * 16 + lq][g * 8];
            bf16x8 a1 = *(const bf16x8*)&Ks[mb * 16 + lq][32 + g * 8];
            z = __builtin_amdgcn_mfma_f32_16x16x32_bf16(a0, qf[0], z, 0, 0, 0);
            z = __builtin_amdgcn_mfma_f32_16x16x32_bf16(a1, qf[1], z, 0, 0, 0);
            s4[mb] = z;
        }

        // online softmax with defer-max (T13): skip rescale if max grew < 8
        float pm = -1e30f;
#pragma unroll
        for (int mb = 0; mb < 4; ++mb)
#pragma unroll
            for (int j = 0; j < 4; ++j) pm = fmaxf(pm, s4[mb][j]);
        pm = fmaxf(pm, __shfl_xor(pm, 16));
        pm = fmaxf(pm, __shfl_xor(pm, 32));

        u16 pbf[4][4];
        float ls = 0.f;
        if (__all(pm - m_run <= 8.f)) {
            // deferred: keep m_run, P bounded by e^8
#pragma unroll
            for (int mb = 0; mb < 4; ++mb)
#pragma unroll
                for (int j = 0; j < 4; ++j) {
                    float p = __expf(s4[mb][j] - m_run);
                    ls += p;
                    pbf[mb][j] = f2bf(p);
                }
            ls += __shfl_xor(ls, 16);
            ls += __shfl_xor(ls, 32);
            l_run += ls;
        } else {
            const float m_new = fmaxf(m_run, pm);
            const float alpha = __expf(m_run - m_new);
#pragma unroll
            for (int mb = 0; mb < 4; ++mb)
#pragma unroll
                for (int j = 0; j < 4; ++j) {
                    float p = __expf(s4[mb][j] - m_new);
                    ls += p;
                    pbf[mb][j] = f2bf(p);
                }
            ls += __shfl_xor(ls, 16);
            ls += __shfl_xor(ls, 32);
            l_run = l_run * alpha + ls;
            m_run = m_new;
            float al[4];
#pragma unroll
            for (int j = 0; j < 4; ++j) al[j] = __shfl(alpha, 4 * g + j);
#pragma unroll
            for (int nb = 0; nb < 4; ++nb)
#pragma unroll
                for (int j = 0; j < 4; ++j) acc_o[nb][j] *= al[j];
        }

        // P -> per-wave LDS
#pragma unroll
        for (int mb = 0; mb < 4; ++mb) {
            u16x4 pk;
            pk[0] = pbf[mb][0]; pk[1] = pbf[mb][1];
            pk[2] = pbf[mb][2]; pk[3] = pbf[mb][3];
            *(u16x4*)&Pw[w][lq][mb * 16 + g * 4] = pk;
        }

        // PV
#pragma unroll
        for (int kc = 0; kc < 2; ++kc) {
            bf16x8 pa = *(const bf16x8*)&Pw[w][lq][kc * 32 + g * 8];
#pragma unroll
            for (int nb = 0; nb < 4; ++nb) {
                bf16x8 bv = *(const bf16x8*)&Vt[nb * 16 + lq][kc * 32 + g * 8];
                acc_o[nb] = __builtin_amdgcn_mfma_f32_16x16x32_bf16(pa, bv, acc_o[nb], 0, 0, 0);
            }
        }
    }

    float linv[4];
#pragma unroll
    for (int j = 0; j < 4; ++j) linv[j] = 1.f / __shfl(l_run, 4 * g + j);
#pragma unroll
    for (int nb = 0; nb < 4; ++nb)
#pragma unroll
        for (int j = 0; j < 4; ++j) {
            const size_t row = (size_t)b * M_ + m0 + w * 16 + 4 * g + j;
            O[row * D_ + hh * 64 + nb * 16 + lq] = f2bf(acc_o[nb][j] * linv[j]);
        }
}

// ---------------------------------------------------------------------------
// One-shot f32->bf16 for all 7 tensors (compile-time segment table).
// Each block converts 2048 elements.
// ---------------------------------------------------------------------------
__global__ __launch_bounds__(256) void cvt_multi_kernel(
    const float* __restrict__ s0, u16* __restrict__ d0,   // tgt      2048 blk
    const float* __restrict__ s1, u16* __restrict__ d1,   // memory   2048
    const float* __restrict__ s2, u16* __restrict__ d2,   // sa_in_w  1536
    const float* __restrict__ s3, u16* __restrict__ d3,   // sa_out_w  512
    const float* __restrict__ s4, u16* __restrict__ d4,   // ca_in_w  1536
    const float* __restrict__ s5, u16* __restrict__ d5,   // ca_out_w  512
    const float* __restrict__ s6, u16* __restrict__ d6)   // lin_w    2048
{
    int blk = blockIdx.x;
    const float* s; u16* d;
    if      (blk < 2048) { s = s0; d = d0; }
    else if (blk < 4096) { s = s1; d = d1; blk -= 2048; }
    else if (blk < 5632) { s = s2; d = d2; blk -= 4096; }
    else if (blk < 6144) { s = s3; d = d3; blk -= 5632; }
    else if (blk < 7680) { s = s4; d = d4; blk -= 6144; }
    else if (blk < 8192) { s = s5; d = d5; blk -= 7680; }
    else                 { s = s6; d = d6; blk -= 8192; }
    const size_t i = ((size_t)blk * 256 + threadIdx.x) * 8;
    float4 a = *(const float4*)(s + i);
    float4 b = *(const float4*)(s + i + 4);
    u16x8 o;
    o[0] = f2bf(a.x); o[1] = f2bf(a.y); o[2] = f2bf(a.z); o[3] = f2bf(a.w);
    o[4] = f2bf(b.x); o[5] = f2bf(b.y); o[6] = f2bf(b.z); o[7] = f2bf(b.w);
    *(u16x8*)(d + i) = o;
}

// ---------------------------------------------------------------------------
// Transpose (R x C) f32 -> (C x R) bf16, batched over z.
// ---------------------------------------------------------------------------
__global__ __launch_bounds__(256) void transpose_f32_bf16_kernel(
    const float* __restrict__ src, u16* __restrict__ dst, int R, int C,
    size_t sI, size_t sO)
{
    __shared__ u16 t[32][33];
    src += (size_t)blockIdx.z * sI;
    dst += (size_t)blockIdx.z * sO;
    const int c0 = blockIdx.x * 32, r0 = blockIdx.y * 32;
    const int x = threadIdx.x & 31, y = threadIdx.x >> 5;
    for (int i = y; i < 32; i += 8)
        t[i][x] = f2bf(src[(size_t)(r0 + i) * C + c0 + x]);
    __syncthreads();
    for (int i = y; i < 32; i += 8)
        dst[(size_t)(c0 + i) * R + r0 + x] = t[x][i];
}

__global__ __launch_bounds__(256) void transpose_bf16_kernel(
    const u16* __restrict__ src, u16* __restrict__ dst, int R, int C,
    size_t sI, size_t sO)
{
    __shared__ u16 t[32][33];
    src += (size_t)blockIdx.z * sI;
    dst += (size_t)blockIdx.z * sO;
    const int c0 = blockIdx.x * 32, r0 = blockIdx.y * 32;
    const int x = threadIdx.x & 31, y = threadIdx.x >> 5;
    for (int i = y; i < 32; i += 8)
        t[i][x] = src[(size_t)(r0 + i) * C + c0 + x];
    __syncthreads();
    for (int i = y; i < 32; i += 8)
        dst[(size_t)(c0 + i) * R + r0 + x] = t[x][i];
}

// ---------------------------------------------------------------------------
// y = LayerNorm(X + R); writes f32 Y and (optionally) bf16 Ybf.
// ---------------------------------------------------------------------------
__global__ __launch_bounds__(256) void resid_ln_kernel(
    const float* __restrict__ X, const float* __restrict__ R,
    const float* __restrict__ g, const float* __restrict__ bt,
    float* __restrict__ Y, u16* __restrict__ Ybf)
{
    __shared__ float s1[4], s2[4];
    const size_t row = blockIdx.x;
    const int tid = threadIdx.x;
    const float4 x4 = *(const float4*)(X + row * 1024 + tid * 4);
    const float4 r4 = *(const float4*)(R + row * 1024 + tid * 4);
    float v[4] = {x4.x + r4.x, x4.y + r4.y, x4.z + r4.z, x4.w + r4.w};
    float s = v[0] + v[1] + v[2] + v[3];
    float q = v[0] * v[0] + v[1] * v[1] + v[2] * v[2] + v[3] * v[3];
#pragma unroll
    for (int off = 32; off; off >>= 1) {
        s += __shfl_xor(s, off);
        q += __shfl_xor(q, off);
    }
    if ((tid & 63) == 0) { s1[tid >> 6] = s; s2[tid >> 6] = q; }
    __syncthreads();
    s = s1[0] + s1[1] + s1[2] + s1[3];
    q = s2[0] + s2[1] + s2[2] + s2[3];
    const float mu = s * (1.f / 1024.f);
    const float var = q * (1.f / 1024.f) - mu * mu;
    const float rinv = rsqrtf(var + 1e-5f);
    const float4 g4 = *(const float4*)(g + tid * 4);
    const float4 b4 = *(const float4*)(bt + tid * 4);
    float o[4];
    o[0] = (v[0] - mu) * rinv * g4.x + b4.x;
    o[1] = (v[1] - mu) * rinv * g4.y + b4.y;
    o[2] = (v[2] - mu) * rinv * g4.z + b4.z;
    o[3] = (v[3] - mu) * rinv * g4.w + b4.w;
    *(float4*)(Y + row * 1024 + tid * 4) = *(float4*)o;
    if (Ybf) {
        u16x4 ob;
        ob[0] = f2bf(o[0]); ob[1] = f2bf(o[1]);
        ob[2] = f2bf(o[2]); ob[3] = f2bf(o[3]);
        *(u16x4*)(Ybf + row * 1024 + tid * 4) = ob;
    }
}

// ---------------------------------------------------------------------------
// dispatch softmax over m (sums 4 split-K partials), bf16 transposed out.
// ---------------------------------------------------------------------------
__global__ __launch_bounds__(256) void dispatch_softmax_T_kernel(
    const float* __restrict__ logitsP, u16* __restrict__ dispT)
{
    __shared__ float red[4];
    constexpr size_t CH = (size_t)B_ * M_ * NE_;
    const int n = blockIdx.x, b = blockIdx.y;
    u16* O = dispT + ((size_t)b * NE_ + n) * M_;
    const int tid = threadIdx.x;
    float v[4];
#pragma unroll
    for (int i = 0; i < 4; ++i) {
        const size_t idx = (size_t)(b * M_ + tid + 256 * i) * NE_ + n;
        v[i] = logitsP[idx] + logitsP[CH + idx] + logitsP[2 * CH + idx] + logitsP[3 * CH + idx];
    }
    float mx = fmaxf(fmaxf(v[0], v[1]), fmaxf(v[2], v[3]));
#pragma unroll
    for (int off = 32; off; off >>= 1) mx = fmaxf(mx, __shfl_xor(mx, off));
    if ((tid & 63) == 0) red[tid >> 6] = mx;
    __syncthreads();
    mx = fmaxf(fmaxf(red[0], red[1]), fmaxf(red[2], red[3]));
    __syncthreads();
    float e[4], s = 0.f;
#pragma unroll
    for (int i = 0; i < 4; ++i) { e[i] = __expf(v[i] - mx); s += e[i]; }
#pragma unroll
    for (int off = 32; off; off >>= 1) s += __shfl_xor(s, off);
    if ((tid & 63) == 0) red[tid >> 6] = s;
    __syncthreads();
    s = red[0] + red[1] + red[2] + red[3];
    const float inv = 1.f / s;
#pragma unroll
    for (int i = 0; i < 4; ++i) O[tid + 256 * i] = f2bf(e[i] * inv);
}

// ---------------------------------------------------------------------------
// combine softmax over 128 experts (sums partials), bf16 out. Grid B*M, 64 thr.
// ---------------------------------------------------------------------------
__global__ __launch_bounds__(64) void combine_softmax_kernel(
    const float* __restrict__ logitsP, u16* __restrict__ comb)
{
    constexpr size_t CH = (size_t)B_ * M_ * NE_;
    const size_t row = blockIdx.x;
    const int lane = threadIdx.x;
    const size_t i0 = row * NE_ + lane;
    const size_t i1 = i0 + 64;
    float a = logitsP[i0] + logitsP[CH + i0] + logitsP[2 * CH + i0] + logitsP[3 * CH + i0];
    float c = logitsP[i1] + logitsP[CH + i1] + logitsP[2 * CH + i1] + logitsP[3 * CH + i1];
    float mx = fmaxf(a, c);
#pragma unroll
    for (int off = 32; off; off >>= 1) mx = fmaxf(mx, __shfl_xor(mx, off));
    float e0 = __expf(a - mx), e1 = __expf(c - mx);
    float s = e0 + e1;
#pragma unroll
    for (int off = 32; off; off >>= 1) s += __shfl_xor(s, off);
    const float inv = 1.f / s;
    comb[row * NE_ + lane]      = f2bf(e0 * inv);
    comb[row * NE_ + lane + 64] = f2bf(e1 * inv);
}

// ---------------------------------------------------------------------------
// Expert partials: part[c][b][n][d] = sum_{f in chunk c} slots[b][n][f]*w[n][f][d]
// Grid (NE, 8). float4 loads of exp_w (16 B/lane, coalesced), slots via LDS
// broadcast. Reads exp_w exactly once (2.15 GB) -> HBM-bound by design.
// ---------------------------------------------------------------------------
__global__ __launch_bounds__(256) void expert_partial_kernel(
    const float* __restrict__ slots, const float* __restrict__ exp_w,
    float* __restrict__ part)
{
    __shared__ float sl[4][512];
    const int n = blockIdx.x;
    const int c = blockIdx.y;
    const int f0 = c * 512;
    const int t = threadIdx.x;
    for (int i = t; i < 2048; i += 256) {
        const int b = i >> 9, f = i & 511;
        sl[b][f] = slots[((size_t)b * NE_ + n) * FF_ + f0 + f];
    }
    __syncthreads();
    const int d4 = t * 4;
    const float* wp = exp_w + ((size_t)n * FF_ + f0) * D_ + d4;
    f32x4 acc[4];
#pragma unroll
    for (int b = 0; b < 4; ++b)
#pragma unroll
        for (int j = 0; j < 4; ++j) acc[b][j] = 0.f;
#pragma unroll 4
    for (int f = 0; f < 512; ++f) {
        const float4 w4 = *(const float4*)wp;
        wp += D_;
#pragma unroll
        for (int b = 0; b < 4; ++b) {
            const float s = sl[b][f];
            acc[b][0] = fmaf(s, w4.x, acc[b][0]);
            acc[b][1] = fmaf(s, w4.y, acc[b][1]);
            acc[b][2] = fmaf(s, w4.z, acc[b][2]);
            acc[b][3] = fmaf(s, w4.w, acc[b][3]);
        }
    }
#pragma unroll
    for (int b = 0; b < 4; ++b)
        *(f32x4*)&part[(((size_t)c * 4 + b) * NE_ + n) * D_ + d4] = acc[b];
}

// ---------------------------------------------------------------------------
// Reduce 8 partials + exp_b, emit yT[b][d][n] bf16 (fused transpose).
// Grid (D/32, NE/32, B), 256 threads, 32x33 LDS tile.
// ---------------------------------------------------------------------------
__global__ __launch_bounds__(256) void reduce_yT_kernel(
    const float* __restrict__ part, const float* __restrict__ exp_b,
    u16* __restrict__ yT)
{
    __shared__ float tile[32][33];
    const int d0 = blockIdx.x * 32, n0 = blockIdx.y * 32, b = blockIdx.z;
    const int x = threadIdx.x & 31, y = threadIdx.x >> 5;
    for (int i = y; i < 32; i += 8) {
        const int n = n0 + i;
        float s = exp_b[(size_t)n * D_ + d0 + x];
#pragma unroll
        for (int c = 0; c < 8; ++c)
            s += part[(((size_t)c * 4 + b) * NE_ + n) * D_ + d0 + x];
        tile[i][x] = s;
    }
    __syncthreads();
    for (int i = y; i < 32; i += 8)
        yT[((size_t)b * D_ + d0 + i) * NE_ + n0 + x] = f2bf(tile[x][i]);
}

// ---------------------------------------------------------------------------
extern "C" void kernel_launch(void* const* d_in, const int* in_sizes, int n_in,
                              void* d_out, int out_size, void* d_ws, size_t ws_size,
                              hipStream_t stream)
{
    const float* tgt      = (const float*)d_in[0];
    const float* memry    = (const float*)d_in[1];
    const float* sa_in_w  = (const float*)d_in[2];
    const float* sa_in_b  = (const float*)d_in[3];
    const float* sa_out_w = (const float*)d_in[4];
    const float* sa_out_b = (const float*)d_in[5];
    const float* ca_in_w  = (const float*)d_in[6];
    const float* ca_in_b  = (const float*)d_in[7];
    const float* ca_out_w = (const float*)d_in[8];
    const float* ca_out_b = (const float*)d_in[9];
    const float* norm1_g  = (const float*)d_in[10];
    const float* norm1_b  = (const float*)d_in[11];
    const float* norm2_g  = (const float*)d_in[12];
    const float* norm2_b  = (const float*)d_in[13];
    const float* norm3_g  = (const float*)d_in[14];
    const float* norm3_b  = (const float*)d_in[15];
    const float* lin_w    = (const float*)d_in[16];
    const float* lin_b    = (const float*)d_in[17];
    const float* phi      = (const float*)d_in[18];
    const float* exp_w    = (const float*)d_in[19];
    const float* exp_b    = (const float*)d_in[20];

    float* ws = (float*)d_ws;
    u16*   qkv_bf  = (u16*)(ws);                 // [4096][3072] u16 (CA reuse)
    float* proj    = ws + 6291456;
    float* x1      = ws + 10485760;
    float* x2      = ws + 14680064;
    float* logitsP = ws + 18874368;              // 4 x 524,288
    float* part    = ws + 20971520;              // 8*4*128*1024 = 4,194,304
    u16*   h_bf    = (u16*)(ws + 25165824);      // [4096][4096]
    u16*   hT_bf   = (u16*)(ws + 33554432);      // [4][4096][1024]
    u16*   obuf_bf = (u16*)(ws + 41943040);      // [4096][1024]
    u16*   x1_bf   = (u16*)(ws + 44040192);
    u16*   x2_bf   = (u16*)(ws + 46137344);
    u16*   tgt_bf  = (u16*)(ws + 48234496);
    u16*   mem_bf  = (u16*)(ws + 50331648);
    u16*   dispT   = (u16*)(ws + 52428800);      // [4][128][1024]
    u16*   comb_bf = (u16*)(ws + 52690944);      // [4096][128]
    u16*   yT_bf   = (u16*)(ws + 52953088);      // [4][1024][128]
    u16*   slots_n = 0; float* slots = ws + 53215232;   // 2,097,152
    (void)slots_n;
    u16*   w_sa_in = (u16*)(ws + 55312384);
    u16*   w_sa_out= (u16*)(ws + 56885248);
    u16*   w_ca_in = (u16*)(ws + 57409536);
    u16*   w_ca_out= (u16*)(ws + 58982400);
    u16*   w_lin   = (u16*)(ws + 59506688);
    u16*   phiT    = (u16*)(ws + 61603840);

    // ---- bf16 conversions (single launch) ----
    cvt_multi_kernel<<<10240, 256, 0, stream>>>(
        tgt, tgt_bf, memry, mem_bf, sa_in_w, w_sa_in, sa_out_w, w_sa_out,
        ca_in_w, w_ca_in, ca_out_w, w_ca_out, lin_w, w_lin);
    transpose_f32_bf16_kernel<<<dim3(4, 128, 1), 256, 0, stream>>>(phi, phiT, 4096, 128, 0, 0);

    // ---- Self-attention ----
    gemm_bt_mfma<1, 0, 1><<<dim3(24, 32, 1), 256, 0, stream>>>(
        tgt_bf, w_sa_in, sa_in_b, qkv_bf, 1024, 3072, 1024, 1024, 0, 0, 0);
    flash_attn_kernel<<<dim3(16, 16, 4), 256, 0, stream>>>(
        qkv_bf, 3072, qkv_bf + 1024, 3072, qkv_bf + 2048, 3072, obuf_bf, S_);
    gemm_bt_mfma<0, 0, 1><<<dim3(8, 32, 1), 256, 0, stream>>>(
        obuf_bf, w_sa_out, sa_out_b, proj, 1024, 1024, 1024, 1024, 0, 0, 0);
    resid_ln_kernel<<<4096, 256, 0, stream>>>(tgt, proj, norm1_g, norm1_b, x1, x1_bf);

    // ---- Cross-attention ----
    u16* qca_bf = qkv_bf;
    u16* kvca_bf = qkv_bf + (size_t)4096 * 1024;
    gemm_bt_mfma<1, 0, 1><<<dim3(8, 32, 1), 256, 0, stream>>>(
        x1_bf, w_ca_in, ca_in_b, qca_bf, 1024, 1024, 1024, 1024, 0, 0, 0);
    gemm_bt_mfma<1, 0, 1><<<dim3(16, 32, 1), 256, 0, stream>>>(
        mem_bf, w_ca_in + (size_t)1024 * 1024, ca_in_b + 1024,
        kvca_bf, 1024, 2048, 1024, 1024, 0, 0, 0);
    flash_attn_kernel<<<dim3(16, 16, 4), 256, 0, stream>>>(
        qca_bf, 1024, kvca_bf, 2048, kvca_bf + 1024, 2048, obuf_bf, S_);
    gemm_bt_mfma<0, 0, 1><<<dim3(8, 32, 1), 256, 0, stream>>>(
        obuf_bf, w_ca_out, ca_out_b, proj, 1024, 1024, 1024, 1024, 0, 0, 0);
    resid_ln_kernel<<<4096, 256, 0, stream>>>(x1, proj, norm2_g, norm2_b, x2, x2_bf);

    // ---- FF + SoftMoE ----
    gemm_bt_mfma<1, 1, 1><<<dim3(32, 32, 1), 256, 0, stream>>>(
        x2_bf, w_lin, lin_b, h_bf, 1024, 4096, 1024, 1024, 0, 0, 0);
    gemm_bt_mfma<0, 0, 0><<<dim3(1, 32, 4), 256, 0, stream>>>(
        h_bf, phiT, nullptr, logitsP, 1024, 128, 4096, 4096,
        1024, 1024, (size_t)B_ * M_ * NE_);
    dispatch_softmax_T_kernel<<<dim3(NE_, B_), 256, 0, stream>>>(logitsP, dispT);
    combine_softmax_kernel<<<dim3(B_ * M_), 64, 0, stream>>>(logitsP, comb_bf);
    transpose_bf16_kernel<<<dim3(128, 32, 4), 256, 0, stream>>>(
        h_bf, hT_bf, 1024, 4096, (size_t)M_ * FF_, (size_t)M_ * FF_);
    gemm_bt_mfma<0, 0, 0><<<dim3(32, 1, 4), 256, 0, stream>>>(
        dispT, hT_bf, nullptr, slots, 1024, 4096, 1024, 1024,
        (size_t)NE_ * M_, (size_t)FF_ * M_, (size_t)NE_ * FF_);
    expert_partial_kernel<<<dim3(NE_, 8), 256, 0, stream>>>(slots, exp_w, part);
    reduce_yT_kernel<<<dim3(32, 4, 4), 256, 0, stream>>>(part, exp_b, yT_bf);
    gemm_bt_mfma<0, 0, 0><<<dim3(8, 8, 4), 256, 0, stream>>>(
        comb_bf, yT_bf, nullptr, proj, 128, 1024, 128, 128,
        (size_t)M_ * NE_, (size_t)D_ * NE_, (size_t)M_ * D_);
    resid_ln_kernel<<<4096, 256, 0, stream>>>(x2, proj, norm3_g, norm3_b,
                                              (float*)d_out, nullptr);
}

// Round 5
// 832.005 us; speedup vs baseline: 4.8011x; 1.0084x over previous
//
#include <hip/hip_runtime.h>
#include <cstdint>
#include <cstddef>

typedef unsigned short u16;
typedef unsigned int   u32;
typedef short bf16x8 __attribute__((ext_vector_type(8)));
typedef float f32x4  __attribute__((ext_vector_type(4)));
typedef u16   u16x8  __attribute__((ext_vector_type(8)));
typedef u16   u16x4  __attribute__((ext_vector_type(4)));
typedef u16   u16x2  __attribute__((ext_vector_type(2)));

constexpr int B_  = 4;
constexpr int M_  = 1024;
constexpr int S_  = 1024;
constexpr int D_  = 1024;
constexpr int H_  = 16;
constexpr int FF_ = 4096;
constexpr int NE_ = 128;

__device__ __forceinline__ u16 f2bf(float f) {
    u32 u = __builtin_bit_cast(u32, f);
    u = (u + 0x7fffu + ((u >> 16) & 1u)) >> 16;   // RNE
    return (u16)u;
}
__device__ __forceinline__ float bf2f(u16 u) {
    u32 x = ((u32)u) << 16;
    return __builtin_bit_cast(float, x);
}
__device__ __forceinline__ void gload_lds16(const u16* g, u16* l) {
    __builtin_amdgcn_global_load_lds(
        (const __attribute__((address_space(1))) u32*)g,
        (__attribute__((address_space(3))) u32*)l, 16, 0, 0);
}

// ---------------------------------------------------------------------------
// 256x256 deep-pipelined bf16 MFMA GEMM (T2+T3+T4+T5).
// C[r][c] = sum_k A[r][k]*W[c][k] + bias[c], bf16 out.
// 512 thr = 8 waves (2 Mrow x 4 Ncol), per-wave 128x64 out (8x4 frags).
// BK=32, triple-buffered LDS (96KB), 2-step prefetch, vmcnt(4) counted.
// LDS tile [256][32] bf16, chunk swizzle q_phys = q ^ ((row>>1)&3) applied
// via per-lane pre-swizzled GLOBAL source (linear gload_lds dest) and the
// matching read offset -> 2-way (free) ds_read_b128 bank conflicts.
// ---------------------------------------------------------------------------
template<int RELU>
__global__ __launch_bounds__(512, 1) void gemm256_mfma(
    const u16* __restrict__ A, const u16* __restrict__ W,
    const float* __restrict__ bias, u16* __restrict__ C,
    int K, int N, int lda, int ldw)
{
    __shared__ u16 lds[49152];                 // A bufs @0/8192/16384, B @+24576
    const int tid = threadIdx.x;
    const int w = tid >> 6, l = tid & 63;
    const int wr = w >> 2, wc = w & 3;
    const int fr = l & 15, g = l >> 4;
    const int bm = blockIdx.y * 256, bn = blockIdx.x * 256;

    // staging: thread -> physical chunk p = i*512 + tid; row r = p>>2,
    // phys q' = tid&3, logical q = q' ^ ((r>>1)&3)  (indep. of issue i)
    const int qcol = (((l & 3) ^ ((l >> 3) & 3))) * 8;
    const int srow = w * 16 + (l >> 2);
    const u16* aG0 = A + (size_t)(bm + srow) * lda + qcol;
    const u16* aG1 = aG0 + (size_t)128 * lda;
    const u16* bG0 = W + (size_t)(bn + srow) * ldw + qcol;
    const u16* bG1 = bG0 + (size_t)128 * ldw;
    const int wofs = w * 512;                  // wave-uniform stage base (elems)

    // fragment read offsets (swizzle factor indep. of mf/nf)
    const int qsw = (g ^ ((fr >> 1) & 3)) * 8;
    const int aoff = (wr * 128 + fr) * 32 + qsw;
    const int boff = (wc * 64 + fr) * 32 + qsw;

    f32x4 acc[8][4];
#pragma unroll
    for (int i = 0; i < 8; ++i)
#pragma unroll
        for (int j = 0; j < 4; ++j)
#pragma unroll
            for (int q = 0; q < 4; ++q) acc[i][j][q] = 0.f;

    // ---- prologue: stage K-steps 0 (buf0) and 1 (buf1) ----
    gload_lds16(aG0, &lds[0 + wofs]);
    gload_lds16(aG1, &lds[4096 + wofs]);
    gload_lds16(bG0, &lds[24576 + wofs]);
    gload_lds16(bG1, &lds[24576 + 4096 + wofs]);
    aG0 += 32; aG1 += 32; bG0 += 32; bG1 += 32;
    gload_lds16(aG0, &lds[8192 + wofs]);
    gload_lds16(aG1, &lds[8192 + 4096 + wofs]);
    gload_lds16(bG0, &lds[32768 + wofs]);
    gload_lds16(bG1, &lds[32768 + 4096 + wofs]);
    aG0 += 32; aG1 += 32; bG0 += 32; bG1 += 32;
    asm volatile("s_waitcnt vmcnt(4)" ::: "memory");   // buf0 landed, buf1 flying
    __builtin_amdgcn_s_barrier();
    __builtin_amdgcn_sched_barrier(0);

    int rb = 0;   // read-buffer index; write buffer = (rb+2)%3

#define G256_STEP(ISSUE_, VMOPT_)                                            \
  {                                                                          \
    const int wb_ = (rb >= 1) ? rb - 1 : 2;                                  \
    const u16* Ab_ = &lds[rb * 8192];                                        \
    const u16* Bb_ = &lds[24576 + rb * 8192];                                \
    u16* Aw_ = &lds[wb_ * 8192];                                             \
    u16* Bw_ = &lds[24576 + wb_ * 8192];                                     \
    bf16x8 af_[4], bf_[4];                                                   \
    _Pragma("unroll") for (int mf = 0; mf < 4; ++mf)                         \
      af_[mf] = *(const bf16x8*)(Ab_ + aoff + mf * 512);                     \
    _Pragma("unroll") for (int nf = 0; nf < 4; ++nf)                         \
      bf_[nf] = *(const bf16x8*)(Bb_ + boff + nf * 512);                     \
    if (ISSUE_) {                                                            \
      gload_lds16(aG0, Aw_ + wofs);                                          \
      gload_lds16(aG1, Aw_ + 4096 + wofs);                                   \
    }                                                                        \
    __builtin_amdgcn_s_barrier();                                            \
    __builtin_amdgcn_sched_barrier(0);                                       \
    __builtin_amdgcn_s_setprio(1);                                           \
    _Pragma("unroll") for (int mf = 0; mf < 4; ++mf)                         \
      _Pragma("unroll") for (int nf = 0; nf < 4; ++nf)                       \
        acc[mf][nf] = __builtin_amdgcn_mfma_f32_16x16x32_bf16(               \
            af_[mf], bf_[nf], acc[mf][nf], 0, 0, 0);                         \
    __builtin_amdgcn_s_setprio(0);                                           \
    __builtin_amdgcn_s_barrier();                                            \
    __builtin_amdgcn_sched_barrier(0);                                       \
    _Pragma("unroll") for (int mf = 0; mf < 4; ++mf)                         \
      af_[mf] = *(const bf16x8*)(Ab_ + aoff + 2048 + mf * 512);              \
    if (ISSUE_) {                                                            \
      gload_lds16(bG0, Bw_ + wofs);                                          \
      gload_lds16(bG1, Bw_ + 4096 + wofs);                                   \
      aG0 += 32; aG1 += 32; bG0 += 32; bG1 += 32;                            \
    }                                                                        \
    VMOPT_                                                                   \
    __builtin_amdgcn_s_barrier();                                            \
    __builtin_amdgcn_sched_barrier(0);                                       \
    __builtin_amdgcn_s_setprio(1);                                           \
    _Pragma("unroll") for (int mf = 0; mf < 4; ++mf)                         \
      _Pragma("unroll") for (int nf = 0; nf < 4; ++nf)                       \
        acc[mf + 4][nf] = __builtin_amdgcn_mfma_f32_16x16x32_bf16(           \
            af_[mf], bf_[nf], acc[mf + 4][nf], 0, 0, 0);                     \
    __builtin_amdgcn_s_setprio(0);                                           \
    __builtin_amdgcn_s_barrier();                                            \
    __builtin_amdgcn_sched_barrier(0);                                       \
    rb = (rb == 2) ? 0 : rb + 1;                                             \
  }

    const int nstep = K >> 5;
    for (int t = 0; t < nstep - 2; ++t) {
        G256_STEP(1, asm volatile("s_waitcnt vmcnt(4)" ::: "memory");)
    }
    G256_STEP(0, asm volatile("s_waitcnt vmcnt(0)" ::: "memory");)
    G256_STEP(0, )
#undef G256_STEP

    // epilogue
    const int row0 = bm + wr * 128 + g * 4;
    const int col0 = bn + wc * 64 + fr;
#pragma unroll
    for (int nf = 0; nf < 4; ++nf) {
        const int col = col0 + nf * 16;
        const float bv = bias[col];
#pragma unroll
        for (int mf = 0; mf < 8; ++mf) {
#pragma unroll
            for (int j = 0; j < 4; ++j) {
                float v = acc[mf][nf][j] + bv;
                if (RELU) v = fmaxf(v, 0.f);
                C[(size_t)(row0 + mf * 16 + j) * N + col] = f2bf(v);
            }
        }
    }
}

// ---------------------------------------------------------------------------
// bf16 MFMA GEMM (m97 structure): C[r][c] = sum_k A[r][k]*W[c][k] (+bias[c])
// ---------------------------------------------------------------------------
template<int OUT_BF16, int RELU, int HAS_BIAS>
__global__ __launch_bounds__(256) void gemm_bt_mfma(
    const u16* __restrict__ A, const u16* __restrict__ W,
    const float* __restrict__ bias, void* __restrict__ Cout,
    int K, int N, int lda, int ldw,
    size_t sA, size_t sW, size_t sC)
{
    __shared__ u16 As[128 * 32];
    __shared__ u16 Bs[128 * 32];
    const int tid = threadIdx.x;
    const int w = tid >> 6, l = tid & 63;
    const int bm = blockIdx.y * 128, bn = blockIdx.x * 128;
    const u16* Ab = A + (size_t)blockIdx.z * sA;
    const u16* Wb = W + (size_t)blockIdx.z * sW;

    const int wr = w >> 1, wc = w & 1;
    const int sr = l >> 2;
    const int sk = (l & 3) * 8;
    const u16* aG0 = Ab + (size_t)(bm + w * 16 + sr) * lda + sk;
    const u16* aG1 = Ab + (size_t)(bm + (w + 4) * 16 + sr) * lda + sk;
    const u16* bG0 = Wb + (size_t)(bn + w * 16 + sr) * ldw + sk;
    const u16* bG1 = Wb + (size_t)(bn + (w + 4) * 16 + sr) * ldw + sk;
    u16* aL0 = &As[w * 512];
    u16* aL1 = &As[(w + 4) * 512];
    u16* bL0 = &Bs[w * 512];
    u16* bL1 = &Bs[(w + 4) * 512];

    const int fr = l & 15;
    const int fk = (l >> 4) * 8;

    f32x4 acc[4][4];
#pragma unroll
    for (int i = 0; i < 4; ++i)
#pragma unroll
        for (int j = 0; j < 4; ++j)
#pragma unroll
            for (int q = 0; q < 4; ++q) acc[i][j][q] = 0.f;

    for (int k0 = 0; k0 < K; k0 += 32) {
        __syncthreads();
        gload_lds16(aG0, aL0);
        gload_lds16(aG1, aL1);
        gload_lds16(bG0, bL0);
        gload_lds16(bG1, bL1);
        aG0 += 32; aG1 += 32; bG0 += 32; bG1 += 32;
        __syncthreads();
        bf16x8 af[4], bfr[4];
#pragma unroll
        for (int m = 0; m < 4; ++m)
            af[m] = *(const bf16x8*)&As[(wr * 64 + m * 16 + fr) * 32 + fk];
#pragma unroll
        for (int n = 0; n < 4; ++n)
            bfr[n] = *(const bf16x8*)&Bs[(wc * 64 + n * 16 + fr) * 32 + fk];
#pragma unroll
        for (int m = 0; m < 4; ++m)
#pragma unroll
            for (int n = 0; n < 4; ++n)
                acc[m][n] = __builtin_amdgcn_mfma_f32_16x16x32_bf16(
                    af[m], bfr[n], acc[m][n], 0, 0, 0);
    }

    const int row0 = bm + wr * 64 + (l >> 4) * 4;
    const int col0 = bn + wc * 64;
#pragma unroll
    for (int n = 0; n < 4; ++n) {
        const int col = col0 + n * 16 + fr;
        float bv = 0.f;
        if (HAS_BIAS) bv = bias[col];
#pragma unroll
        for (int m = 0; m < 4; ++m) {
            const int row = row0 + m * 16;
#pragma unroll
            for (int j = 0; j < 4; ++j) {
                float v = acc[m][n][j] + bv;
                if (RELU) v = fmaxf(v, 0.f);
                const size_t idx = (size_t)blockIdx.z * sC + (size_t)(row + j) * N + col;
                if (OUT_BF16) ((u16*)Cout)[idx] = f2bf(v);
                else          ((float*)Cout)[idx] = v;
            }
        }
    }
}

// ---------------------------------------------------------------------------
// Flash attention fwd with defer-max (THR=8). bf16 in/out, f32 softmax state.
// ---------------------------------------------------------------------------
__global__ __launch_bounds__(256) void flash_attn_kernel(
    const u16* __restrict__ Q, int qs,
    const u16* __restrict__ K, int ks,
    const u16* __restrict__ V, int vs,
    u16* __restrict__ O, int Slen)
{
    __shared__ u16 Qs[64][72];
    __shared__ u16 Ks[64][72];
    __shared__ u16 Vt[64][72];
    __shared__ u16 Pw[4][16][72];
    const int b = blockIdx.z, hh = blockIdx.y;
    const int m0 = blockIdx.x * 64;
    const int tid = threadIdx.x;
    const int w = tid >> 6, l = tid & 63;
    const int lq = l & 15, g = l >> 4;

    {
        const int row = tid >> 2, cg = (tid & 3) * 16;
        const u16* qp = Q + ((size_t)b * M_ + m0 + row) * qs + hh * 64 + cg;
        u16x8 v0 = *(const u16x8*)qp;
        u16x8 v1 = *(const u16x8*)(qp + 8);
        u16x8 o0, o1;
#pragma unroll
        for (int i = 0; i < 8; ++i) {
            o0[i] = f2bf(bf2f(v0[i]) * 0.125f);
            o1[i] = f2bf(bf2f(v1[i]) * 0.125f);
        }
        *(u16x8*)&Qs[row][cg]     = o0;
        *(u16x8*)&Qs[row][cg + 8] = o1;
    }
    __syncthreads();
    bf16x8 qf[2];
    qf[0] = *(const bf16x8*)&Qs[w * 16 + lq][g * 8];
    qf[1] = *(const bf16x8*)&Qs[w * 16 + lq][32 + g * 8];

    f32x4 acc_o[4];
#pragma unroll
    for (int nb = 0; nb < 4; ++nb)
#pragma unroll
        for (int j = 0; j < 4; ++j) acc_o[nb][j] = 0.f;
    float m_run = -1e30f, l_run = 0.f;

    const int kp = tid & 31, dg = tid >> 5;
    const int krow = tid >> 2, kcg = (tid & 3) * 16;

    for (int s0 = 0; s0 < Slen; s0 += 64) {
        __syncthreads();
        {   // K tile
            const u16* kpp = K + ((size_t)b * Slen + s0 + krow) * ks + hh * 64 + kcg;
            *(u16x8*)&Ks[krow][kcg]     = *(const u16x8*)kpp;
            *(u16x8*)&Ks[krow][kcg + 8] = *(const u16x8*)(kpp + 8);
        }
        {   // V^T tile (paired u16x2 writes: 2-way banks, free)
            const u16* vp0 = V + ((size_t)b * Slen + s0 + 2 * kp) * vs + hh * 64 + dg * 8;
            const u16* vp1 = vp0 + vs;
            u16x8 a = *(const u16x8*)vp0;
            u16x8 c = *(const u16x8*)vp1;
#pragma unroll
            for (int i = 0; i < 8; ++i) {
                u16x2 pk; pk[0] = a[i]; pk[1] = c[i];
                *(u16x2*)&Vt[dg * 8 + i][2 * kp] = pk;
            }
        }
        __syncthreads();

        // S^T = K @ Q^T
        f32x4 s4[4];
#pragma unroll
        for (int mb = 0; mb < 4; ++mb) {
            f32x4 z = {0.f, 0.f, 0.f, 0.f};
            bf16x8 a0 = *(const bf16x8*)&Ks[mb * 16 + lq][g * 8];
            bf16x8 a1 = *(const bf16x8*)&Ks[mb * 16 + lq][32 + g * 8];
            z = __builtin_amdgcn_mfma_f32_16x16x32_bf16(a0, qf[0], z, 0, 0, 0);
            z = __builtin_amdgcn_mfma_f32_16x16x32_bf16(a1, qf[1], z, 0, 0, 0);
            s4[mb] = z;
        }

        // online softmax with defer-max (T13)
        float pm = -1e30f;
#pragma unroll
        for (int mb = 0; mb < 4; ++mb)
#pragma unroll
            for (int j = 0; j < 4; ++j) pm = fmaxf(pm, s4[mb][j]);
        pm = fmaxf(pm, __shfl_xor(pm, 16));
        pm = fmaxf(pm, __shfl_xor(pm, 32));

        u16 pbf[4][4];
        float ls = 0.f;
        if (__all(pm - m_run <= 8.f)) {
#pragma unroll
            for (int mb = 0; mb < 4; ++mb)
#pragma unroll
                for (int j = 0; j < 4; ++j) {
                    float p = __expf(s4[mb][j] - m_run);
                    ls += p;
                    pbf[mb][j] = f2bf(p);
                }
            ls += __shfl_xor(ls, 16);
            ls += __shfl_xor(ls, 32);
            l_run += ls;
        } else {
            const float m_new = fmaxf(m_run, pm);
            const float alpha = __expf(m_run - m_new);
#pragma unroll
            for (int mb = 0; mb < 4; ++mb)
#pragma unroll
                for (int j = 0; j < 4; ++j) {
                    float p = __expf(s4[mb][j] - m_new);
                    ls += p;
                    pbf[mb][j] = f2bf(p);
                }
            ls += __shfl_xor(ls, 16);
            ls += __shfl_xor(ls, 32);
            l_run = l_run * alpha + ls;
            m_run = m_new;
            float al[4];
#pragma unroll
            for (int j = 0; j < 4; ++j) al[j] = __shfl(alpha, 4 * g + j);
#pragma unroll
            for (int nb = 0; nb < 4; ++nb)
#pragma unroll
                for (int j = 0; j < 4; ++j) acc_o[nb][j] *= al[j];
        }

        // P -> per-wave LDS
#pragma unroll
        for (int mb = 0; mb < 4; ++mb) {
            u16x4 pk;
            pk[0] = pbf[mb][0]; pk[1] = pbf[mb][1];
            pk[2] = pbf[mb][2]; pk[3] = pbf[mb][3];
            *(u16x4*)&Pw[w][lq][mb * 16 + g * 4] = pk;
        }

        // PV
#pragma unroll
        for (int kc = 0; kc < 2; ++kc) {
            bf16x8 pa = *(const bf16x8*)&Pw[w][lq][kc * 32 + g * 8];
#pragma unroll
            for (int nb = 0; nb < 4; ++nb) {
                bf16x8 bv = *(const bf16x8*)&Vt[nb * 16 + lq][kc * 32 + g * 8];
                acc_o[nb] = __builtin_amdgcn_mfma_f32_16x16x32_bf16(pa, bv, acc_o[nb], 0, 0, 0);
            }
        }
    }

    float linv[4];
#pragma unroll
    for (int j = 0; j < 4; ++j) linv[j] = 1.f / __shfl(l_run, 4 * g + j);
#pragma unroll
    for (int nb = 0; nb < 4; ++nb)
#pragma unroll
        for (int j = 0; j < 4; ++j) {
            const size_t row = (size_t)b * M_ + m0 + w * 16 + 4 * g + j;
            O[row * D_ + hh * 64 + nb * 16 + lq] = f2bf(acc_o[nb][j] * linv[j]);
        }
}

// ---------------------------------------------------------------------------
// One-shot f32->bf16 for all 7 tensors.
// ---------------------------------------------------------------------------
__global__ __launch_bounds__(256) void cvt_multi_kernel(
    const float* __restrict__ s0, u16* __restrict__ d0,
    const float* __restrict__ s1, u16* __restrict__ d1,
    const float* __restrict__ s2, u16* __restrict__ d2,
    const float* __restrict__ s3, u16* __restrict__ d3,
    const float* __restrict__ s4, u16* __restrict__ d4,
    const float* __restrict__ s5, u16* __restrict__ d5,
    const float* __restrict__ s6, u16* __restrict__ d6)
{
    int blk = blockIdx.x;
    const float* s; u16* d;
    if      (blk < 2048) { s = s0; d = d0; }
    else if (blk < 4096) { s = s1; d = d1; blk -= 2048; }
    else if (blk < 5632) { s = s2; d = d2; blk -= 4096; }
    else if (blk < 6144) { s = s3; d = d3; blk -= 5632; }
    else if (blk < 7680) { s = s4; d = d4; blk -= 6144; }
    else if (blk < 8192) { s = s5; d = d5; blk -= 7680; }
    else                 { s = s6; d = d6; blk -= 8192; }
    const size_t i = ((size_t)blk * 256 + threadIdx.x) * 8;
    float4 a = *(const float4*)(s + i);
    float4 b = *(const float4*)(s + i + 4);
    u16x8 o;
    o[0] = f2bf(a.x); o[1] = f2bf(a.y); o[2] = f2bf(a.z); o[3] = f2bf(a.w);
    o[4] = f2bf(b.x); o[5] = f2bf(b.y); o[6] = f2bf(b.z); o[7] = f2bf(b.w);
    *(u16x8*)(d + i) = o;
}

// ---------------------------------------------------------------------------
// Transpose (R x C) f32 -> (C x R) bf16, batched over z.
// ---------------------------------------------------------------------------
__global__ __launch_bounds__(256) void transpose_f32_bf16_kernel(
    const float* __restrict__ src, u16* __restrict__ dst, int R, int C,
    size_t sI, size_t sO)
{
    __shared__ u16 t[32][33];
    src += (size_t)blockIdx.z * sI;
    dst += (size_t)blockIdx.z * sO;
    const int c0 = blockIdx.x * 32, r0 = blockIdx.y * 32;
    const int x = threadIdx.x & 31, y = threadIdx.x >> 5;
    for (int i = y; i < 32; i += 8)
        t[i][x] = f2bf(src[(size_t)(r0 + i) * C + c0 + x]);
    __syncthreads();
    for (int i = y; i < 32; i += 8)
        dst[(size_t)(c0 + i) * R + r0 + x] = t[x][i];
}

__global__ __launch_bounds__(256) void transpose_bf16_kernel(
    const u16* __restrict__ src, u16* __restrict__ dst, int R, int C,
    size_t sI, size_t sO)
{
    __shared__ u16 t[32][33];
    src += (size_t)blockIdx.z * sI;
    dst += (size_t)blockIdx.z * sO;
    const int c0 = blockIdx.x * 32, r0 = blockIdx.y * 32;
    const int x = threadIdx.x & 31, y = threadIdx.x >> 5;
    for (int i = y; i < 32; i += 8)
        t[i][x] = src[(size_t)(r0 + i) * C + c0 + x];
    __syncthreads();
    for (int i = y; i < 32; i += 8)
        dst[(size_t)(c0 + i) * R + r0 + x] = t[x][i];
}

// ---------------------------------------------------------------------------
// y = LayerNorm(X + R); writes f32 Y and (optionally) bf16 Ybf.
// ---------------------------------------------------------------------------
__global__ __launch_bounds__(256) void resid_ln_kernel(
    const float* __restrict__ X, const float* __restrict__ R,
    const float* __restrict__ g, const float* __restrict__ bt,
    float* __restrict__ Y, u16* __restrict__ Ybf)
{
    __shared__ float s1[4], s2[4];
    const size_t row = blockIdx.x;
    const int tid = threadIdx.x;
    const float4 x4 = *(const float4*)(X + row * 1024 + tid * 4);
    const float4 r4 = *(const float4*)(R + row * 1024 + tid * 4);
    float v[4] = {x4.x + r4.x, x4.y + r4.y, x4.z + r4.z, x4.w + r4.w};
    float s = v[0] + v[1] + v[2] + v[3];
    float q = v[0] * v[0] + v[1] * v[1] + v[2] * v[2] + v[3] * v[3];
#pragma unroll
    for (int off = 32; off; off >>= 1) {
        s += __shfl_xor(s, off);
        q += __shfl_xor(q, off);
    }
    if ((tid & 63) == 0) { s1[tid >> 6] = s; s2[tid >> 6] = q; }
    __syncthreads();
    s = s1[0] + s1[1] + s1[2] + s1[3];
    q = s2[0] + s2[1] + s2[2] + s2[3];
    const float mu = s * (1.f / 1024.f);
    const float var = q * (1.f / 1024.f) - mu * mu;
    const float rinv = rsqrtf(var + 1e-5f);
    const float4 g4 = *(const float4*)(g + tid * 4);
    const float4 b4 = *(const float4*)(bt + tid * 4);
    float o[4];
    o[0] = (v[0] - mu) * rinv * g4.x + b4.x;
    o[1] = (v[1] - mu) * rinv * g4.y + b4.y;
    o[2] = (v[2] - mu) * rinv * g4.z + b4.z;
    o[3] = (v[3] - mu) * rinv * g4.w + b4.w;
    *(float4*)(Y + row * 1024 + tid * 4) = *(float4*)o;
    if (Ybf) {
        u16x4 ob;
        ob[0] = f2bf(o[0]); ob[1] = f2bf(o[1]);
        ob[2] = f2bf(o[2]); ob[3] = f2bf(o[3]);
        *(u16x4*)(Ybf + row * 1024 + tid * 4) = ob;
    }
}

// ---------------------------------------------------------------------------
// dispatch softmax over m (sums 4 split-K partials), bf16 transposed out.
// ---------------------------------------------------------------------------
__global__ __launch_bounds__(256) void dispatch_softmax_T_kernel(
    const float* __restrict__ logitsP, u16* __restrict__ dispT)
{
    __shared__ float red[4];
    constexpr size_t CH = (size_t)B_ * M_ * NE_;
    const int n = blockIdx.x, b = blockIdx.y;
    u16* O = dispT + ((size_t)b * NE_ + n) * M_;
    const int tid = threadIdx.x;
    float v[4];
#pragma unroll
    for (int i = 0; i < 4; ++i) {
        const size_t idx = (size_t)(b * M_ + tid + 256 * i) * NE_ + n;
        v[i] = logitsP[idx] + logitsP[CH + idx] + logitsP[2 * CH + idx] + logitsP[3 * CH + idx];
    }
    float mx = fmaxf(fmaxf(v[0], v[1]), fmaxf(v[2], v[3]));
#pragma unroll
    for (int off = 32; off; off >>= 1) mx = fmaxf(mx, __shfl_xor(mx, off));
    if ((tid & 63) == 0) red[tid >> 6] = mx;
    __syncthreads();
    mx = fmaxf(fmaxf(red[0], red[1]), fmaxf(red[2], red[3]));
    __syncthreads();
    float e[4], s = 0.f;
#pragma unroll
    for (int i = 0; i < 4; ++i) { e[i] = __expf(v[i] - mx); s += e[i]; }
#pragma unroll
    for (int off = 32; off; off >>= 1) s += __shfl_xor(s, off);
    if ((tid & 63) == 0) red[tid >> 6] = s;
    __syncthreads();
    s = red[0] + red[1] + red[2] + red[3];
    const float inv = 1.f / s;
#pragma unroll
    for (int i = 0; i < 4; ++i) O[tid + 256 * i] = f2bf(e[i] * inv);
}

// ---------------------------------------------------------------------------
// combine softmax over 128 experts (sums partials), bf16 out.
// ---------------------------------------------------------------------------
__global__ __launch_bounds__(64) void combine_softmax_kernel(
    const float* __restrict__ logitsP, u16* __restrict__ comb)
{
    constexpr size_t CH = (size_t)B_ * M_ * NE_;
    const size_t row = blockIdx.x;
    const int lane = threadIdx.x;
    const size_t i0 = row * NE_ + lane;
    const size_t i1 = i0 + 64;
    float a = logitsP[i0] + logitsP[CH + i0] + logitsP[2 * CH + i0] + logitsP[3 * CH + i0];
    float c = logitsP[i1] + logitsP[CH + i1] + logitsP[2 * CH + i1] + logitsP[3 * CH + i1];
    float mx = fmaxf(a, c);
#pragma unroll
    for (int off = 32; off; off >>= 1) mx = fmaxf(mx, __shfl_xor(mx, off));
    float e0 = __expf(a - mx), e1 = __expf(c - mx);
    float s = e0 + e1;
#pragma unroll
    for (int off = 32; off; off >>= 1) s += __shfl_xor(s, off);
    const float inv = 1.f / s;
    comb[row * NE_ + lane]      = f2bf(e0 * inv);
    comb[row * NE_ + lane + 64] = f2bf(e1 * inv);
}

// ---------------------------------------------------------------------------
// Expert partials: part[c][b][n][d] = sum_{f in chunk c} slots[b][n][f]*w[n][f][d]
// ---------------------------------------------------------------------------
__global__ __launch_bounds__(256) void expert_partial_kernel(
    const float* __restrict__ slots, const float* __restrict__ exp_w,
    float* __restrict__ part)
{
    __shared__ float sl[4][512];
    const int n = blockIdx.x;
    const int c = blockIdx.y;
    const int f0 = c * 512;
    const int t = threadIdx.x;
    for (int i = t; i < 2048; i += 256) {
        const int b = i >> 9, f = i & 511;
        sl[b][f] = slots[((size_t)b * NE_ + n) * FF_ + f0 + f];
    }
    __syncthreads();
    const int d4 = t * 4;
    const float* wp = exp_w + ((size_t)n * FF_ + f0) * D_ + d4;
    f32x4 acc[4];
#pragma unroll
    for (int b = 0; b < 4; ++b)
#pragma unroll
        for (int j = 0; j < 4; ++j) acc[b][j] = 0.f;
#pragma unroll 4
    for (int f = 0; f < 512; ++f) {
        const float4 w4 = *(const float4*)wp;
        wp += D_;
#pragma unroll
        for (int b = 0; b < 4; ++b) {
            const float s = sl[b][f];
            acc[b][0] = fmaf(s, w4.x, acc[b][0]);
            acc[b][1] = fmaf(s, w4.y, acc[b][1]);
            acc[b][2] = fmaf(s, w4.z, acc[b][2]);
            acc[b][3] = fmaf(s, w4.w, acc[b][3]);
        }
    }
#pragma unroll
    for (int b = 0; b < 4; ++b)
        *(f32x4*)&part[(((size_t)c * 4 + b) * NE_ + n) * D_ + d4] = acc[b];
}

// ---------------------------------------------------------------------------
// Reduce 8 partials + exp_b, emit yT[b][d][n] bf16 (fused transpose).
// ---------------------------------------------------------------------------
__global__ __launch_bounds__(256) void reduce_yT_kernel(
    const float* __restrict__ part, const float* __restrict__ exp_b,
    u16* __restrict__ yT)
{
    __shared__ float tile[32][33];
    const int d0 = blockIdx.x * 32, n0 = blockIdx.y * 32, b = blockIdx.z;
    const int x = threadIdx.x & 31, y = threadIdx.x >> 5;
    for (int i = y; i < 32; i += 8) {
        const int n = n0 + i;
        float s = exp_b[(size_t)n * D_ + d0 + x];
#pragma unroll
        for (int c = 0; c < 8; ++c)
            s += part[(((size_t)c * 4 + b) * NE_ + n) * D_ + d0 + x];
        tile[i][x] = s;
    }
    __syncthreads();
    for (int i = y; i < 32; i += 8)
        yT[((size_t)b * D_ + d0 + i) * NE_ + n0 + x] = f2bf(tile[x][i]);
}

// ---------------------------------------------------------------------------
extern "C" void kernel_launch(void* const* d_in, const int* in_sizes, int n_in,
                              void* d_out, int out_size, void* d_ws, size_t ws_size,
                              hipStream_t stream)
{
    const float* tgt      = (const float*)d_in[0];
    const float* memry    = (const float*)d_in[1];
    const float* sa_in_w  = (const float*)d_in[2];
    const float* sa_in_b  = (const float*)d_in[3];
    const float* sa_out_w = (const float*)d_in[4];
    const float* sa_out_b = (const float*)d_in[5];
    const float* ca_in_w  = (const float*)d_in[6];
    const float* ca_in_b  = (const float*)d_in[7];
    const float* ca_out_w = (const float*)d_in[8];
    const float* ca_out_b = (const float*)d_in[9];
    const float* norm1_g  = (const float*)d_in[10];
    const float* norm1_b  = (const float*)d_in[11];
    const float* norm2_g  = (const float*)d_in[12];
    const float* norm2_b  = (const float*)d_in[13];
    const float* norm3_g  = (const float*)d_in[14];
    const float* norm3_b  = (const float*)d_in[15];
    const float* lin_w    = (const float*)d_in[16];
    const float* lin_b    = (const float*)d_in[17];
    const float* phi      = (const float*)d_in[18];
    const float* exp_w    = (const float*)d_in[19];
    const float* exp_b    = (const float*)d_in[20];

    float* ws = (float*)d_ws;
    u16*   qkv_bf  = (u16*)(ws);                 // [4096][3072] u16 (CA reuse)
    float* proj    = ws + 6291456;
    float* x1      = ws + 10485760;
    float* x2      = ws + 14680064;
    float* logitsP = ws + 18874368;              // 4 x 524,288
    float* part    = ws + 20971520;              // 4,194,304
    u16*   h_bf    = (u16*)(ws + 25165824);      // [4096][4096]
    u16*   hT_bf   = (u16*)(ws + 33554432);      // [4][4096][1024]
    u16*   obuf_bf = (u16*)(ws + 41943040);      // [4096][1024]
    u16*   x1_bf   = (u16*)(ws + 44040192);
    u16*   x2_bf   = (u16*)(ws + 46137344);
    u16*   tgt_bf  = (u16*)(ws + 48234496);
    u16*   mem_bf  = (u16*)(ws + 50331648);
    u16*   dispT   = (u16*)(ws + 52428800);      // [4][128][1024]
    u16*   comb_bf = (u16*)(ws + 52690944);      // [4096][128]
    u16*   yT_bf   = (u16*)(ws + 52953088);      // [4][1024][128]
    float* slots   = ws + 53215232;              // 2,097,152
    u16*   w_sa_in = (u16*)(ws + 55312384);
    u16*   w_sa_out= (u16*)(ws + 56885248);
    u16*   w_ca_in = (u16*)(ws + 57409536);
    u16*   w_ca_out= (u16*)(ws + 58982400);
    u16*   w_lin   = (u16*)(ws + 59506688);
    u16*   phiT    = (u16*)(ws + 61603840);

    // ---- bf16 conversions (single launch) ----
    cvt_multi_kernel<<<10240, 256, 0, stream>>>(
        tgt, tgt_bf, memry, mem_bf, sa_in_w, w_sa_in, sa_out_w, w_sa_out,
        ca_in_w, w_ca_in, ca_out_w, w_ca_out, lin_w, w_lin);
    transpose_f32_bf16_kernel<<<dim3(4, 128, 1), 256, 0, stream>>>(phi, phiT, 4096, 128, 0, 0);

    // ---- Self-attention ----
    gemm256_mfma<0><<<dim3(12, 16, 1), 512, 0, stream>>>(
        tgt_bf, w_sa_in, sa_in_b, qkv_bf, 1024, 3072, 1024, 1024);
    flash_attn_kernel<<<dim3(16, 16, 4), 256, 0, stream>>>(
        qkv_bf, 3072, qkv_bf + 1024, 3072, qkv_bf + 2048, 3072, obuf_bf, S_);
    gemm_bt_mfma<0, 0, 1><<<dim3(8, 32, 1), 256, 0, stream>>>(
        obuf_bf, w_sa_out, sa_out_b, proj, 1024, 1024, 1024, 1024, 0, 0, 0);
    resid_ln_kernel<<<4096, 256, 0, stream>>>(tgt, proj, norm1_g, norm1_b, x1, x1_bf);

    // ---- Cross-attention ----
    u16* qca_bf = qkv_bf;
    u16* kvca_bf = qkv_bf + (size_t)4096 * 1024;
    gemm_bt_mfma<1, 0, 1><<<dim3(8, 32, 1), 256, 0, stream>>>(
        x1_bf, w_ca_in, ca_in_b, qca_bf, 1024, 1024, 1024, 1024, 0, 0, 0);
    gemm256_mfma<0><<<dim3(8, 16, 1), 512, 0, stream>>>(
        mem_bf, w_ca_in + (size_t)1024 * 1024, ca_in_b + 1024,
        kvca_bf, 1024, 2048, 1024, 1024);
    flash_attn_kernel<<<dim3(16, 16, 4), 256, 0, stream>>>(
        qca_bf, 1024, kvca_bf, 2048, kvca_bf + 1024, 2048, obuf_bf, S_);
    gemm_bt_mfma<0, 0, 1><<<dim3(8, 32, 1), 256, 0, stream>>>(
        obuf_bf, w_ca_out, ca_out_b, proj, 1024, 1024, 1024, 1024, 0, 0, 0);
    resid_ln_kernel<<<4096, 256, 0, stream>>>(x1, proj, norm2_g, norm2_b, x2, x2_bf);

    // ---- FF + SoftMoE ----
    gemm256_mfma<1><<<dim3(16, 16, 1), 512, 0, stream>>>(
        x2_bf, w_lin, lin_b, h_bf, 1024, 4096, 1024, 1024);
    gemm_bt_mfma<0, 0, 0><<<dim3(1, 32, 4), 256, 0, stream>>>(
        h_bf, phiT, nullptr, logitsP, 1024, 128, 4096, 4096,
        1024, 1024, (size_t)B_ * M_ * NE_);
    dispatch_softmax_T_kernel<<<dim3(NE_, B_), 256, 0, stream>>>(logitsP, dispT);
    combine_softmax_kernel<<<dim3(B_ * M_), 64, 0, stream>>>(logitsP, comb_bf);
    transpose_bf16_kernel<<<dim3(128, 32, 4), 256, 0, stream>>>(
        h_bf, hT_bf, 1024, 4096, (size_t)M_ * FF_, (size_t)M_ * FF_);
    gemm_bt_mfma<0, 0, 0><<<dim3(32, 1, 4), 256, 0, stream>>>(
        dispT, hT_bf, nullptr, slots, 1024, 4096, 1024, 1024,
        (size_t)NE_ * M_, (size_t)FF_ * M_, (size_t)NE_ * FF_);
    expert_partial_kernel<<<dim3(NE_, 8), 256, 0, stream>>>(slots, exp_w, part);
    reduce_yT_kernel<<<dim3(32, 4, 4), 256, 0, stream>>>(part, exp_b, yT_bf);
    gemm_bt_mfma<0, 0, 0><<<dim3(8, 8, 4), 256, 0, stream>>>(
        comb_bf, yT_bf, nullptr, proj, 128, 1024, 128, 128,
        (size_t)M_ * NE_, (size_t)D_ * NE_, (size_t)M_ * D_);
    resid_ln_kernel<<<4096, 256, 0, stream>>>(x2, proj, norm3_g, norm3_b,
                                              (float*)d_out, nullptr);
}

// Round 6
// 831.792 us; speedup vs baseline: 4.8023x; 1.0003x over previous
//
#include <hip/hip_runtime.h>
#include <cstdint>
#include <cstddef>

typedef unsigned short u16;
typedef unsigned int   u32;
typedef short bf16x8 __attribute__((ext_vector_type(8)));
typedef float f32x4  __attribute__((ext_vector_type(4)));
typedef u16   u16x8  __attribute__((ext_vector_type(8)));
typedef u16   u16x4  __attribute__((ext_vector_type(4)));
typedef u16   u16x2  __attribute__((ext_vector_type(2)));

constexpr int B_  = 4;
constexpr int M_  = 1024;
constexpr int S_  = 1024;
constexpr int D_  = 1024;
constexpr int H_  = 16;
constexpr int FF_ = 4096;
constexpr int NE_ = 128;

__device__ __forceinline__ u16 f2bf(float f) {
    u32 u = __builtin_bit_cast(u32, f);
    u = (u + 0x7fffu + ((u >> 16) & 1u)) >> 16;   // RNE
    return (u16)u;
}
__device__ __forceinline__ float bf2f(u16 u) {
    u32 x = ((u32)u) << 16;
    return __builtin_bit_cast(float, x);
}
__device__ __forceinline__ void gload_lds16(const u16* g, u16* l) {
    __builtin_amdgcn_global_load_lds(
        (const __attribute__((address_space(1))) u32*)g,
        (__attribute__((address_space(3))) u32*)l, 16, 0, 0);
}

// ---------------------------------------------------------------------------
// 256x256 deep-pipelined bf16 MFMA GEMM (T2+T3+T4+T5).
// Optionally also writes the transposed output HT[batch][col][row&1023]
// (batch = row>>10) directly from the accumulator fragments.
// ---------------------------------------------------------------------------
template<int RELU, int WRITE_HT>
__global__ __launch_bounds__(512, 1) void gemm256_mfma(
    const u16* __restrict__ A, const u16* __restrict__ W,
    const float* __restrict__ bias, u16* __restrict__ C,
    u16* __restrict__ HT,
    int K, int N, int lda, int ldw)
{
    __shared__ u16 lds[49152];                 // A bufs @0/8192/16384, B @+24576
    const int tid = threadIdx.x;
    const int w = tid >> 6, l = tid & 63;
    const int wr = w >> 2, wc = w & 3;
    const int fr = l & 15, g = l >> 4;
    const int bm = blockIdx.y * 256, bn = blockIdx.x * 256;

    const int qcol = (((l & 3) ^ ((l >> 3) & 3))) * 8;
    const int srow = w * 16 + (l >> 2);
    const u16* aG0 = A + (size_t)(bm + srow) * lda + qcol;
    const u16* aG1 = aG0 + (size_t)128 * lda;
    const u16* bG0 = W + (size_t)(bn + srow) * ldw + qcol;
    const u16* bG1 = bG0 + (size_t)128 * ldw;
    const int wofs = w * 512;

    const int qsw = (g ^ ((fr >> 1) & 3)) * 8;
    const int aoff = (wr * 128 + fr) * 32 + qsw;
    const int boff = (wc * 64 + fr) * 32 + qsw;

    f32x4 acc[8][4];
#pragma unroll
    for (int i = 0; i < 8; ++i)
#pragma unroll
        for (int j = 0; j < 4; ++j)
#pragma unroll
            for (int q = 0; q < 4; ++q) acc[i][j][q] = 0.f;

    gload_lds16(aG0, &lds[0 + wofs]);
    gload_lds16(aG1, &lds[4096 + wofs]);
    gload_lds16(bG0, &lds[24576 + wofs]);
    gload_lds16(bG1, &lds[24576 + 4096 + wofs]);
    aG0 += 32; aG1 += 32; bG0 += 32; bG1 += 32;
    gload_lds16(aG0, &lds[8192 + wofs]);
    gload_lds16(aG1, &lds[8192 + 4096 + wofs]);
    gload_lds16(bG0, &lds[32768 + wofs]);
    gload_lds16(bG1, &lds[32768 + 4096 + wofs]);
    aG0 += 32; aG1 += 32; bG0 += 32; bG1 += 32;
    asm volatile("s_waitcnt vmcnt(4)" ::: "memory");
    __builtin_amdgcn_s_barrier();
    __builtin_amdgcn_sched_barrier(0);

    int rb = 0;

#define G256_STEP(ISSUE_, VMOPT_)                                            \
  {                                                                          \
    const int wb_ = (rb >= 1) ? rb - 1 : 2;                                  \
    const u16* Ab_ = &lds[rb * 8192];                                        \
    const u16* Bb_ = &lds[24576 + rb * 8192];                                \
    u16* Aw_ = &lds[wb_ * 8192];                                             \
    u16* Bw_ = &lds[24576 + wb_ * 8192];                                     \
    bf16x8 af_[4], bf_[4];                                                   \
    _Pragma("unroll") for (int mf = 0; mf < 4; ++mf)                         \
      af_[mf] = *(const bf16x8*)(Ab_ + aoff + mf * 512);                     \
    _Pragma("unroll") for (int nf = 0; nf < 4; ++nf)                         \
      bf_[nf] = *(const bf16x8*)(Bb_ + boff + nf * 512);                     \
    if (ISSUE_) {                                                            \
      gload_lds16(aG0, Aw_ + wofs);                                          \
      gload_lds16(aG1, Aw_ + 4096 + wofs);                                   \
    }                                                                        \
    __builtin_amdgcn_s_barrier();                                            \
    __builtin_amdgcn_sched_barrier(0);                                       \
    __builtin_amdgcn_s_setprio(1);                                           \
    _Pragma("unroll") for (int mf = 0; mf < 4; ++mf)                         \
      _Pragma("unroll") for (int nf = 0; nf < 4; ++nf)                       \
        acc[mf][nf] = __builtin_amdgcn_mfma_f32_16x16x32_bf16(               \
            af_[mf], bf_[nf], acc[mf][nf], 0, 0, 0);                         \
    __builtin_amdgcn_s_setprio(0);                                           \
    __builtin_amdgcn_s_barrier();                                            \
    __builtin_amdgcn_sched_barrier(0);                                       \
    _Pragma("unroll") for (int mf = 0; mf < 4; ++mf)                         \
      af_[mf] = *(const bf16x8*)(Ab_ + aoff + 2048 + mf * 512);              \
    if (ISSUE_) {                                                            \
      gload_lds16(bG0, Bw_ + wofs);                                          \
      gload_lds16(bG1, Bw_ + 4096 + wofs);                                   \
      aG0 += 32; aG1 += 32; bG0 += 32; bG1 += 32;                            \
    }                                                                        \
    VMOPT_                                                                   \
    __builtin_amdgcn_s_barrier();                                            \
    __builtin_amdgcn_sched_barrier(0);                                       \
    __builtin_amdgcn_s_setprio(1);                                           \
    _Pragma("unroll") for (int mf = 0; mf < 4; ++mf)                         \
      _Pragma("unroll") for (int nf = 0; nf < 4; ++nf)                       \
        acc[mf + 4][nf] = __builtin_amdgcn_mfma_f32_16x16x32_bf16(           \
            af_[mf], bf_[nf], acc[mf + 4][nf], 0, 0, 0);                     \
    __builtin_amdgcn_s_setprio(0);                                           \
    __builtin_amdgcn_s_barrier();                                            \
    __builtin_amdgcn_sched_barrier(0);                                       \
    rb = (rb == 2) ? 0 : rb + 1;                                             \
  }

    const int nstep = K >> 5;
    for (int t = 0; t < nstep - 2; ++t) {
        G256_STEP(1, asm volatile("s_waitcnt vmcnt(4)" ::: "memory");)
    }
    G256_STEP(0, asm volatile("s_waitcnt vmcnt(0)" ::: "memory");)
    G256_STEP(0, )
#undef G256_STEP

    const int row0 = bm + wr * 128 + g * 4;
    const int col0 = bn + wc * 64 + fr;
#pragma unroll
    for (int nf = 0; nf < 4; ++nf) {
        const int col = col0 + nf * 16;
        const float bv = bias[col];
#pragma unroll
        for (int mf = 0; mf < 8; ++mf) {
            const int rowm = row0 + mf * 16;
            u16 o[4];
#pragma unroll
            for (int j = 0; j < 4; ++j) {
                float v = acc[mf][nf][j] + bv;
                if (RELU) v = fmaxf(v, 0.f);
                o[j] = f2bf(v);
                C[(size_t)(rowm + j) * N + col] = o[j];
            }
            if (WRITE_HT) {
                // HT[batch][col][row&1023], batch = row>>10; j-quad contiguous
                u16x4 pk; pk[0] = o[0]; pk[1] = o[1]; pk[2] = o[2]; pk[3] = o[3];
                *(u16x4*)&HT[(((size_t)(rowm >> 10)) * N + col) * 1024 + (rowm & 1023)] = pk;
            }
        }
    }
}

// ---------------------------------------------------------------------------
// bf16 MFMA GEMM (m97 structure): C[r][c] = sum_k A[r][k]*W[c][k] (+bias[c])
// ---------------------------------------------------------------------------
template<int OUT_BF16, int RELU, int HAS_BIAS>
__global__ __launch_bounds__(256) void gemm_bt_mfma(
    const u16* __restrict__ A, const u16* __restrict__ W,
    const float* __restrict__ bias, void* __restrict__ Cout,
    int K, int N, int lda, int ldw,
    size_t sA, size_t sW, size_t sC)
{
    __shared__ u16 As[128 * 32];
    __shared__ u16 Bs[128 * 32];
    const int tid = threadIdx.x;
    const int w = tid >> 6, l = tid & 63;
    const int bm = blockIdx.y * 128, bn = blockIdx.x * 128;
    const u16* Ab = A + (size_t)blockIdx.z * sA;
    const u16* Wb = W + (size_t)blockIdx.z * sW;

    const int wr = w >> 1, wc = w & 1;
    const int sr = l >> 2;
    const int sk = (l & 3) * 8;
    const u16* aG0 = Ab + (size_t)(bm + w * 16 + sr) * lda + sk;
    const u16* aG1 = Ab + (size_t)(bm + (w + 4) * 16 + sr) * lda + sk;
    const u16* bG0 = Wb + (size_t)(bn + w * 16 + sr) * ldw + sk;
    const u16* bG1 = Wb + (size_t)(bn + (w + 4) * 16 + sr) * ldw + sk;
    u16* aL0 = &As[w * 512];
    u16* aL1 = &As[(w + 4) * 512];
    u16* bL0 = &Bs[w * 512];
    u16* bL1 = &Bs[(w + 4) * 512];

    const int fr = l & 15;
    const int fk = (l >> 4) * 8;

    f32x4 acc[4][4];
#pragma unroll
    for (int i = 0; i < 4; ++i)
#pragma unroll
        for (int j = 0; j < 4; ++j)
#pragma unroll
            for (int q = 0; q < 4; ++q) acc[i][j][q] = 0.f;

    for (int k0 = 0; k0 < K; k0 += 32) {
        __syncthreads();
        gload_lds16(aG0, aL0);
        gload_lds16(aG1, aL1);
        gload_lds16(bG0, bL0);
        gload_lds16(bG1, bL1);
        aG0 += 32; aG1 += 32; bG0 += 32; bG1 += 32;
        __syncthreads();
        bf16x8 af[4], bfr[4];
#pragma unroll
        for (int m = 0; m < 4; ++m)
            af[m] = *(const bf16x8*)&As[(wr * 64 + m * 16 + fr) * 32 + fk];
#pragma unroll
        for (int n = 0; n < 4; ++n)
            bfr[n] = *(const bf16x8*)&Bs[(wc * 64 + n * 16 + fr) * 32 + fk];
#pragma unroll
        for (int m = 0; m < 4; ++m)
#pragma unroll
            for (int n = 0; n < 4; ++n)
                acc[m][n] = __builtin_amdgcn_mfma_f32_16x16x32_bf16(
                    af[m], bfr[n], acc[m][n], 0, 0, 0);
    }

    const int row0 = bm + wr * 64 + (l >> 4) * 4;
    const int col0 = bn + wc * 64;
#pragma unroll
    for (int n = 0; n < 4; ++n) {
        const int col = col0 + n * 16 + fr;
        float bv = 0.f;
        if (HAS_BIAS) bv = bias[col];
#pragma unroll
        for (int m = 0; m < 4; ++m) {
            const int row = row0 + m * 16;
#pragma unroll
            for (int j = 0; j < 4; ++j) {
                float v = acc[m][n][j] + bv;
                if (RELU) v = fmaxf(v, 0.f);
                const size_t idx = (size_t)blockIdx.z * sC + (size_t)(row + j) * N + col;
                if (OUT_BF16) ((u16*)Cout)[idx] = f2bf(v);
                else          ((float*)Cout)[idx] = v;
            }
        }
    }
}

// ---------------------------------------------------------------------------
// Flash attention fwd v2: double-buffered LDS, async reg-staged K/V (T14),
// direct Q fragment load, one barrier per KV-tile, defer-max (T13).
// ---------------------------------------------------------------------------
__global__ __launch_bounds__(256) void flash_attn_kernel(
    const u16* __restrict__ Q, int qs,
    const u16* __restrict__ K, int ks,
    const u16* __restrict__ V, int vs,
    u16* __restrict__ O, int Slen)
{
    __shared__ u16 Ks[2][64][72];
    __shared__ u16 Vt[2][64][72];
    __shared__ u16 Pw[4][16][72];
    const int b = blockIdx.z, hh = blockIdx.y;
    const int m0 = blockIdx.x * 64;
    const int tid = threadIdx.x;
    const int w = tid >> 6, l = tid & 63;
    const int lq = l & 15, g = l >> 4;

    // Q directly into fragments (row = w*16+lq, k = g*8..+8 / 32+g*8..+8)
    bf16x8 qf[2];
    {
        const u16* qp = Q + ((size_t)b * M_ + m0 + w * 16 + lq) * qs + hh * 64;
        u16x8 v0 = *(const u16x8*)(qp + g * 8);
        u16x8 v1 = *(const u16x8*)(qp + 32 + g * 8);
        u16x8 o0, o1;
#pragma unroll
        for (int i = 0; i < 8; ++i) {
            o0[i] = f2bf(bf2f(v0[i]) * 0.125f);
            o1[i] = f2bf(bf2f(v1[i]) * 0.125f);
        }
        qf[0] = __builtin_bit_cast(bf16x8, o0);
        qf[1] = __builtin_bit_cast(bf16x8, o1);
    }

    f32x4 acc_o[4];
#pragma unroll
    for (int nb = 0; nb < 4; ++nb)
#pragma unroll
        for (int j = 0; j < 4; ++j) acc_o[nb][j] = 0.f;
    float m_run = -1e30f, l_run = 0.f;

    const int kp = tid & 31, dg = tid >> 5;          // V: rows 2kp,2kp+1; cols dg*8..+8
    const int krow = tid >> 2, kcg = (tid & 3) * 16; // K: row krow, cols kcg..+16

    const int nt = Slen >> 6;
    u16x8 kv0, kv1, va, vb;                          // staged tile registers

#define ATT_LOAD(T_)                                                          \
    {                                                                         \
        const u16* kpp = K + ((size_t)b * Slen + (T_) * 64 + krow) * ks + hh * 64 + kcg; \
        kv0 = *(const u16x8*)kpp;                                             \
        kv1 = *(const u16x8*)(kpp + 8);                                       \
        const u16* vp0 = V + ((size_t)b * Slen + (T_) * 64 + 2 * kp) * vs + hh * 64 + dg * 8; \
        va = *(const u16x8*)vp0;                                              \
        vb = *(const u16x8*)(vp0 + vs);                                       \
    }
#define ATT_WRITE(BUF_)                                                       \
    {                                                                         \
        *(u16x8*)&Ks[BUF_][krow][kcg]     = kv0;                              \
        *(u16x8*)&Ks[BUF_][krow][kcg + 8] = kv1;                              \
        _Pragma("unroll") for (int i = 0; i < 8; ++i) {                       \
            u16x2 pk; pk[0] = va[i]; pk[1] = vb[i];                           \
            *(u16x2*)&Vt[BUF_][dg * 8 + i][2 * kp] = pk;                      \
        }                                                                     \
    }

    ATT_LOAD(0)
    ATT_WRITE(0)
    __syncthreads();

    for (int t = 0; t < nt; ++t) {
        if (t + 1 < nt) ATT_LOAD(t + 1)
        const int cb = t & 1;

        // S^T = K @ Q^T
        f32x4 s4[4];
#pragma unroll
        for (int mb = 0; mb < 4; ++mb) {
            f32x4 z = {0.f, 0.f, 0.f, 0.f};
            bf16x8 a0 = *(const bf16x8*)&Ks[cb][mb * 16 + lq][g * 8];
            bf16x8 a1 = *(const bf16x8*)&Ks[cb][mb * 16 + lq][32 + g * 8];
            z = __builtin_amdgcn_mfma_f32_16x16x32_bf16(a0, qf[0], z, 0, 0, 0);
            z = __builtin_amdgcn_mfma_f32_16x16x32_bf16(a1, qf[1], z, 0, 0, 0);
            s4[mb] = z;
        }

        // online softmax with defer-max
        float pm = -1e30f;
#pragma unroll
        for (int mb = 0; mb < 4; ++mb)
#pragma unroll
            for (int j = 0; j < 4; ++j) pm = fmaxf(pm, s4[mb][j]);
        pm = fmaxf(pm, __shfl_xor(pm, 16));
        pm = fmaxf(pm, __shfl_xor(pm, 32));

        u16 pbf[4][4];
        float ls = 0.f;
        if (__all(pm - m_run <= 8.f)) {
#pragma unroll
            for (int mb = 0; mb < 4; ++mb)
#pragma unroll
                for (int j = 0; j < 4; ++j) {
                    float p = __expf(s4[mb][j] - m_run);
                    ls += p;
                    pbf[mb][j] = f2bf(p);
                }
            ls += __shfl_xor(ls, 16);
            ls += __shfl_xor(ls, 32);
            l_run += ls;
        } else {
            const float m_new = fmaxf(m_run, pm);
            const float alpha = __expf(m_run - m_new);
#pragma unroll
            for (int mb = 0; mb < 4; ++mb)
#pragma unroll
                for (int j = 0; j < 4; ++j) {
                    float p = __expf(s4[mb][j] - m_new);
                    ls += p;
                    pbf[mb][j] = f2bf(p);
                }
            ls += __shfl_xor(ls, 16);
            ls += __shfl_xor(ls, 32);
            l_run = l_run * alpha + ls;
            m_run = m_new;
            float al[4];
#pragma unroll
            for (int j = 0; j < 4; ++j) al[j] = __shfl(alpha, 4 * g + j);
#pragma unroll
            for (int nb = 0; nb < 4; ++nb)
#pragma unroll
                for (int j = 0; j < 4; ++j) acc_o[nb][j] *= al[j];
        }

        // P -> per-wave LDS (same wave consumes; lgkmcnt handled by compiler)
#pragma unroll
        for (int mb = 0; mb < 4; ++mb) {
            u16x4 pk;
            pk[0] = pbf[mb][0]; pk[1] = pbf[mb][1];
            pk[2] = pbf[mb][2]; pk[3] = pbf[mb][3];
            *(u16x4*)&Pw[w][lq][mb * 16 + g * 4] = pk;
        }

        // PV
#pragma unroll
        for (int kc = 0; kc < 2; ++kc) {
            bf16x8 pa = *(const bf16x8*)&Pw[w][lq][kc * 32 + g * 8];
#pragma unroll
            for (int nb = 0; nb < 4; ++nb) {
                bf16x8 bv = *(const bf16x8*)&Vt[cb][nb * 16 + lq][kc * 32 + g * 8];
                acc_o[nb] = __builtin_amdgcn_mfma_f32_16x16x32_bf16(pa, bv, acc_o[nb], 0, 0, 0);
            }
        }

        if (t + 1 < nt) ATT_WRITE((t + 1) & 1)
        __syncthreads();
    }
#undef ATT_LOAD
#undef ATT_WRITE

    float linv[4];
#pragma unroll
    for (int j = 0; j < 4; ++j) linv[j] = 1.f / __shfl(l_run, 4 * g + j);
#pragma unroll
    for (int nb = 0; nb < 4; ++nb)
#pragma unroll
        for (int j = 0; j < 4; ++j) {
            const size_t row = (size_t)b * M_ + m0 + w * 16 + 4 * g + j;
            O[row * D_ + hh * 64 + nb * 16 + lq] = f2bf(acc_o[nb][j] * linv[j]);
        }
}

// ---------------------------------------------------------------------------
// One-shot f32->bf16 for all 7 tensors.
// ---------------------------------------------------------------------------
__global__ __launch_bounds__(256) void cvt_multi_kernel(
    const float* __restrict__ s0, u16* __restrict__ d0,
    const float* __restrict__ s1, u16* __restrict__ d1,
    const float* __restrict__ s2, u16* __restrict__ d2,
    const float* __restrict__ s3, u16* __restrict__ d3,
    const float* __restrict__ s4, u16* __restrict__ d4,
    const float* __restrict__ s5, u16* __restrict__ d5,
    const float* __restrict__ s6, u16* __restrict__ d6)
{
    int blk = blockIdx.x;
    const float* s; u16* d;
    if      (blk < 2048) { s = s0; d = d0; }
    else if (blk < 4096) { s = s1; d = d1; blk -= 2048; }
    else if (blk < 5632) { s = s2; d = d2; blk -= 4096; }
    else if (blk < 6144) { s = s3; d = d3; blk -= 5632; }
    else if (blk < 7680) { s = s4; d = d4; blk -= 6144; }
    else if (blk < 8192) { s = s5; d = d5; blk -= 7680; }
    else                 { s = s6; d = d6; blk -= 8192; }
    const size_t i = ((size_t)blk * 256 + threadIdx.x) * 8;
    float4 a = *(const float4*)(s + i);
    float4 b = *(const float4*)(s + i + 4);
    u16x8 o;
    o[0] = f2bf(a.x); o[1] = f2bf(a.y); o[2] = f2bf(a.z); o[3] = f2bf(a.w);
    o[4] = f2bf(b.x); o[5] = f2bf(b.y); o[6] = f2bf(b.z); o[7] = f2bf(b.w);
    *(u16x8*)(d + i) = o;
}

// ---------------------------------------------------------------------------
// Transpose (R x C) f32 -> (C x R) bf16, batched over z.
// ---------------------------------------------------------------------------
__global__ __launch_bounds__(256) void transpose_f32_bf16_kernel(
    const float* __restrict__ src, u16* __restrict__ dst, int R, int C,
    size_t sI, size_t sO)
{
    __shared__ u16 t[32][33];
    src += (size_t)blockIdx.z * sI;
    dst += (size_t)blockIdx.z * sO;
    const int c0 = blockIdx.x * 32, r0 = blockIdx.y * 32;
    const int x = threadIdx.x & 31, y = threadIdx.x >> 5;
    for (int i = y; i < 32; i += 8)
        t[i][x] = f2bf(src[(size_t)(r0 + i) * C + c0 + x]);
    __syncthreads();
    for (int i = y; i < 32; i += 8)
        dst[(size_t)(c0 + i) * R + r0 + x] = t[x][i];
}

// ---------------------------------------------------------------------------
// y = LayerNorm(X + R); writes f32 Y and (optionally) bf16 Ybf.
// ---------------------------------------------------------------------------
__global__ __launch_bounds__(256) void resid_ln_kernel(
    const float* __restrict__ X, const float* __restrict__ R,
    const float* __restrict__ g, const float* __restrict__ bt,
    float* __restrict__ Y, u16* __restrict__ Ybf)
{
    __shared__ float s1[4], s2[4];
    const size_t row = blockIdx.x;
    const int tid = threadIdx.x;
    const float4 x4 = *(const float4*)(X + row * 1024 + tid * 4);
    const float4 r4 = *(const float4*)(R + row * 1024 + tid * 4);
    float v[4] = {x4.x + r4.x, x4.y + r4.y, x4.z + r4.z, x4.w + r4.w};
    float s = v[0] + v[1] + v[2] + v[3];
    float q = v[0] * v[0] + v[1] * v[1] + v[2] * v[2] + v[3] * v[3];
#pragma unroll
    for (int off = 32; off; off >>= 1) {
        s += __shfl_xor(s, off);
        q += __shfl_xor(q, off);
    }
    if ((tid & 63) == 0) { s1[tid >> 6] = s; s2[tid >> 6] = q; }
    __syncthreads();
    s = s1[0] + s1[1] + s1[2] + s1[3];
    q = s2[0] + s2[1] + s2[2] + s2[3];
    const float mu = s * (1.f / 1024.f);
    const float var = q * (1.f / 1024.f) - mu * mu;
    const float rinv = rsqrtf(var + 1e-5f);
    const float4 g4 = *(const float4*)(g + tid * 4);
    const float4 b4 = *(const float4*)(bt + tid * 4);
    float o[4];
    o[0] = (v[0] - mu) * rinv * g4.x + b4.x;
    o[1] = (v[1] - mu) * rinv * g4.y + b4.y;
    o[2] = (v[2] - mu) * rinv * g4.z + b4.z;
    o[3] = (v[3] - mu) * rinv * g4.w + b4.w;
    *(float4*)(Y + row * 1024 + tid * 4) = *(float4*)o;
    if (Ybf) {
        u16x4 ob;
        ob[0] = f2bf(o[0]); ob[1] = f2bf(o[1]);
        ob[2] = f2bf(o[2]); ob[3] = f2bf(o[3]);
        *(u16x4*)(Ybf + row * 1024 + tid * 4) = ob;
    }
}

// ---------------------------------------------------------------------------
// dispatch softmax over m (sums 4 split-K partials), bf16 transposed out.
// ---------------------------------------------------------------------------
__global__ __launch_bounds__(256) void dispatch_softmax_T_kernel(
    const float* __restrict__ logitsP, u16* __restrict__ dispT)
{
    __shared__ float red[4];
    constexpr size_t CH = (size_t)B_ * M_ * NE_;
    const int n = blockIdx.x, b = blockIdx.y;
    u16* O = dispT + ((size_t)b * NE_ + n) * M_;
    const int tid = threadIdx.x;
    float v[4];
#pragma unroll
    for (int i = 0; i < 4; ++i) {
        const size_t idx = (size_t)(b * M_ + tid + 256 * i) * NE_ + n;
        v[i] = logitsP[idx] + logitsP[CH + idx] + logitsP[2 * CH + idx] + logitsP[3 * CH + idx];
    }
    float mx = fmaxf(fmaxf(v[0], v[1]), fmaxf(v[2], v[3]));
#pragma unroll
    for (int off = 32; off; off >>= 1) mx = fmaxf(mx, __shfl_xor(mx, off));
    if ((tid & 63) == 0) red[tid >> 6] = mx;
    __syncthreads();
    mx = fmaxf(fmaxf(red[0], red[1]), fmaxf(red[2], red[3]));
    __syncthreads();
    float e[4], s = 0.f;
#pragma unroll
    for (int i = 0; i < 4; ++i) { e[i] = __expf(v[i] - mx); s += e[i]; }
#pragma unroll
    for (int off = 32; off; off >>= 1) s += __shfl_xor(s, off);
    if ((tid & 63) == 0) red[tid >> 6] = s;
    __syncthreads();
    s = red[0] + red[1] + red[2] + red[3];
    const float inv = 1.f / s;
#pragma unroll
    for (int i = 0; i < 4; ++i) O[tid + 256 * i] = f2bf(e[i] * inv);
}

// ---------------------------------------------------------------------------
// combine softmax over 128 experts (sums partials), bf16 out.
// ---------------------------------------------------------------------------
__global__ __launch_bounds__(64) void combine_softmax_kernel(
    const float* __restrict__ logitsP, u16* __restrict__ comb)
{
    constexpr size_t CH = (size_t)B_ * M_ * NE_;
    const size_t row = blockIdx.x;
    const int lane = threadIdx.x;
    const size_t i0 = row * NE_ + lane;
    const size_t i1 = i0 + 64;
    float a = logitsP[i0] + logitsP[CH + i0] + logitsP[2 * CH + i0] + logitsP[3 * CH + i0];
    float c = logitsP[i1] + logitsP[CH + i1] + logitsP[2 * CH + i1] + logitsP[3 * CH + i1];
    float mx = fmaxf(a, c);
#pragma unroll
    for (int off = 32; off; off >>= 1) mx = fmaxf(mx, __shfl_xor(mx, off));
    float e0 = __expf(a - mx), e1 = __expf(c - mx);
    float s = e0 + e1;
#pragma unroll
    for (int off = 32; off; off >>= 1) s += __shfl_xor(s, off);
    const float inv = 1.f / s;
    comb[row * NE_ + lane]      = f2bf(e0 * inv);
    comb[row * NE_ + lane + 64] = f2bf(e1 * inv);
}

// ---------------------------------------------------------------------------
// Expert partials: part[c][b][n][d] = sum_{f in chunk c} slots[b][n][f]*w[n][f][d]
// ---------------------------------------------------------------------------
__global__ __launch_bounds__(256) void expert_partial_kernel(
    const float* __restrict__ slots, const float* __restrict__ exp_w,
    float* __restrict__ part)
{
    __shared__ float sl[4][512];
    const int n = blockIdx.x;
    const int c = blockIdx.y;
    const int f0 = c * 512;
    const int t = threadIdx.x;
    for (int i = t; i < 2048; i += 256) {
        const int b = i >> 9, f = i & 511;
        sl[b][f] = slots[((size_t)b * NE_ + n) * FF_ + f0 + f];
    }
    __syncthreads();
    const int d4 = t * 4;
    const float* wp = exp_w + ((size_t)n * FF_ + f0) * D_ + d4;
    f32x4 acc[4];
#pragma unroll
    for (int b = 0; b < 4; ++b)
#pragma unroll
        for (int j = 0; j < 4; ++j) acc[b][j] = 0.f;
#pragma unroll 4
    for (int f = 0; f < 512; ++f) {
        const float4 w4 = *(const float4*)wp;
        wp += D_;
#pragma unroll
        for (int b = 0; b < 4; ++b) {
            const float s = sl[b][f];
            acc[b][0] = fmaf(s, w4.x, acc[b][0]);
            acc[b][1] = fmaf(s, w4.y, acc[b][1]);
            acc[b][2] = fmaf(s, w4.z, acc[b][2]);
            acc[b][3] = fmaf(s, w4.w, acc[b][3]);
        }
    }
#pragma unroll
    for (int b = 0; b < 4; ++b)
        *(f32x4*)&part[(((size_t)c * 4 + b) * NE_ + n) * D_ + d4] = acc[b];
}

// ---------------------------------------------------------------------------
// Reduce 8 partials + exp_b, emit yT[b][d][n] bf16 (fused transpose).
// ---------------------------------------------------------------------------
__global__ __launch_bounds__(256) void reduce_yT_kernel(
    const float* __restrict__ part, const float* __restrict__ exp_b,
    u16* __restrict__ yT)
{
    __shared__ float tile[32][33];
    const int d0 = blockIdx.x * 32, n0 = blockIdx.y * 32, b = blockIdx.z;
    const int x = threadIdx.x & 31, y = threadIdx.x >> 5;
    for (int i = y; i < 32; i += 8) {
        const int n = n0 + i;
        float s = exp_b[(size_t)n * D_ + d0 + x];
#pragma unroll
        for (int c = 0; c < 8; ++c)
            s += part[(((size_t)c * 4 + b) * NE_ + n) * D_ + d0 + x];
        tile[i][x] = s;
    }
    __syncthreads();
    for (int i = y; i < 32; i += 8)
        yT[((size_t)b * D_ + d0 + i) * NE_ + n0 + x] = f2bf(tile[x][i]);
}

// ---------------------------------------------------------------------------
extern "C" void kernel_launch(void* const* d_in, const int* in_sizes, int n_in,
                              void* d_out, int out_size, void* d_ws, size_t ws_size,
                              hipStream_t stream)
{
    const float* tgt      = (const float*)d_in[0];
    const float* memry    = (const float*)d_in[1];
    const float* sa_in_w  = (const float*)d_in[2];
    const float* sa_in_b  = (const float*)d_in[3];
    const float* sa_out_w = (const float*)d_in[4];
    const float* sa_out_b = (const float*)d_in[5];
    const float* ca_in_w  = (const float*)d_in[6];
    const float* ca_in_b  = (const float*)d_in[7];
    const float* ca_out_w = (const float*)d_in[8];
    const float* ca_out_b = (const float*)d_in[9];
    const float* norm1_g  = (const float*)d_in[10];
    const float* norm1_b  = (const float*)d_in[11];
    const float* norm2_g  = (const float*)d_in[12];
    const float* norm2_b  = (const float*)d_in[13];
    const float* norm3_g  = (const float*)d_in[14];
    const float* norm3_b  = (const float*)d_in[15];
    const float* lin_w    = (const float*)d_in[16];
    const float* lin_b    = (const float*)d_in[17];
    const float* phi      = (const float*)d_in[18];
    const float* exp_w    = (const float*)d_in[19];
    const float* exp_b    = (const float*)d_in[20];

    float* ws = (float*)d_ws;
    u16*   qkv_bf  = (u16*)(ws);                 // [4096][3072] u16 (CA reuse)
    float* proj    = ws + 6291456;
    float* x1      = ws + 10485760;
    float* x2      = ws + 14680064;
    float* logitsP = ws + 18874368;              // 4 x 524,288
    float* part    = ws + 20971520;              // 4,194,304
    u16*   h_bf    = (u16*)(ws + 25165824);      // [4096][4096]
    u16*   hT_bf   = (u16*)(ws + 33554432);      // [4][4096][1024]
    u16*   obuf_bf = (u16*)(ws + 41943040);      // [4096][1024]
    u16*   x1_bf   = (u16*)(ws + 44040192);
    u16*   x2_bf   = (u16*)(ws + 46137344);
    u16*   tgt_bf  = (u16*)(ws + 48234496);
    u16*   mem_bf  = (u16*)(ws + 50331648);
    u16*   dispT   = (u16*)(ws + 52428800);      // [4][128][1024]
    u16*   comb_bf = (u16*)(ws + 52690944);      // [4096][128]
    u16*   yT_bf   = (u16*)(ws + 52953088);      // [4][1024][128]
    float* slots   = ws + 53215232;              // 2,097,152
    u16*   w_sa_in = (u16*)(ws + 55312384);
    u16*   w_sa_out= (u16*)(ws + 56885248);
    u16*   w_ca_in = (u16*)(ws + 57409536);
    u16*   w_ca_out= (u16*)(ws + 58982400);
    u16*   w_lin   = (u16*)(ws + 59506688);
    u16*   phiT    = (u16*)(ws + 61603840);

    // ---- bf16 conversions (single launch) ----
    cvt_multi_kernel<<<10240, 256, 0, stream>>>(
        tgt, tgt_bf, memry, mem_bf, sa_in_w, w_sa_in, sa_out_w, w_sa_out,
        ca_in_w, w_ca_in, ca_out_w, w_ca_out, lin_w, w_lin);
    transpose_f32_bf16_kernel<<<dim3(4, 128, 1), 256, 0, stream>>>(phi, phiT, 4096, 128, 0, 0);

    // ---- Self-attention ----
    gemm256_mfma<0, 0><<<dim3(12, 16, 1), 512, 0, stream>>>(
        tgt_bf, w_sa_in, sa_in_b, qkv_bf, nullptr, 1024, 3072, 1024, 1024);
    flash_attn_kernel<<<dim3(16, 16, 4), 256, 0, stream>>>(
        qkv_bf, 3072, qkv_bf + 1024, 3072, qkv_bf + 2048, 3072, obuf_bf, S_);
    gemm_bt_mfma<0, 0, 1><<<dim3(8, 32, 1), 256, 0, stream>>>(
        obuf_bf, w_sa_out, sa_out_b, proj, 1024, 1024, 1024, 1024, 0, 0, 0);
    resid_ln_kernel<<<4096, 256, 0, stream>>>(tgt, proj, norm1_g, norm1_b, x1, x1_bf);

    // ---- Cross-attention ----
    u16* qca_bf = qkv_bf;
    u16* kvca_bf = qkv_bf + (size_t)4096 * 1024;
    gemm_bt_mfma<1, 0, 1><<<dim3(8, 32, 1), 256, 0, stream>>>(
        x1_bf, w_ca_in, ca_in_b, qca_bf, 1024, 1024, 1024, 1024, 0, 0, 0);
    gemm256_mfma<0, 0><<<dim3(8, 16, 1), 512, 0, stream>>>(
        mem_bf, w_ca_in + (size_t)1024 * 1024, ca_in_b + 1024,
        kvca_bf, nullptr, 1024, 2048, 1024, 1024);
    flash_attn_kernel<<<dim3(16, 16, 4), 256, 0, stream>>>(
        qca_bf, 1024, kvca_bf, 2048, kvca_bf + 1024, 2048, obuf_bf, S_);
    gemm_bt_mfma<0, 0, 1><<<dim3(8, 32, 1), 256, 0, stream>>>(
        obuf_bf, w_ca_out, ca_out_b, proj, 1024, 1024, 1024, 1024, 0, 0, 0);
    resid_ln_kernel<<<4096, 256, 0, stream>>>(x1, proj, norm2_g, norm2_b, x2, x2_bf);

    // ---- FF + SoftMoE ----
    // FF GEMM also emits hT directly (fused transpose write)
    gemm256_mfma<1, 1><<<dim3(16, 16, 1), 512, 0, stream>>>(
        x2_bf, w_lin, lin_b, h_bf, hT_bf, 1024, 4096, 1024, 1024);
    gemm_bt_mfma<0, 0, 0><<<dim3(1, 32, 4), 256, 0, stream>>>(
        h_bf, phiT, nullptr, logitsP, 1024, 128, 4096, 4096,
        1024, 1024, (size_t)B_ * M_ * NE_);
    dispatch_softmax_T_kernel<<<dim3(NE_, B_), 256, 0, stream>>>(logitsP, dispT);
    combine_softmax_kernel<<<dim3(B_ * M_), 64, 0, stream>>>(logitsP, comb_bf);
    gemm_bt_mfma<0, 0, 0><<<dim3(32, 1, 4), 256, 0, stream>>>(
        dispT, hT_bf, nullptr, slots, 1024, 4096, 1024, 1024,
        (size_t)NE_ * M_, (size_t)FF_ * M_, (size_t)NE_ * FF_);
    expert_partial_kernel<<<dim3(NE_, 8), 256, 0, stream>>>(slots, exp_w, part);
    reduce_yT_kernel<<<dim3(32, 4, 4), 256, 0, stream>>>(part, exp_b, yT_bf);
    gemm_bt_mfma<0, 0, 0><<<dim3(8, 8, 4), 256, 0, stream>>>(
        comb_bf, yT_bf, nullptr, proj, 128, 1024, 128, 128,
        (size_t)M_ * NE_, (size_t)D_ * NE_, (size_t)M_ * D_);
    resid_ln_kernel<<<4096, 256, 0, stream>>>(x2, proj, norm3_g, norm3_b,
                                              (float*)d_out, nullptr);
}

// Round 7
// 821.444 us; speedup vs baseline: 4.8628x; 1.0126x over previous
//
#include <hip/hip_runtime.h>
#include <cstdint>
#include <cstddef>

typedef unsigned short u16;
typedef unsigned int   u32;
typedef short bf16x8 __attribute__((ext_vector_type(8)));
typedef float f32x4  __attribute__((ext_vector_type(4)));
typedef u16   u16x8  __attribute__((ext_vector_type(8)));
typedef u16   u16x4  __attribute__((ext_vector_type(4)));
typedef u16   u16x2  __attribute__((ext_vector_type(2)));

constexpr int B_  = 4;
constexpr int M_  = 1024;
constexpr int S_  = 1024;
constexpr int D_  = 1024;
constexpr int H_  = 16;
constexpr int FF_ = 4096;
constexpr int NE_ = 128;

__device__ __forceinline__ u16 f2bf(float f) {
    u32 u = __builtin_bit_cast(u32, f);
    u = (u + 0x7fffu + ((u >> 16) & 1u)) >> 16;   // RNE
    return (u16)u;
}
__device__ __forceinline__ float bf2f(u16 u) {
    u32 x = ((u32)u) << 16;
    return __builtin_bit_cast(float, x);
}
__device__ __forceinline__ void gload_lds16(const u16* g, u16* l) {
    __builtin_amdgcn_global_load_lds(
        (const __attribute__((address_space(1))) u32*)g,
        (__attribute__((address_space(3))) u32*)l, 16, 0, 0);
}

// ---------------------------------------------------------------------------
// Occupancy-first bf16 MFMA GEMM: C[r][c] = sum_k A[r][k]*W[c][k] (+bias[c]).
// BM=64, BN=128, BK=32, 256 thr = 4 waves (wave w -> cols w*32..+32).
// 12 KB LDS + ~100 VGPR -> 4-5 blocks/CU resident: latency hiding via TLP.
// Chunk swizzle q_phys = q ^ ((row>>1)&3) via pre-swizzled global source
// (linear gload_lds dest, rule #21) -> 2-way (free) ds_read_b128 banks.
// z-batched via sA/sW/sC element strides (also used for split-K partials).
// Optional HT write: HT[(row>>10)*N + col][row&1023] (fused transpose).
// ---------------------------------------------------------------------------
template<int OUT_BF16, int RELU, int HAS_BIAS, int WRITE_HT>
__global__ __launch_bounds__(256) void gemm64_mfma(
    const u16* __restrict__ A, const u16* __restrict__ W,
    const float* __restrict__ bias, void* __restrict__ Cout,
    u16* __restrict__ HT,
    int K, int N, int lda, int ldw,
    size_t sA, size_t sW, size_t sC)
{
    __shared__ u16 As[64 * 32];     // 4 KB
    __shared__ u16 Bs[128 * 32];    // 8 KB
    const int tid = threadIdx.x;
    const int w = tid >> 6, l = tid & 63;
    const int fr = l & 15, g = l >> 4;
    const int bm = blockIdx.y * 64, bn = blockIdx.x * 128;
    const u16* Ab = A + (size_t)blockIdx.z * sA;
    const u16* Wb = W + (size_t)blockIdx.z * sW;

    // staging: thread t stages 16B; LDS row t>>2, phys chunk t&3.
    // logical chunk = (t&3) ^ ((row>>1)&3) -> pre-swizzle the global column.
    const int qcol = ((l & 3) ^ ((l >> 3) & 3)) * 8;
    const int srow = w * 16 + (l >> 2);
    const u16* aG  = Ab + (size_t)(bm + srow) * lda + qcol;
    const u16* bG0 = Wb + (size_t)(bn + srow) * ldw + qcol;
    const u16* bG1 = bG0 + (size_t)64 * ldw;
    u16* aL  = &As[w * 512];
    u16* bL0 = &Bs[w * 512];
    u16* bL1 = &Bs[2048 + w * 512];

    // fragment read: swizzled chunk (row>>1)&3 == (fr>>1)&3 (m*16, n*16, w*32
    // all ≡ 0 mod 4 after >>1)
    const int qsw = (g ^ ((fr >> 1) & 3)) * 8;

    f32x4 acc[4][2];
#pragma unroll
    for (int m = 0; m < 4; ++m)
#pragma unroll
        for (int n = 0; n < 2; ++n)
#pragma unroll
            for (int q = 0; q < 4; ++q) acc[m][n][q] = 0.f;

    for (int k0 = 0; k0 < K; k0 += 32) {
        __syncthreads();                    // prev reads done before overwrite
        gload_lds16(aG,  aL);
        gload_lds16(bG0, bL0);
        gload_lds16(bG1, bL1);
        aG += 32; bG0 += 32; bG1 += 32;
        __syncthreads();                    // drains vmcnt(0): tiles ready
        bf16x8 af[4], bf[2];
#pragma unroll
        for (int m = 0; m < 4; ++m)
            af[m] = *(const bf16x8*)&As[(m * 16 + fr) * 32 + qsw];
#pragma unroll
        for (int n = 0; n < 2; ++n)
            bf[n] = *(const bf16x8*)&Bs[(w * 32 + n * 16 + fr) * 32 + qsw];
#pragma unroll
        for (int m = 0; m < 4; ++m)
#pragma unroll
            for (int n = 0; n < 2; ++n)
                acc[m][n] = __builtin_amdgcn_mfma_f32_16x16x32_bf16(
                    af[m], bf[n], acc[m][n], 0, 0, 0);
    }

    // epilogue: D row = (l>>4)*4 + j (+ m*16), col = l&15 (+ n*16 + w*32)
    const int row0 = bm + g * 4;
#pragma unroll
    for (int n = 0; n < 2; ++n) {
        const int col = bn + w * 32 + n * 16 + fr;
        float bv = 0.f;
        if (HAS_BIAS) bv = bias[col];
#pragma unroll
        for (int m = 0; m < 4; ++m) {
            const int rowm = row0 + m * 16;
            u16 o[4];
#pragma unroll
            for (int j = 0; j < 4; ++j) {
                float v = acc[m][n][j] + bv;
                if (RELU) v = fmaxf(v, 0.f);
                const size_t idx = (size_t)blockIdx.z * sC +
                                   (size_t)(rowm + j) * N + col;
                if (OUT_BF16) { o[j] = f2bf(v); ((u16*)Cout)[idx] = o[j]; }
                else          { ((float*)Cout)[idx] = v; }
            }
            if (WRITE_HT) {
                u16x4 pk; pk[0] = o[0]; pk[1] = o[1]; pk[2] = o[2]; pk[3] = o[3];
                *(u16x4*)&HT[(((size_t)(rowm >> 10)) * N + col) * 1024 + (rowm & 1023)] = pk;
            }
        }
    }
}

// ---------------------------------------------------------------------------
// Flash attention fwd v2: double-buffered LDS, async reg-staged K/V (T14),
// direct Q fragment load, one barrier per KV-tile, defer-max (T13).
// ---------------------------------------------------------------------------
__global__ __launch_bounds__(256) void flash_attn_kernel(
    const u16* __restrict__ Q, int qs,
    const u16* __restrict__ K, int ks,
    const u16* __restrict__ V, int vs,
    u16* __restrict__ O, int Slen)
{
    __shared__ u16 Ks[2][64][72];
    __shared__ u16 Vt[2][64][72];
    __shared__ u16 Pw[4][16][72];
    const int b = blockIdx.z, hh = blockIdx.y;
    const int m0 = blockIdx.x * 64;
    const int tid = threadIdx.x;
    const int w = tid >> 6, l = tid & 63;
    const int lq = l & 15, g = l >> 4;

    bf16x8 qf[2];
    {
        const u16* qp = Q + ((size_t)b * M_ + m0 + w * 16 + lq) * qs + hh * 64;
        u16x8 v0 = *(const u16x8*)(qp + g * 8);
        u16x8 v1 = *(const u16x8*)(qp + 32 + g * 8);
        u16x8 o0, o1;
#pragma unroll
        for (int i = 0; i < 8; ++i) {
            o0[i] = f2bf(bf2f(v0[i]) * 0.125f);
            o1[i] = f2bf(bf2f(v1[i]) * 0.125f);
        }
        qf[0] = __builtin_bit_cast(bf16x8, o0);
        qf[1] = __builtin_bit_cast(bf16x8, o1);
    }

    f32x4 acc_o[4];
#pragma unroll
    for (int nb = 0; nb < 4; ++nb)
#pragma unroll
        for (int j = 0; j < 4; ++j) acc_o[nb][j] = 0.f;
    float m_run = -1e30f, l_run = 0.f;

    const int kp = tid & 31, dg = tid >> 5;
    const int krow = tid >> 2, kcg = (tid & 3) * 16;

    const int nt = Slen >> 6;
    u16x8 kv0, kv1, va, vb;

#define ATT_LOAD(T_)                                                          \
    {                                                                         \
        const u16* kpp = K + ((size_t)b * Slen + (T_) * 64 + krow) * ks + hh * 64 + kcg; \
        kv0 = *(const u16x8*)kpp;                                             \
        kv1 = *(const u16x8*)(kpp + 8);                                       \
        const u16* vp0 = V + ((size_t)b * Slen + (T_) * 64 + 2 * kp) * vs + hh * 64 + dg * 8; \
        va = *(const u16x8*)vp0;                                              \
        vb = *(const u16x8*)(vp0 + vs);                                       \
    }
#define ATT_WRITE(BUF_)                                                       \
    {                                                                         \
        *(u16x8*)&Ks[BUF_][krow][kcg]     = kv0;                              \
        *(u16x8*)&Ks[BUF_][krow][kcg + 8] = kv1;                              \
        _Pragma("unroll") for (int i = 0; i < 8; ++i) {                       \
            u16x2 pk; pk[0] = va[i]; pk[1] = vb[i];                           \
            *(u16x2*)&Vt[BUF_][dg * 8 + i][2 * kp] = pk;                      \
        }                                                                     \
    }

    ATT_LOAD(0)
    ATT_WRITE(0)
    __syncthreads();

    for (int t = 0; t < nt; ++t) {
        if (t + 1 < nt) ATT_LOAD(t + 1)
        const int cb = t & 1;

        f32x4 s4[4];
#pragma unroll
        for (int mb = 0; mb < 4; ++mb) {
            f32x4 z = {0.f, 0.f, 0.f, 0.f};
            bf16x8 a0 = *(const bf16x8*)&Ks[cb][mb * 16 + lq][g * 8];
            bf16x8 a1 = *(const bf16x8*)&Ks[cb][mb * 16 + lq][32 + g * 8];
            z = __builtin_amdgcn_mfma_f32_16x16x32_bf16(a0, qf[0], z, 0, 0, 0);
            z = __builtin_amdgcn_mfma_f32_16x16x32_bf16(a1, qf[1], z, 0, 0, 0);
            s4[mb] = z;
        }

        float pm = -1e30f;
#pragma unroll
        for (int mb = 0; mb < 4; ++mb)
#pragma unroll
            for (int j = 0; j < 4; ++j) pm = fmaxf(pm, s4[mb][j]);
        pm = fmaxf(pm, __shfl_xor(pm, 16));
        pm = fmaxf(pm, __shfl_xor(pm, 32));

        u16 pbf[4][4];
        float ls = 0.f;
        if (__all(pm - m_run <= 8.f)) {
#pragma unroll
            for (int mb = 0; mb < 4; ++mb)
#pragma unroll
                for (int j = 0; j < 4; ++j) {
                    float p = __expf(s4[mb][j] - m_run);
                    ls += p;
                    pbf[mb][j] = f2bf(p);
                }
            ls += __shfl_xor(ls, 16);
            ls += __shfl_xor(ls, 32);
            l_run += ls;
        } else {
            const float m_new = fmaxf(m_run, pm);
            const float alpha = __expf(m_run - m_new);
#pragma unroll
            for (int mb = 0; mb < 4; ++mb)
#pragma unroll
                for (int j = 0; j < 4; ++j) {
                    float p = __expf(s4[mb][j] - m_new);
                    ls += p;
                    pbf[mb][j] = f2bf(p);
                }
            ls += __shfl_xor(ls, 16);
            ls += __shfl_xor(ls, 32);
            l_run = l_run * alpha + ls;
            m_run = m_new;
            float al[4];
#pragma unroll
            for (int j = 0; j < 4; ++j) al[j] = __shfl(alpha, 4 * g + j);
#pragma unroll
            for (int nb = 0; nb < 4; ++nb)
#pragma unroll
                for (int j = 0; j < 4; ++j) acc_o[nb][j] *= al[j];
        }

#pragma unroll
        for (int mb = 0; mb < 4; ++mb) {
            u16x4 pk;
            pk[0] = pbf[mb][0]; pk[1] = pbf[mb][1];
            pk[2] = pbf[mb][2]; pk[3] = pbf[mb][3];
            *(u16x4*)&Pw[w][lq][mb * 16 + g * 4] = pk;
        }

#pragma unroll
        for (int kc = 0; kc < 2; ++kc) {
            bf16x8 pa = *(const bf16x8*)&Pw[w][lq][kc * 32 + g * 8];
#pragma unroll
            for (int nb = 0; nb < 4; ++nb) {
                bf16x8 bv = *(const bf16x8*)&Vt[cb][nb * 16 + lq][kc * 32 + g * 8];
                acc_o[nb] = __builtin_amdgcn_mfma_f32_16x16x32_bf16(pa, bv, acc_o[nb], 0, 0, 0);
            }
        }

        if (t + 1 < nt) ATT_WRITE((t + 1) & 1)
        __syncthreads();
    }
#undef ATT_LOAD
#undef ATT_WRITE

    float linv[4];
#pragma unroll
    for (int j = 0; j < 4; ++j) linv[j] = 1.f / __shfl(l_run, 4 * g + j);
#pragma unroll
    for (int nb = 0; nb < 4; ++nb)
#pragma unroll
        for (int j = 0; j < 4; ++j) {
            const size_t row = (size_t)b * M_ + m0 + w * 16 + 4 * g + j;
            O[row * D_ + hh * 64 + nb * 16 + lq] = f2bf(acc_o[nb][j] * linv[j]);
        }
}

// ---------------------------------------------------------------------------
// One-shot f32->bf16 for all 7 tensors.
// ---------------------------------------------------------------------------
__global__ __launch_bounds__(256) void cvt_multi_kernel(
    const float* __restrict__ s0, u16* __restrict__ d0,
    const float* __restrict__ s1, u16* __restrict__ d1,
    const float* __restrict__ s2, u16* __restrict__ d2,
    const float* __restrict__ s3, u16* __restrict__ d3,
    const float* __restrict__ s4, u16* __restrict__ d4,
    const float* __restrict__ s5, u16* __restrict__ d5,
    const float* __restrict__ s6, u16* __restrict__ d6)
{
    int blk = blockIdx.x;
    const float* s; u16* d;
    if      (blk < 2048) { s = s0; d = d0; }
    else if (blk < 4096) { s = s1; d = d1; blk -= 2048; }
    else if (blk < 5632) { s = s2; d = d2; blk -= 4096; }
    else if (blk < 6144) { s = s3; d = d3; blk -= 5632; }
    else if (blk < 7680) { s = s4; d = d4; blk -= 6144; }
    else if (blk < 8192) { s = s5; d = d5; blk -= 7680; }
    else                 { s = s6; d = d6; blk -= 8192; }
    const size_t i = ((size_t)blk * 256 + threadIdx.x) * 8;
    float4 a = *(const float4*)(s + i);
    float4 b = *(const float4*)(s + i + 4);
    u16x8 o;
    o[0] = f2bf(a.x); o[1] = f2bf(a.y); o[2] = f2bf(a.z); o[3] = f2bf(a.w);
    o[4] = f2bf(b.x); o[5] = f2bf(b.y); o[6] = f2bf(b.z); o[7] = f2bf(b.w);
    *(u16x8*)(d + i) = o;
}

// ---------------------------------------------------------------------------
// Transpose (R x C) f32 -> (C x R) bf16, batched over z.
// ---------------------------------------------------------------------------
__global__ __launch_bounds__(256) void transpose_f32_bf16_kernel(
    const float* __restrict__ src, u16* __restrict__ dst, int R, int C,
    size_t sI, size_t sO)
{
    __shared__ u16 t[32][33];
    src += (size_t)blockIdx.z * sI;
    dst += (size_t)blockIdx.z * sO;
    const int c0 = blockIdx.x * 32, r0 = blockIdx.y * 32;
    const int x = threadIdx.x & 31, y = threadIdx.x >> 5;
    for (int i = y; i < 32; i += 8)
        t[i][x] = f2bf(src[(size_t)(r0 + i) * C + c0 + x]);
    __syncthreads();
    for (int i = y; i < 32; i += 8)
        dst[(size_t)(c0 + i) * R + r0 + x] = t[x][i];
}

// ---------------------------------------------------------------------------
// y = LayerNorm(X + R); writes f32 Y and (optionally) bf16 Ybf.
// ---------------------------------------------------------------------------
__global__ __launch_bounds__(256) void resid_ln_kernel(
    const float* __restrict__ X, const float* __restrict__ R,
    const float* __restrict__ g, const float* __restrict__ bt,
    float* __restrict__ Y, u16* __restrict__ Ybf)
{
    __shared__ float s1[4], s2[4];
    const size_t row = blockIdx.x;
    const int tid = threadIdx.x;
    const float4 x4 = *(const float4*)(X + row * 1024 + tid * 4);
    const float4 r4 = *(const float4*)(R + row * 1024 + tid * 4);
    float v[4] = {x4.x + r4.x, x4.y + r4.y, x4.z + r4.z, x4.w + r4.w};
    float s = v[0] + v[1] + v[2] + v[3];
    float q = v[0] * v[0] + v[1] * v[1] + v[2] * v[2] + v[3] * v[3];
#pragma unroll
    for (int off = 32; off; off >>= 1) {
        s += __shfl_xor(s, off);
        q += __shfl_xor(q, off);
    }
    if ((tid & 63) == 0) { s1[tid >> 6] = s; s2[tid >> 6] = q; }
    __syncthreads();
    s = s1[0] + s1[1] + s1[2] + s1[3];
    q = s2[0] + s2[1] + s2[2] + s2[3];
    const float mu = s * (1.f / 1024.f);
    const float var = q * (1.f / 1024.f) - mu * mu;
    const float rinv = rsqrtf(var + 1e-5f);
    const float4 g4 = *(const float4*)(g + tid * 4);
    const float4 b4 = *(const float4*)(bt + tid * 4);
    float o[4];
    o[0] = (v[0] - mu) * rinv * g4.x + b4.x;
    o[1] = (v[1] - mu) * rinv * g4.y + b4.y;
    o[2] = (v[2] - mu) * rinv * g4.z + b4.z;
    o[3] = (v[3] - mu) * rinv * g4.w + b4.w;
    *(float4*)(Y + row * 1024 + tid * 4) = *(float4*)o;
    if (Ybf) {
        u16x4 ob;
        ob[0] = f2bf(o[0]); ob[1] = f2bf(o[1]);
        ob[2] = f2bf(o[2]); ob[3] = f2bf(o[3]);
        *(u16x4*)(Ybf + row * 1024 + tid * 4) = ob;
    }
}

// ---------------------------------------------------------------------------
// dispatch softmax over m (sums 4 split-K partials), bf16 transposed out.
// ---------------------------------------------------------------------------
__global__ __launch_bounds__(256) void dispatch_softmax_T_kernel(
    const float* __restrict__ logitsP, u16* __restrict__ dispT)
{
    __shared__ float red[4];
    constexpr size_t CH = (size_t)B_ * M_ * NE_;
    const int n = blockIdx.x, b = blockIdx.y;
    u16* O = dispT + ((size_t)b * NE_ + n) * M_;
    const int tid = threadIdx.x;
    float v[4];
#pragma unroll
    for (int i = 0; i < 4; ++i) {
        const size_t idx = (size_t)(b * M_ + tid + 256 * i) * NE_ + n;
        v[i] = logitsP[idx] + logitsP[CH + idx] + logitsP[2 * CH + idx] + logitsP[3 * CH + idx];
    }
    float mx = fmaxf(fmaxf(v[0], v[1]), fmaxf(v[2], v[3]));
#pragma unroll
    for (int off = 32; off; off >>= 1) mx = fmaxf(mx, __shfl_xor(mx, off));
    if ((tid & 63) == 0) red[tid >> 6] = mx;
    __syncthreads();
    mx = fmaxf(fmaxf(red[0], red[1]), fmaxf(red[2], red[3]));
    __syncthreads();
    float e[4], s = 0.f;
#pragma unroll
    for (int i = 0; i < 4; ++i) { e[i] = __expf(v[i] - mx); s += e[i]; }
#pragma unroll
    for (int off = 32; off; off >>= 1) s += __shfl_xor(s, off);
    if ((tid & 63) == 0) red[tid >> 6] = s;
    __syncthreads();
    s = red[0] + red[1] + red[2] + red[3];
    const float inv = 1.f / s;
#pragma unroll
    for (int i = 0; i < 4; ++i) O[tid + 256 * i] = f2bf(e[i] * inv);
}

// ---------------------------------------------------------------------------
// combine softmax over 128 experts (sums partials), bf16 out.
// ---------------------------------------------------------------------------
__global__ __launch_bounds__(64) void combine_softmax_kernel(
    const float* __restrict__ logitsP, u16* __restrict__ comb)
{
    constexpr size_t CH = (size_t)B_ * M_ * NE_;
    const size_t row = blockIdx.x;
    const int lane = threadIdx.x;
    const size_t i0 = row * NE_ + lane;
    const size_t i1 = i0 + 64;
    float a = logitsP[i0] + logitsP[CH + i0] + logitsP[2 * CH + i0] + logitsP[3 * CH + i0];
    float c = logitsP[i1] + logitsP[CH + i1] + logitsP[2 * CH + i1] + logitsP[3 * CH + i1];
    float mx = fmaxf(a, c);
#pragma unroll
    for (int off = 32; off; off >>= 1) mx = fmaxf(mx, __shfl_xor(mx, off));
    float e0 = __expf(a - mx), e1 = __expf(c - mx);
    float s = e0 + e1;
#pragma unroll
    for (int off = 32; off; off >>= 1) s += __shfl_xor(s, off);
    const float inv = 1.f / s;
    comb[row * NE_ + lane]      = f2bf(e0 * inv);
    comb[row * NE_ + lane + 64] = f2bf(e1 * inv);
}

// ---------------------------------------------------------------------------
// Expert partials: part[c][b][n][d] = sum_{f in chunk c} slots[b][n][f]*w[n][f][d]
// ---------------------------------------------------------------------------
__global__ __launch_bounds__(256) void expert_partial_kernel(
    const float* __restrict__ slots, const float* __restrict__ exp_w,
    float* __restrict__ part)
{
    __shared__ float sl[4][512];
    const int n = blockIdx.x;
    const int c = blockIdx.y;
    const int f0 = c * 512;
    const int t = threadIdx.x;
    for (int i = t; i < 2048; i += 256) {
        const int b = i >> 9, f = i & 511;
        sl[b][f] = slots[((size_t)b * NE_ + n) * FF_ + f0 + f];
    }
    __syncthreads();
    const int d4 = t * 4;
    const float* wp = exp_w + ((size_t)n * FF_ + f0) * D_ + d4;
    f32x4 acc[4];
#pragma unroll
    for (int b = 0; b < 4; ++b)
#pragma unroll
        for (int j = 0; j < 4; ++j) acc[b][j] = 0.f;
#pragma unroll 4
    for (int f = 0; f < 512; ++f) {
        const float4 w4 = *(const float4*)wp;
        wp += D_;
#pragma unroll
        for (int b = 0; b < 4; ++b) {
            const float s = sl[b][f];
            acc[b][0] = fmaf(s, w4.x, acc[b][0]);
            acc[b][1] = fmaf(s, w4.y, acc[b][1]);
            acc[b][2] = fmaf(s, w4.z, acc[b][2]);
            acc[b][3] = fmaf(s, w4.w, acc[b][3]);
        }
    }
#pragma unroll
    for (int b = 0; b < 4; ++b)
        *(f32x4*)&part[(((size_t)c * 4 + b) * NE_ + n) * D_ + d4] = acc[b];
}

// ---------------------------------------------------------------------------
// Reduce 8 partials + exp_b, emit yT[b][d][n] bf16 (fused transpose).
// ---------------------------------------------------------------------------
__global__ __launch_bounds__(256) void reduce_yT_kernel(
    const float* __restrict__ part, const float* __restrict__ exp_b,
    u16* __restrict__ yT)
{
    __shared__ float tile[32][33];
    const int d0 = blockIdx.x * 32, n0 = blockIdx.y * 32, b = blockIdx.z;
    const int x = threadIdx.x & 31, y = threadIdx.x >> 5;
    for (int i = y; i < 32; i += 8) {
        const int n = n0 + i;
        float s = exp_b[(size_t)n * D_ + d0 + x];
#pragma unroll
        for (int c = 0; c < 8; ++c)
            s += part[(((size_t)c * 4 + b) * NE_ + n) * D_ + d0 + x];
        tile[i][x] = s;
    }
    __syncthreads();
    for (int i = y; i < 32; i += 8)
        yT[((size_t)b * D_ + d0 + i) * NE_ + n0 + x] = f2bf(tile[x][i]);
}

// ---------------------------------------------------------------------------
extern "C" void kernel_launch(void* const* d_in, const int* in_sizes, int n_in,
                              void* d_out, int out_size, void* d_ws, size_t ws_size,
                              hipStream_t stream)
{
    const float* tgt      = (const float*)d_in[0];
    const float* memry    = (const float*)d_in[1];
    const float* sa_in_w  = (const float*)d_in[2];
    const float* sa_in_b  = (const float*)d_in[3];
    const float* sa_out_w = (const float*)d_in[4];
    const float* sa_out_b = (const float*)d_in[5];
    const float* ca_in_w  = (const float*)d_in[6];
    const float* ca_in_b  = (const float*)d_in[7];
    const float* ca_out_w = (const float*)d_in[8];
    const float* ca_out_b = (const float*)d_in[9];
    const float* norm1_g  = (const float*)d_in[10];
    const float* norm1_b  = (const float*)d_in[11];
    const float* norm2_g  = (const float*)d_in[12];
    const float* norm2_b  = (const float*)d_in[13];
    const float* norm3_g  = (const float*)d_in[14];
    const float* norm3_b  = (const float*)d_in[15];
    const float* lin_w    = (const float*)d_in[16];
    const float* lin_b    = (const float*)d_in[17];
    const float* phi      = (const float*)d_in[18];
    const float* exp_w    = (const float*)d_in[19];
    const float* exp_b    = (const float*)d_in[20];

    float* ws = (float*)d_ws;
    u16*   qkv_bf  = (u16*)(ws);                 // [4096][3072] u16 (CA reuse)
    float* proj    = ws + 6291456;
    float* x1      = ws + 10485760;
    float* x2      = ws + 14680064;
    float* logitsP = ws + 18874368;              // 4 x 524,288
    float* part    = ws + 20971520;              // 4,194,304
    u16*   h_bf    = (u16*)(ws + 25165824);      // [4096][4096]
    u16*   hT_bf   = (u16*)(ws + 33554432);      // [4][4096][1024]
    u16*   obuf_bf = (u16*)(ws + 41943040);      // [4096][1024]
    u16*   x1_bf   = (u16*)(ws + 44040192);
    u16*   x2_bf   = (u16*)(ws + 46137344);
    u16*   tgt_bf  = (u16*)(ws + 48234496);
    u16*   mem_bf  = (u16*)(ws + 50331648);
    u16*   dispT   = (u16*)(ws + 52428800);      // [4][128][1024]
    u16*   comb_bf = (u16*)(ws + 52690944);      // [4096][128]
    u16*   yT_bf   = (u16*)(ws + 52953088);      // [4][1024][128]
    float* slots   = ws + 53215232;              // 2,097,152
    u16*   w_sa_in = (u16*)(ws + 55312384);
    u16*   w_sa_out= (u16*)(ws + 56885248);
    u16*   w_ca_in = (u16*)(ws + 57409536);
    u16*   w_ca_out= (u16*)(ws + 58982400);
    u16*   w_lin   = (u16*)(ws + 59506688);
    u16*   phiT    = (u16*)(ws + 61603840);

    constexpr size_t CH = (size_t)B_ * M_ * NE_;

    // ---- bf16 conversions (single launch) ----
    cvt_multi_kernel<<<10240, 256, 0, stream>>>(
        tgt, tgt_bf, memry, mem_bf, sa_in_w, w_sa_in, sa_out_w, w_sa_out,
        ca_in_w, w_ca_in, ca_out_w, w_ca_out, lin_w, w_lin);
    transpose_f32_bf16_kernel<<<dim3(4, 128, 1), 256, 0, stream>>>(phi, phiT, 4096, 128, 0, 0);

    // ---- Self-attention ----
    gemm64_mfma<1, 0, 1, 0><<<dim3(24, 64, 1), 256, 0, stream>>>(
        tgt_bf, w_sa_in, sa_in_b, qkv_bf, nullptr, 1024, 3072, 1024, 1024, 0, 0, 0);
    flash_attn_kernel<<<dim3(16, 16, 4), 256, 0, stream>>>(
        qkv_bf, 3072, qkv_bf + 1024, 3072, qkv_bf + 2048, 3072, obuf_bf, S_);
    gemm64_mfma<0, 0, 1, 0><<<dim3(8, 64, 1), 256, 0, stream>>>(
        obuf_bf, w_sa_out, sa_out_b, proj, nullptr, 1024, 1024, 1024, 1024, 0, 0, 0);
    resid_ln_kernel<<<4096, 256, 0, stream>>>(tgt, proj, norm1_g, norm1_b, x1, x1_bf);

    // ---- Cross-attention ----
    u16* qca_bf = qkv_bf;
    u16* kvca_bf = qkv_bf + (size_t)4096 * 1024;
    gemm64_mfma<1, 0, 1, 0><<<dim3(8, 64, 1), 256, 0, stream>>>(
        x1_bf, w_ca_in, ca_in_b, qca_bf, nullptr, 1024, 1024, 1024, 1024, 0, 0, 0);
    gemm64_mfma<1, 0, 1, 0><<<dim3(16, 64, 1), 256, 0, stream>>>(
        mem_bf, w_ca_in + (size_t)1024 * 1024, ca_in_b + 1024,
        kvca_bf, nullptr, 1024, 2048, 1024, 1024, 0, 0, 0);
    flash_attn_kernel<<<dim3(16, 16, 4), 256, 0, stream>>>(
        qca_bf, 1024, kvca_bf, 2048, kvca_bf + 1024, 2048, obuf_bf, S_);
    gemm64_mfma<0, 0, 1, 0><<<dim3(8, 64, 1), 256, 0, stream>>>(
        obuf_bf, w_ca_out, ca_out_b, proj, nullptr, 1024, 1024, 1024, 1024, 0, 0, 0);
    resid_ln_kernel<<<4096, 256, 0, stream>>>(x1, proj, norm2_g, norm2_b, x2, x2_bf);

    // ---- FF + SoftMoE ----
    gemm64_mfma<1, 1, 1, 1><<<dim3(32, 64, 1), 256, 0, stream>>>(
        x2_bf, w_lin, lin_b, h_bf, hT_bf, 1024, 4096, 1024, 1024, 0, 0, 0);
    // logits: split-K x4 (z = K-chunk of 1024)
    gemm64_mfma<0, 0, 0, 0><<<dim3(1, 64, 4), 256, 0, stream>>>(
        h_bf, phiT, nullptr, logitsP, nullptr, 1024, 128, 4096, 4096,
        1024, 1024, CH);
    dispatch_softmax_T_kernel<<<dim3(NE_, B_), 256, 0, stream>>>(logitsP, dispT);
    combine_softmax_kernel<<<dim3(B_ * M_), 64, 0, stream>>>(logitsP, comb_bf);
    // slots = dispT @ hT (batched over B)
    gemm64_mfma<0, 0, 0, 0><<<dim3(32, 2, 4), 256, 0, stream>>>(
        dispT, hT_bf, nullptr, slots, nullptr, 1024, 4096, 1024, 1024,
        (size_t)NE_ * M_, (size_t)FF_ * M_, (size_t)NE_ * FF_);
    expert_partial_kernel<<<dim3(NE_, 8), 256, 0, stream>>>(slots, exp_w, part);
    reduce_yT_kernel<<<dim3(32, 4, 4), 256, 0, stream>>>(part, exp_b, yT_bf);
    // ff_out = combine @ y (batched over B)
    gemm64_mfma<0, 0, 0, 0><<<dim3(8, 16, 4), 256, 0, stream>>>(
        comb_bf, yT_bf, nullptr, proj, nullptr, 128, 1024, 128, 128,
        (size_t)M_ * NE_, (size_t)D_ * NE_, (size_t)M_ * D_);
    resid_ln_kernel<<<4096, 256, 0, stream>>>(x2, proj, norm3_g, norm3_b,
                                              (float*)d_out, nullptr);
}